// Round 1
// baseline (1403.673 us; speedup 1.0000x reference)
//
#include <hip/hip_runtime.h>
#include <math.h>

#define LQ 1024      // sequence length L
#define DM 512       // model dim D
#define HN 8         // heads
#define DHD 64       // head dim
#define NSB 8        // N*S
#define ROWS 8192    // NSB*LQ
#define DE 128       // effective attention dim (2*DHD)

// ---------------------------------------------------------------------------
// GEMM: C = X @ W^T + bias, optional relu.  X:[M,Kd] W:[Nn,Kd] C:[M,Nn]
// BM=BN=64, BK=16, 256 threads, 4x4 per thread.
// ---------------------------------------------------------------------------
__global__ __launch_bounds__(256)
void gemm_xwt(const float* __restrict__ X, const float* __restrict__ W,
              const float* __restrict__ bias, float* __restrict__ C,
              int M, int Kd, int Nn, int relu)
{
    const int bn = blockIdx.x;   // col tile
    const int bm = blockIdx.y;   // row tile
    const int tid = threadIdx.x;
    const int tx = tid & 15, ty = tid >> 4;
    const int m0 = bm * 64, n0 = bn * 64;

    __shared__ float Xs[16][65];
    __shared__ float Ws[16][65];
    float acc[4][4] = {};

    const int r  = tid >> 2;          // 0..63
    const int kq = (tid & 3) << 2;    // 0,4,8,12

    for (int k0 = 0; k0 < Kd; k0 += 16) {
        float4 xv = *(const float4*)&X[(size_t)(m0 + r) * Kd + k0 + kq];
        float4 wv = *(const float4*)&W[(size_t)(n0 + r) * Kd + k0 + kq];
        Xs[kq + 0][r] = xv.x; Xs[kq + 1][r] = xv.y;
        Xs[kq + 2][r] = xv.z; Xs[kq + 3][r] = xv.w;
        Ws[kq + 0][r] = wv.x; Ws[kq + 1][r] = wv.y;
        Ws[kq + 2][r] = wv.z; Ws[kq + 3][r] = wv.w;
        __syncthreads();
        #pragma unroll
        for (int kk = 0; kk < 16; ++kk) {
            float a[4], b[4];
            #pragma unroll
            for (int i = 0; i < 4; ++i) a[i] = Xs[kk][ty * 4 + i];
            #pragma unroll
            for (int j = 0; j < 4; ++j) b[j] = Ws[kk][tx * 4 + j];
            #pragma unroll
            for (int i = 0; i < 4; ++i)
                #pragma unroll
                for (int j = 0; j < 4; ++j)
                    acc[i][j] += a[i] * b[j];
        }
        __syncthreads();
    }

    #pragma unroll
    for (int i = 0; i < 4; ++i) {
        int row = m0 + ty * 4 + i;
        #pragma unroll
        for (int j = 0; j < 4; ++j) {
            int col = n0 + tx * 4 + j;
            float v = acc[i][j] + bias[col];
            if (relu) v = fmaxf(v, 0.f);
            C[(size_t)row * Nn + col] = v;
        }
    }
}

// ---------------------------------------------------------------------------
// Build attention operands:
//   A[head,l,0:64]   = q*sin(pq),       A[head,l,64:128] = -q*cos(pq)
//   B[head,l,0:64]   = k*cos(pk-b),     B[head,l,64:128] =  k*sin(pk-b)
//   Vh[head,l,0:64]  = v
// pq = Pq@Wp^T + bp,  pk-b = Pk@Wp^T   (P=3, computed inline, f32 sincos)
// ---------------------------------------------------------------------------
__global__ __launch_bounds__(512)
void make_ab(const float* __restrict__ Pq, const float* __restrict__ Pk,
             const float* __restrict__ Wp, const float* __restrict__ bp,
             const float* __restrict__ qf, const float* __restrict__ kf,
             const float* __restrict__ vf,
             float* __restrict__ A, float* __restrict__ B, float* __restrict__ Vh)
{
    const int row = blockIdx.x;          // ns*1024 + l
    const int d = threadIdx.x;           // 0..511
    const int ns = row >> 10, l = row & 1023;
    const int h = d >> 6, dh = d & 63;
    const int head = ns * HN + h;

    const float p0 = Pq[row * 3 + 0], p1 = Pq[row * 3 + 1], p2 = Pq[row * 3 + 2];
    const float r0 = Pk[row * 3 + 0], r1 = Pk[row * 3 + 1], r2 = Pk[row * 3 + 2];
    const float w0 = Wp[d * 3 + 0], w1 = Wp[d * 3 + 1], w2 = Wp[d * 3 + 2];
    const float bpd = bp[d];

    const float pq   = p0 * w0 + p1 * w1 + p2 * w2 + bpd;
    const float pkmb = r0 * w0 + r1 * w1 + r2 * w2;   // (pk) - b == Pk@Wp^T

    const float qv = qf[(size_t)row * DM + d];
    const float kv = kf[(size_t)row * DM + d];
    const float vv = vf[(size_t)row * DM + d];

    float sq, cq, sk, ck;
    sincosf(pq, &sq, &cq);
    sincosf(pkmb, &sk, &ck);

    const size_t ab = ((size_t)head * LQ + l) * DE + dh;
    A[ab]      = qv * sq;
    A[ab + 64] = -qv * cq;
    B[ab]      = kv * ck;
    B[ab + 64] = kv * sk;
    Vh[((size_t)head * LQ + l) * DHD + dh] = vv;
}

// ---------------------------------------------------------------------------
// Attention: one block = one head x 8 query rows. Scores staged in LDS.
// ---------------------------------------------------------------------------
__global__ __launch_bounds__(256)
void attn(const float* __restrict__ A, const float* __restrict__ B,
          const float* __restrict__ Vh, float* __restrict__ T)
{
    const int bid = blockIdx.x;          // 64 heads * 128 row-blocks
    const int head = bid >> 7;
    const int row0 = (bid & 127) * 8;
    const int tid = threadIdx.x;
    const int ns = head >> 3, h = head & 7;

    __shared__ float As[8][DE];          // 4 KB
    __shared__ float sc[8][LQ];          // 32 KB
    __shared__ float red[8][32];         // 1 KB
    __shared__ float rowmax[8];
    __shared__ float rowsum[8];
    __shared__ float opart[4][8][DHD];   // 8 KB

    for (int idx = tid; idx < 8 * DE; idx += 256) {
        int q = idx >> 7, dd = idx & 127;
        As[q][dd] = A[((size_t)head * LQ + row0 + q) * DE + dd];
    }
    __syncthreads();

    // ---- scores: each thread does 4 keys, dotted against the 8 A-rows ----
    for (int kt = 0; kt < 4; ++kt) {
        const int k = kt * 256 + tid;
        const float4* Brow = (const float4*)&B[((size_t)head * LQ + k) * DE];
        float acc[8] = {};
        for (int d4 = 0; d4 < 32; ++d4) {
            float4 bv = Brow[d4];
            #pragma unroll
            for (int q = 0; q < 8; ++q) {
                float4 av = *(const float4*)&As[q][d4 * 4];
                acc[q] += av.x * bv.x + av.y * bv.y + av.z * bv.z + av.w * bv.w;
            }
        }
        #pragma unroll
        for (int q = 0; q < 8; ++q) sc[q][k] = acc[q];
    }
    __syncthreads();

    // ---- row max ----
    const int q8 = tid >> 5, lane32 = tid & 31;
    {
        float m = -1e30f;
        for (int k = lane32; k < LQ; k += 32) m = fmaxf(m, sc[q8][k]);
        red[q8][lane32] = m;
    }
    __syncthreads();
    if (tid < 8) {
        float mm = red[tid][0];
        for (int i = 1; i < 32; ++i) mm = fmaxf(mm, red[tid][i]);
        rowmax[tid] = mm;
    }
    __syncthreads();

    // ---- exp + row sum ----
    {
        const float m2 = rowmax[q8];
        float s = 0.f;
        for (int k = lane32; k < LQ; k += 32) {
            float e = __expf(sc[q8][k] - m2);
            sc[q8][k] = e;
            s += e;
        }
        red[q8][lane32] = s;
    }
    __syncthreads();
    if (tid < 8) {
        float ss = 0.f;
        for (int i = 0; i < 32; ++i) ss += red[tid][i];
        rowsum[tid] = ss;
    }
    __syncthreads();

    // ---- PV: thread (g, dd): keys g*256..g*256+255, output dim dd ----
    {
        const int dd = tid & 63;
        const int g = tid >> 6;
        float o[8] = {};
        for (int k = g * 256; k < g * 256 + 256; ++k) {
            float vv = Vh[((size_t)head * LQ + k) * DHD + dd];
            #pragma unroll
            for (int qq = 0; qq < 8; ++qq) o[qq] += sc[qq][k] * vv;
        }
        #pragma unroll
        for (int qq = 0; qq < 8; ++qq) opart[g][qq][dd] = o[qq];
    }
    __syncthreads();
    for (int idx = tid; idx < 8 * DHD; idx += 256) {
        int qq = idx >> 6, d2 = idx & 63;
        float s = opart[0][qq][d2] + opart[1][qq][d2] +
                  opart[2][qq][d2] + opart[3][qq][d2];
        s /= rowsum[qq];
        // merged-head layout: T[ns, l, h*64 + d]
        T[((size_t)ns * LQ + row0 + qq) * DM + h * DHD + d2] = s;
    }
}

// ---------------------------------------------------------------------------
// BatchNorm: deterministic two-stage reduction (no float atomics)
// ---------------------------------------------------------------------------
__global__ __launch_bounds__(256)
void bn_partial(const float* __restrict__ Y, float* __restrict__ partial)
{
    const int blk = blockIdx.x;          // 256 blocks x 32 rows
    const int tid = threadIdx.x;
    float s0 = 0, s1 = 0, s20 = 0, s21 = 0;
    const int r0 = blk * 32;
    for (int r2 = 0; r2 < 32; ++r2) {
        const float* row = Y + (size_t)(r0 + r2) * DM;
        float v0 = row[tid];       s0 += v0; s20 += v0 * v0;
        float v1 = row[tid + 256]; s1 += v1; s21 += v1 * v1;
    }
    float* base = partial + (size_t)blk * 1024;
    base[tid]             = s0;   // sum, channel tid
    base[tid + 256]       = s1;   // sum, channel tid+256
    base[512 + tid]       = s20;  // sumsq
    base[512 + tid + 256] = s21;
}

__global__ __launch_bounds__(256)
void bn_reduce(const float* __restrict__ partial, float* __restrict__ stats)
{
    const int c = blockIdx.x * 256 + threadIdx.x;   // 0..1023
    float s = 0.f;
    for (int b = 0; b < 256; ++b) s += partial[(size_t)b * 1024 + c];
    stats[c] = s;
}

__global__ __launch_bounds__(256)
void bn_final(const float* __restrict__ Y, const float* __restrict__ Qin,
              const float* __restrict__ stats,
              const float* __restrict__ gamma, const float* __restrict__ beta,
              float* __restrict__ out)
{
    const int i = blockIdx.x * 256 + threadIdx.x;   // 0..ROWS*DM-1
    const int c = i & (DM - 1);
    const float mu  = stats[c] * (1.f / ROWS);
    const float var = stats[512 + c] * (1.f / ROWS) - mu * mu;
    const float rs  = rsqrtf(var + 1e-5f);
    out[i] = Qin[i] + (Y[i] - mu) * rs * gamma[c] + beta[c];
}

// ---------------------------------------------------------------------------
extern "C" void kernel_launch(void* const* d_in, const int* in_sizes, int n_in,
                              void* d_out, int out_size, void* d_ws, size_t ws_size,
                              hipStream_t stream)
{
    (void)in_sizes; (void)n_in; (void)out_size; (void)ws_size;

    const float* Q    = (const float*)d_in[0];
    const float* K    = (const float*)d_in[1];
    const float* Pq   = (const float*)d_in[2];
    const float* Pk   = (const float*)d_in[3];
    const float* Wq   = (const float*)d_in[4];
    const float* bq   = (const float*)d_in[5];
    const float* Wk   = (const float*)d_in[6];
    const float* bk   = (const float*)d_in[7];
    const float* Wv   = (const float*)d_in[8];
    const float* bv   = (const float*)d_in[9];
    const float* Wp   = (const float*)d_in[10];
    const float* bp   = (const float*)d_in[11];
    const float* We   = (const float*)d_in[12];
    const float* be   = (const float*)d_in[13];
    const float* Wc   = (const float*)d_in[14];
    const float* bc   = (const float*)d_in[15];
    const float* gamma= (const float*)d_in[16];
    const float* beta = (const float*)d_in[17];

    float* ws = (float*)d_ws;
    // workspace layout (floats); buffers reused across phases
    float* qfull = ws;                       // 4,194,304
    float* kfull = ws + 4194304;             // 4,194,304
    float* vfull = ws + 8388608;             // 4,194,304
    float* Abuf  = ws + 12582912;            // 8,388,608
    float* Bbuf  = ws + 20971520;            // 8,388,608
    float* Vh    = ws + 29360128;            // 4,194,304
    // total: 33,554,432 floats = 128 MiB
    float* T     = qfull;                    // reuse (qfull dead after make_ab)
    float* H1    = kfull;                    // spans kfull+vfull (8,388,608)
    float* Y     = Abuf;                     // reuse (A dead after attn)
    float* part  = Bbuf;                     // 262,144 (B dead after attn)
    float* stats = Bbuf + 262144;            // 1,024

    dim3 blk256(256);

    // QKV projections
    gemm_xwt<<<dim3(8, 128), blk256, 0, stream>>>(Q, Wq, bq, qfull, ROWS, DM, DM, 0);
    gemm_xwt<<<dim3(8, 128), blk256, 0, stream>>>(K, Wk, bk, kfull, ROWS, DM, DM, 0);
    gemm_xwt<<<dim3(8, 128), blk256, 0, stream>>>(K, Wv, bv, vfull, ROWS, DM, DM, 0);

    // phase projection + sin/cos operand build
    make_ab<<<ROWS, 512, 0, stream>>>(Pq, Pk, Wp, bp, qfull, kfull, vfull,
                                      Abuf, Bbuf, Vh);

    // attention (writes merged-head T)
    attn<<<64 * 128, blk256, 0, stream>>>(Abuf, Bbuf, Vh, T);

    // FFN
    gemm_xwt<<<dim3(16, 128), blk256, 0, stream>>>(T, We, be, H1, ROWS, DM, 2 * DM, 1);
    gemm_xwt<<<dim3(8, 128), blk256, 0, stream>>>(H1, Wc, bc, Y, ROWS, 2 * DM, DM, 0);

    // BatchNorm (training stats) + residual
    bn_partial<<<256, blk256, 0, stream>>>(Y, part);
    bn_reduce<<<4, blk256, 0, stream>>>(part, stats);
    bn_final<<<ROWS * DM / 256, blk256, 0, stream>>>(Y, Q, stats, gamma, beta,
                                                     (float*)d_out);
}

// Round 2
// 302.420 us; speedup vs baseline: 4.6415x; 4.6415x over previous
//
#include <hip/hip_runtime.h>
#include <math.h>

#define LQ 1024      // sequence length L
#define DM 512       // model dim D
#define HN 8         // heads
#define DHD 64       // head dim
#define ROWS 8192    // N*S*L
#define DE 128       // effective attention dim (2*DHD)

typedef __attribute__((ext_vector_type(8))) short bf16x8;
typedef __attribute__((ext_vector_type(4))) float floatx4;

static __device__ __forceinline__ unsigned short f2bf(float x) {
    unsigned int u = __float_as_uint(x);
    u = (u + 0x7fffu + ((u >> 16) & 1u)) >> 16;   // round-nearest-even
    return (unsigned short)u;
}

// ---------------------------------------------------------------------------
// MFMA GEMM: C = X @ W^T + bias (optional relu). X:[M,Kd] f32, W:[Nn,Kd] f32.
// 64x64 tile, BK=64, 256 thr = 4 waves; wave w owns rows w*16..w*16+15.
// f32 -> bf16 conversion happens inline during LDS staging.
// ---------------------------------------------------------------------------
__global__ __launch_bounds__(256)
void gemm_mfma(const float* __restrict__ X, const float* __restrict__ W,
               const float* __restrict__ bias, float* __restrict__ C,
               int M, int Kd, int Nn, int relu)
{
    const int bn = blockIdx.x, bm = blockIdx.y;
    const int tid = threadIdx.x;
    const int w = tid >> 6, lane = tid & 63;
    const int lr = lane & 15, lg = lane >> 4;
    const int m0 = bm * 64, n0 = bn * 64;

    __shared__ unsigned short Xs[64][72];   // pad: 144B stride, 16B aligned
    __shared__ unsigned short Ws2[64][72];

    floatx4 acc[4] = {};

    const int sr = tid >> 2;            // staging row 0..63
    const int sc = (tid & 3) << 4;      // k offset in elements: 0,16,32,48

    for (int k0 = 0; k0 < Kd; k0 += 64) {
        const float* xp = &X[(size_t)(m0 + sr) * Kd + k0 + sc];
        const float* wp = &W[(size_t)(n0 + sr) * Kd + k0 + sc];
        float4 xa = ((const float4*)xp)[0], xb = ((const float4*)xp)[1];
        float4 xc = ((const float4*)xp)[2], xd = ((const float4*)xp)[3];
        float4 wa = ((const float4*)wp)[0], wb = ((const float4*)wp)[1];
        float4 wc = ((const float4*)wp)[2], wd = ((const float4*)wp)[3];
        bf16x8 v0, v1;
        v0[0]=f2bf(xa.x); v0[1]=f2bf(xa.y); v0[2]=f2bf(xa.z); v0[3]=f2bf(xa.w);
        v0[4]=f2bf(xb.x); v0[5]=f2bf(xb.y); v0[6]=f2bf(xb.z); v0[7]=f2bf(xb.w);
        v1[0]=f2bf(xc.x); v1[1]=f2bf(xc.y); v1[2]=f2bf(xc.z); v1[3]=f2bf(xc.w);
        v1[4]=f2bf(xd.x); v1[5]=f2bf(xd.y); v1[6]=f2bf(xd.z); v1[7]=f2bf(xd.w);
        *(bf16x8*)&Xs[sr][sc]     = v0;
        *(bf16x8*)&Xs[sr][sc + 8] = v1;
        v0[0]=f2bf(wa.x); v0[1]=f2bf(wa.y); v0[2]=f2bf(wa.z); v0[3]=f2bf(wa.w);
        v0[4]=f2bf(wb.x); v0[5]=f2bf(wb.y); v0[6]=f2bf(wb.z); v0[7]=f2bf(wb.w);
        v1[0]=f2bf(wc.x); v1[1]=f2bf(wc.y); v1[2]=f2bf(wc.z); v1[3]=f2bf(wc.w);
        v1[4]=f2bf(wd.x); v1[5]=f2bf(wd.y); v1[6]=f2bf(wd.z); v1[7]=f2bf(wd.w);
        *(bf16x8*)&Ws2[sr][sc]     = v0;
        *(bf16x8*)&Ws2[sr][sc + 8] = v1;
        __syncthreads();

        #pragma unroll
        for (int ks = 0; ks < 2; ++ks) {
            bf16x8 a = *(const bf16x8*)&Xs[w * 16 + lr][ks * 32 + lg * 8];
            #pragma unroll
            for (int c = 0; c < 4; ++c) {
                bf16x8 b = *(const bf16x8*)&Ws2[c * 16 + lr][ks * 32 + lg * 8];
                acc[c] = __builtin_amdgcn_mfma_f32_16x16x32_bf16(a, b, acc[c], 0, 0, 0);
            }
        }
        __syncthreads();
    }

    #pragma unroll
    for (int c = 0; c < 4; ++c) {
        const int col = n0 + c * 16 + lr;
        const float bi = bias[col];
        #pragma unroll
        for (int r = 0; r < 4; ++r) {
            const int row = m0 + w * 16 + lg * 4 + r;
            float v = acc[c][r] + bi;
            if (relu) v = fmaxf(v, 0.f);
            C[(size_t)row * Nn + col] = v;
        }
    }
}

// ---------------------------------------------------------------------------
// Build bf16 attention operands:
//   A[head,l,0:64]  = q*sin(pq),    A[head,l,64:128] = -q*cos(pq)
//   B[head,l,0:64]  = k*cos(pk-b),  B[head,l,64:128] =  k*sin(pk-b)
//   Vt[head,d,l]    = v (transposed per head for PV MFMA B-operand)
// Phases computed in f32 (P=3 projection inline).
// ---------------------------------------------------------------------------
__global__ __launch_bounds__(512)
void make_ab(const float* __restrict__ Pq, const float* __restrict__ Pk,
             const float* __restrict__ Wp, const float* __restrict__ bp,
             const float* __restrict__ qf, const float* __restrict__ kf,
             const float* __restrict__ vf,
             unsigned short* __restrict__ A, unsigned short* __restrict__ B,
             unsigned short* __restrict__ Vt)
{
    const int row = blockIdx.x;          // ns*1024 + l
    const int d = threadIdx.x;           // 0..511
    const int ns = row >> 10, l = row & 1023;
    const int h = d >> 6, dh = d & 63;
    const int head = ns * HN + h;

    const float p0 = Pq[row * 3 + 0], p1 = Pq[row * 3 + 1], p2 = Pq[row * 3 + 2];
    const float r0 = Pk[row * 3 + 0], r1 = Pk[row * 3 + 1], r2 = Pk[row * 3 + 2];
    const float w0 = Wp[d * 3 + 0], w1 = Wp[d * 3 + 1], w2 = Wp[d * 3 + 2];
    const float bpd = bp[d];

    const float pq   = p0 * w0 + p1 * w1 + p2 * w2 + bpd;
    const float pkmb = r0 * w0 + r1 * w1 + r2 * w2;   // pk - b

    const float qv = qf[(size_t)row * DM + d];
    const float kv = kf[(size_t)row * DM + d];
    const float vv = vf[(size_t)row * DM + d];

    float sq, cq, sk, ck;
    sincosf(pq, &sq, &cq);
    sincosf(pkmb, &sk, &ck);

    const size_t ab = ((size_t)head * LQ + l) * DE + dh;
    A[ab]      = f2bf(qv * sq);
    A[ab + 64] = f2bf(-qv * cq);
    B[ab]      = f2bf(kv * ck);
    B[ab + 64] = f2bf(kv * sk);
    Vt[((size_t)(head * DHD + dh)) * LQ + l] = f2bf(vv);
}

// ---------------------------------------------------------------------------
// Flash attention (bf16 MFMA). Block = (head, 64 q rows), 4 waves x 16 rows.
// Online softmax in registers; P through per-wave LDS; V pre-transposed.
// ---------------------------------------------------------------------------
__global__ __launch_bounds__(256)
void attn_mfma(const unsigned short* __restrict__ Ag,
               const unsigned short* __restrict__ Bg,
               const unsigned short* __restrict__ Vtg,
               float* __restrict__ T)
{
    int bid = blockIdx.x;
    bid = (bid & 7) * 128 + (bid >> 3);   // XCD swizzle: 16 q-tiles/head share an XCD
    const int head = bid >> 4;            // 0..63
    const int row0 = (bid & 15) * 64;
    const int ns = head >> 3, h = head & 7;
    const int tid = threadIdx.x, w = tid >> 6, lane = tid & 63;
    const int lr = lane & 15, lg = lane >> 4;

    __shared__ unsigned short As[64][136];      // 17408 B (272B stride)
    __shared__ unsigned short Bs[64][136];      // 17408 B
    __shared__ unsigned short Vt[64][72];       // 9216 B
    __shared__ unsigned short Ps[4][16][72];    // 9216 B   (per-wave P tile)

    // stage A once (64 rows x 128 dims bf16)
    {
        const int r = tid >> 2, c0 = (tid & 3) * 32;
        const uint4* src = (const uint4*)&Ag[((size_t)head * LQ + row0 + r) * DE + c0];
        #pragma unroll
        for (int j = 0; j < 4; ++j)
            *(uint4*)&As[r][c0 + 8 * j] = ((const uint4*)src)[j];
    }

    floatx4 o_acc[4] = {};
    float m_r[4], l_r[4];
    #pragma unroll
    for (int r = 0; r < 4; ++r) { m_r[r] = -1e30f; l_r[r] = 0.f; }

    for (int kt = 0; kt < 16; ++kt) {
        {   // stage B tile [64][128]
            const int r = tid >> 2, c0 = (tid & 3) * 32;
            const uint4* src = (const uint4*)&Bg[((size_t)head * LQ + kt * 64 + r) * DE + c0];
            #pragma unroll
            for (int j = 0; j < 4; ++j)
                *(uint4*)&Bs[r][c0 + 8 * j] = ((const uint4*)src)[j];
        }
        {   // stage Vt tile [64 d][64 keys]
            const int d = tid >> 2, k0 = (tid & 3) * 16;
            const uint4* src = (const uint4*)&Vtg[((size_t)(head * DHD + d)) * LQ + kt * 64 + k0];
            *(uint4*)&Vt[d][k0]     = src[0];
            *(uint4*)&Vt[d][k0 + 8] = src[1];
        }
        __syncthreads();

        // ---- QK^T: 16x64 strip per wave ----
        floatx4 s[4] = {};
        #pragma unroll
        for (int ks = 0; ks < 4; ++ks) {
            bf16x8 a = *(const bf16x8*)&As[w * 16 + lr][ks * 32 + lg * 8];
            #pragma unroll
            for (int j = 0; j < 4; ++j) {
                bf16x8 b = *(const bf16x8*)&Bs[j * 16 + lr][ks * 32 + lg * 8];
                s[j] = __builtin_amdgcn_mfma_f32_16x16x32_bf16(a, b, s[j], 0, 0, 0);
            }
        }

        // ---- online softmax (lane holds q = lg*4+r, key = j*16+lr) ----
        #pragma unroll
        for (int r = 0; r < 4; ++r) {
            float tm = fmaxf(fmaxf(s[0][r], s[1][r]), fmaxf(s[2][r], s[3][r]));
            tm = fmaxf(tm, __shfl_xor(tm, 1));
            tm = fmaxf(tm, __shfl_xor(tm, 2));
            tm = fmaxf(tm, __shfl_xor(tm, 4));
            tm = fmaxf(tm, __shfl_xor(tm, 8));
            const float mn = fmaxf(m_r[r], tm);
            const float sc2 = __expf(m_r[r] - mn);
            m_r[r] = mn;
            float ts = 0.f;
            #pragma unroll
            for (int j = 0; j < 4; ++j) {
                float e = __expf(s[j][r] - mn);
                s[j][r] = e;
                ts += e;
            }
            ts += __shfl_xor(ts, 1);
            ts += __shfl_xor(ts, 2);
            ts += __shfl_xor(ts, 4);
            ts += __shfl_xor(ts, 8);
            l_r[r] = l_r[r] * sc2 + ts;
            #pragma unroll
            for (int jd = 0; jd < 4; ++jd) o_acc[jd][r] *= sc2;
        }

        // ---- P -> per-wave LDS (bf16) ----
        #pragma unroll
        for (int j = 0; j < 4; ++j)
            #pragma unroll
            for (int r = 0; r < 4; ++r)
                Ps[w][lg * 4 + r][j * 16 + lr] = f2bf(s[j][r]);

        // ---- PV: O += P @ V ----
        #pragma unroll
        for (int kk = 0; kk < 2; ++kk) {
            bf16x8 p = *(const bf16x8*)&Ps[w][lr][kk * 32 + lg * 8];
            #pragma unroll
            for (int jd = 0; jd < 4; ++jd) {
                bf16x8 v = *(const bf16x8*)&Vt[jd * 16 + lr][kk * 32 + lg * 8];
                o_acc[jd] = __builtin_amdgcn_mfma_f32_16x16x32_bf16(p, v, o_acc[jd], 0, 0, 0);
            }
        }
        __syncthreads();
    }

    // epilogue: divide by softmax denom, write merged-head T (f32)
    #pragma unroll
    for (int jd = 0; jd < 4; ++jd) {
        const int dcol = h * DHD + jd * 16 + lr;
        #pragma unroll
        for (int r = 0; r < 4; ++r) {
            const int q = row0 + w * 16 + lg * 4 + r;
            T[((size_t)ns * LQ + q) * DM + dcol] = o_acc[jd][r] / l_r[r];
        }
    }
}

// ---------------------------------------------------------------------------
// BatchNorm: deterministic two-stage reduction
// ---------------------------------------------------------------------------
__global__ __launch_bounds__(256)
void bn_partial(const float* __restrict__ Y, float* __restrict__ partial)
{
    const int blk = blockIdx.x;
    const int tid = threadIdx.x;
    float s0 = 0, s1 = 0, s20 = 0, s21 = 0;
    const int r0 = blk * 32;
    for (int r2 = 0; r2 < 32; ++r2) {
        const float* row = Y + (size_t)(r0 + r2) * DM;
        float v0 = row[tid];       s0 += v0; s20 += v0 * v0;
        float v1 = row[tid + 256]; s1 += v1; s21 += v1 * v1;
    }
    float* base = partial + (size_t)blk * 1024;
    base[tid]             = s0;
    base[tid + 256]       = s1;
    base[512 + tid]       = s20;
    base[512 + tid + 256] = s21;
}

__global__ __launch_bounds__(256)
void bn_reduce(const float* __restrict__ partial, float* __restrict__ stats)
{
    const int c = blockIdx.x * 256 + threadIdx.x;   // 0..1023
    float s = 0.f;
    for (int b = 0; b < 256; ++b) s += partial[(size_t)b * 1024 + c];
    stats[c] = s;
}

__global__ __launch_bounds__(256)
void bn_final(const float* __restrict__ Y, const float* __restrict__ Qin,
              const float* __restrict__ stats,
              const float* __restrict__ gamma, const float* __restrict__ beta,
              float* __restrict__ out)
{
    const int i = blockIdx.x * 256 + threadIdx.x;
    const int c = i & (DM - 1);
    const float mu  = stats[c] * (1.f / ROWS);
    const float var = stats[512 + c] * (1.f / ROWS) - mu * mu;
    const float rs  = rsqrtf(var + 1e-5f);
    out[i] = Qin[i] + (Y[i] - mu) * rs * gamma[c] + beta[c];
}

// ---------------------------------------------------------------------------
extern "C" void kernel_launch(void* const* d_in, const int* in_sizes, int n_in,
                              void* d_out, int out_size, void* d_ws, size_t ws_size,
                              hipStream_t stream)
{
    (void)in_sizes; (void)n_in; (void)out_size; (void)ws_size;

    const float* Q    = (const float*)d_in[0];
    const float* K    = (const float*)d_in[1];
    const float* Pq   = (const float*)d_in[2];
    const float* Pk   = (const float*)d_in[3];
    const float* Wq   = (const float*)d_in[4];
    const float* bq   = (const float*)d_in[5];
    const float* Wk   = (const float*)d_in[6];
    const float* bk   = (const float*)d_in[7];
    const float* Wv   = (const float*)d_in[8];
    const float* bv   = (const float*)d_in[9];
    const float* Wp   = (const float*)d_in[10];
    const float* bp   = (const float*)d_in[11];
    const float* We   = (const float*)d_in[12];
    const float* be   = (const float*)d_in[13];
    const float* Wc   = (const float*)d_in[14];
    const float* bc   = (const float*)d_in[15];
    const float* gamma= (const float*)d_in[16];
    const float* beta = (const float*)d_in[17];

    char* w8 = (char*)d_ws;
    float* qf           = (float*)(w8);                          // 16 MB
    float* kf           = (float*)(w8 + (16u << 20));            // 16 MB
    float* vf           = (float*)(w8 + (32u << 20));            // 16 MB
    unsigned short* Abf = (unsigned short*)(w8 + (48u << 20));   // 16 MB
    unsigned short* Bbf = (unsigned short*)(w8 + (64u << 20));   // 16 MB
    unsigned short* Vtb = (unsigned short*)(w8 + (80u << 20));   // 8 MB
    float* T     = qf;                                 // reuse after make_ab
    float* H1    = kf;                                 // spans kf+vf (32 MB)
    float* Y     = (float*)(w8 + (48u << 20));         // reuse Abf region
    float* part  = (float*)(w8 + (64u << 20));         // reuse Bbf region
    float* stats = part + 262144;

    dim3 blk256(256);

    // QKV projections (bf16 MFMA, f32 in/out)
    gemm_mfma<<<dim3(8, 128), blk256, 0, stream>>>(Q, Wq, bq, qf, ROWS, DM, DM, 0);
    gemm_mfma<<<dim3(8, 128), blk256, 0, stream>>>(K, Wk, bk, kf, ROWS, DM, DM, 0);
    gemm_mfma<<<dim3(8, 128), blk256, 0, stream>>>(K, Wv, bv, vf, ROWS, DM, DM, 0);

    // phase projection + sin/cos operand build (bf16 out, V transposed)
    make_ab<<<ROWS, 512, 0, stream>>>(Pq, Pk, Wp, bp, qf, kf, vf, Abf, Bbf, Vtb);

    // flash attention (bf16 MFMA)
    attn_mfma<<<1024, blk256, 0, stream>>>(Abf, Bbf, Vtb, T);

    // FFN
    gemm_mfma<<<dim3(16, 128), blk256, 0, stream>>>(T, We, be, H1, ROWS, DM, 2 * DM, 1);
    gemm_mfma<<<dim3(8, 128), blk256, 0, stream>>>(H1, Wc, bc, Y, ROWS, 2 * DM, DM, 0);

    // BatchNorm (training stats) + residual
    bn_partial<<<256, blk256, 0, stream>>>(Y, part);
    bn_reduce<<<4, blk256, 0, stream>>>(part, stats);
    bn_final<<<ROWS * DM / 256, blk256, 0, stream>>>(Y, Q, stats, gamma, beta,
                                                     (float*)d_out);
}

// Round 3
// 224.806 us; speedup vs baseline: 6.2439x; 1.3452x over previous
//
#include <hip/hip_runtime.h>
#include <math.h>

#define LQ 1024      // sequence length L
#define DM 512       // model dim D
#define HN 8         // heads
#define DHD 64       // head dim
#define ROWS 8192    // N*S*L
#define DE 128       // effective attention dim (2*DHD)
#define LOG2E 1.44269504088896f

typedef __attribute__((ext_vector_type(8))) short bf16x8;
typedef __attribute__((ext_vector_type(4))) float floatx4;
typedef unsigned short u16;

static __device__ __forceinline__ u16 f2bf(float x) {
    unsigned int u = __float_as_uint(x);
    u = (u + 0x7fffu + ((u >> 16) & 1u)) >> 16;   // round-nearest-even
    return (u16)u;
}

// async global->LDS 16B copy (dest = wave-uniform base + lane*16, linear)
static __device__ __forceinline__ void gload16(const void* g, void* l) {
    __builtin_amdgcn_global_load_lds((const __attribute__((address_space(1))) void*)g,
                                     (__attribute__((address_space(3))) void*)l,
                                     16, 0, 0);
}

// ---------------------------------------------------------------------------
// f32 -> bf16 cast, 8 elems/thread
// ---------------------------------------------------------------------------
__global__ __launch_bounds__(256)
void cvt_bf16(const float* __restrict__ s, u16* __restrict__ d, int n8)
{
    int i = blockIdx.x * 256 + threadIdx.x;
    if (i >= n8) return;
    const float4* sp = (const float4*)s + 2 * (size_t)i;
    float4 a = sp[0], b = sp[1];
    union { u16 u[8]; uint4 v; } o;
    o.u[0]=f2bf(a.x); o.u[1]=f2bf(a.y); o.u[2]=f2bf(a.z); o.u[3]=f2bf(a.w);
    o.u[4]=f2bf(b.x); o.u[5]=f2bf(b.y); o.u[6]=f2bf(b.z); o.u[7]=f2bf(b.w);
    ((uint4*)d)[i] = o.v;
}

// ---------------------------------------------------------------------------
// bf16 MFMA GEMM, m97-style: 128x128 tile, BK=64, global_load_lds staging,
// linear LDS + XOR swizzle (inverse-swizzled global source).
// C = X @ W^T + bias, optional relu, f32 or bf16 output.
// ---------------------------------------------------------------------------
__global__ __launch_bounds__(256)
void gemm_bf16(const u16* __restrict__ X, const u16* __restrict__ W,
               const float* __restrict__ bias, void* __restrict__ Cout,
               int Kd, int Nn, int relu, int obf)
{
    const int n0 = blockIdx.x * 128, m0 = blockIdx.y * 128;
    const int tid = threadIdx.x;
    const int w = tid >> 6, lane = tid & 63;
    const int lr = lane & 15, lg = lane >> 4;
    const int wm = w >> 1, wn = w & 1;

    __shared__ __align__(16) u16 AsL[128 * 64];
    __shared__ __align__(16) u16 BsL[128 * 64];

    floatx4 acc[4][4] = {};

    const int xorp = (lr & 7) << 4;
    const int colb = lg << 4;

    for (int k0 = 0; k0 < Kd; k0 += 64) {
        #pragma unroll
        for (int r = 0; r < 4; ++r) {
            const int cid = r * 256 + tid;
            const int row = cid >> 3, c16 = cid & 7;
            const int kc = ((c16 ^ (row & 7)) << 3);
            gload16(&X[(size_t)(m0 + row) * Kd + k0 + kc], &AsL[cid * 8]);
        }
        #pragma unroll
        for (int r = 0; r < 4; ++r) {
            const int cid = r * 256 + tid;
            const int row = cid >> 3, c16 = cid & 7;
            const int kc = ((c16 ^ (row & 7)) << 3);
            gload16(&W[(size_t)(n0 + row) * Kd + k0 + kc], &BsL[cid * 8]);
        }
        __syncthreads();

        const char* la = (const char*)AsL;
        const char* lb = (const char*)BsL;
        #pragma unroll
        for (int ks = 0; ks < 2; ++ks) {
            const int cb = (ks * 64 + colb) ^ xorp;
            bf16x8 a[4], b[4];
            #pragma unroll
            for (int i = 0; i < 4; ++i)
                a[i] = *(const bf16x8*)(la + (((wm * 64 + i * 16 + lr) << 7) + cb));
            #pragma unroll
            for (int j = 0; j < 4; ++j)
                b[j] = *(const bf16x8*)(lb + (((wn * 64 + j * 16 + lr) << 7) + cb));
            #pragma unroll
            for (int i = 0; i < 4; ++i)
                #pragma unroll
                for (int j = 0; j < 4; ++j)
                    acc[i][j] = __builtin_amdgcn_mfma_f32_16x16x32_bf16(a[i], b[j], acc[i][j], 0, 0, 0);
        }
        __syncthreads();
    }

    #pragma unroll
    for (int j = 0; j < 4; ++j) {
        const int col = n0 + wn * 64 + j * 16 + lr;
        const float bi = bias[col];
        #pragma unroll
        for (int i = 0; i < 4; ++i) {
            #pragma unroll
            for (int rr = 0; rr < 4; ++rr) {
                const int row = m0 + wm * 64 + i * 16 + lg * 4 + rr;
                float v = acc[i][j][rr] + bi;
                if (relu) v = fmaxf(v, 0.f);
                if (obf) ((u16*)Cout)[(size_t)row * Nn + col] = f2bf(v);
                else     ((float*)Cout)[(size_t)row * Nn + col] = v;
            }
        }
    }
}

// ---------------------------------------------------------------------------
// Build bf16 attention operands (A pre-scaled by log2e for exp2 softmax):
//   A[head,l,0:64]  = q*sin(pq)*log2e,  A[head,l,64:128] = -q*cos(pq)*log2e
//   B[head,l,0:64]  = k*cos(pk-b),      B[head,l,64:128] =  k*sin(pk-b)
//   Vt[head,d,l]    = v   (per-head transposed)
// ---------------------------------------------------------------------------
__global__ __launch_bounds__(512)
void make_ab(const float* __restrict__ Pq, const float* __restrict__ Pk,
             const float* __restrict__ Wp, const float* __restrict__ bp,
             const float* __restrict__ qf, const float* __restrict__ kvf,
             u16* __restrict__ A, u16* __restrict__ B, u16* __restrict__ Vt)
{
    const int row = blockIdx.x;          // ns*1024 + l
    const int d = threadIdx.x;           // 0..511
    const int ns = row >> 10, l = row & 1023;
    const int h = d >> 6, dh = d & 63;
    const int head = ns * HN + h;

    const float p0 = Pq[row * 3 + 0], p1 = Pq[row * 3 + 1], p2 = Pq[row * 3 + 2];
    const float r0 = Pk[row * 3 + 0], r1 = Pk[row * 3 + 1], r2 = Pk[row * 3 + 2];
    const float w0 = Wp[d * 3 + 0], w1 = Wp[d * 3 + 1], w2 = Wp[d * 3 + 2];
    const float bpd = bp[d];

    const float pq   = p0 * w0 + p1 * w1 + p2 * w2 + bpd;
    const float pkmb = r0 * w0 + r1 * w1 + r2 * w2;   // pk - b

    const float qv = qf[(size_t)row * DM + d];
    const float kv = kvf[(size_t)row * 1024 + d];
    const float vv = kvf[(size_t)row * 1024 + 512 + d];

    float sq, cq, sk, ck;
    sincosf(pq, &sq, &cq);
    sincosf(pkmb, &sk, &ck);

    const size_t ab = ((size_t)head * LQ + l) * DE + dh;
    A[ab]      = f2bf(qv * sq * LOG2E);
    A[ab + 64] = f2bf(-qv * cq * LOG2E);
    B[ab]      = f2bf(kv * ck);
    B[ab + 64] = f2bf(kv * sk);
    Vt[((size_t)(head * DHD + dh)) * LQ + l] = f2bf(vv);
}

// ---------------------------------------------------------------------------
// Flash attention, S^T orientation: st = mfma(K_frag, Q_frag) puts all 16
// keys of one q-row in a single lane -> softmax = in-reg reduce + 2 shuffles.
// global_load_lds staging with XOR swizzle; P via packed per-wave LDS.
// ---------------------------------------------------------------------------
__global__ __launch_bounds__(256)
void attn_mfma(const u16* __restrict__ Ag, const u16* __restrict__ Bg,
               const u16* __restrict__ Vtg, u16* __restrict__ Tbf)
{
    int bid = blockIdx.x;
    bid = (bid & 7) * 128 + (bid >> 3);   // XCD swizzle (1024 % 8 == 0)
    const int head = bid >> 4;            // 0..63
    const int row0 = (bid & 15) * 64;
    const int ns = head >> 3, h = head & 7;
    const int tid = threadIdx.x, w = tid >> 6, lane = tid & 63;
    const int lr = lane & 15, lg = lane >> 4;

    __shared__ __align__(16) u16 AsL[64 * 128];   // 16 KB
    __shared__ __align__(16) u16 BsL[64 * 128];   // 16 KB
    __shared__ __align__(16) u16 VtL[64 * 64];    //  8 KB
    __shared__ __align__(16) u16 Ps[4][16][72];   //  9 KB (per-wave P tiles)

    // stage A once (64 q-rows x 128)
    #pragma unroll
    for (int r = 0; r < 4; ++r) {
        const int cid = r * 256 + tid;
        const int row = cid >> 4, c16 = cid & 15;
        const int kc = ((c16 ^ (row & 7)) << 3);
        gload16(&Ag[((size_t)head * LQ + row0 + row) * DE + kc], &AsL[cid * 8]);
    }

    floatx4 o0 = {}, o1 = {}, o2 = {}, o3 = {};
    float m_ = -1e30f, l_ = 0.f;

    const int xorp = (lr & 7) << 4;
    const int colb = lg << 4;

    for (int kt = 0; kt < 16; ++kt) {
        #pragma unroll
        for (int r = 0; r < 4; ++r) {           // B tile: keys kt*64..+63
            const int cid = r * 256 + tid;
            const int row = cid >> 4, c16 = cid & 15;
            const int kc = ((c16 ^ (row & 7)) << 3);
            gload16(&Bg[((size_t)head * LQ + kt * 64 + row) * DE + kc], &BsL[cid * 8]);
        }
        #pragma unroll
        for (int r = 0; r < 2; ++r) {           // Vt tile: [64 d][64 keys]
            const int cid = r * 256 + tid;
            const int row = cid >> 3, c16 = cid & 7;
            const int kc = ((c16 ^ (row & 7)) << 3);
            gload16(&Vtg[((size_t)head * DHD + row) * LQ + kt * 64 + kc], &VtL[cid * 8]);
        }
        __syncthreads();

        const char* la = (const char*)AsL;
        const char* lbs = (const char*)BsL;
        const char* lv = (const char*)VtL;

        // ---- S^T = K-rows x Q-cols: lane holds 16 keys for q = w*16+lr ----
        floatx4 st[4] = {};
        #pragma unroll
        for (int ks = 0; ks < 4; ++ks) {
            const int cb = (ks * 64 + colb) ^ xorp;
            bf16x8 qfrag = *(const bf16x8*)(la + (((w * 16 + lr) << 8) + cb));
            #pragma unroll
            for (int j = 0; j < 4; ++j) {
                bf16x8 kfrag = *(const bf16x8*)(lbs + (((j * 16 + lr) << 8) + cb));
                st[j] = __builtin_amdgcn_mfma_f32_16x16x32_bf16(kfrag, qfrag, st[j], 0, 0, 0);
            }
        }

        // ---- online softmax (base-2; A pre-scaled by log2e) ----
        float tm = -1e30f;
        #pragma unroll
        for (int j = 0; j < 4; ++j)
            #pragma unroll
            for (int r = 0; r < 4; ++r) tm = fmaxf(tm, st[j][r]);
        tm = fmaxf(tm, __shfl_xor(tm, 16));
        tm = fmaxf(tm, __shfl_xor(tm, 32));
        const float mn = fmaxf(m_, tm);
        const float sc2 = exp2f(m_ - mn);
        m_ = mn;
        float ts = 0.f;
        #pragma unroll
        for (int j = 0; j < 4; ++j)
            #pragma unroll
            for (int r = 0; r < 4; ++r) {
                float e = exp2f(st[j][r] - mn);
                st[j][r] = e;
                ts += e;
            }
        ts += __shfl_xor(ts, 16);
        ts += __shfl_xor(ts, 32);
        l_ = l_ * sc2 + ts;
        o0 *= sc2; o1 *= sc2; o2 *= sc2; o3 *= sc2;

        // ---- P -> per-wave LDS, row q=lr, packed 4 keys per write ----
        #pragma unroll
        for (int j = 0; j < 4; ++j) {
            union { u16 u[4]; uint2 v; } pk;
            pk.u[0] = f2bf(st[j][0]); pk.u[1] = f2bf(st[j][1]);
            pk.u[2] = f2bf(st[j][2]); pk.u[3] = f2bf(st[j][3]);
            *(uint2*)&Ps[w][lr][j * 16 + lg * 4] = pk.v;
        }

        // ---- PV: O^T[d][q] += Vt[d][k] * P^T[k][q] ----
        #pragma unroll
        for (int ks2 = 0; ks2 < 2; ++ks2) {
            bf16x8 pfrag = *(const bf16x8*)&Ps[w][lr][ks2 * 32 + lg * 8];
            const int cb = (ks2 * 64 + colb) ^ xorp;
            bf16x8 vf0 = *(const bf16x8*)(lv + (((0 + lr) << 7) + cb));
            o0 = __builtin_amdgcn_mfma_f32_16x16x32_bf16(vf0, pfrag, o0, 0, 0, 0);
            bf16x8 vf1 = *(const bf16x8*)(lv + (((16 + lr) << 7) + cb));
            o1 = __builtin_amdgcn_mfma_f32_16x16x32_bf16(vf1, pfrag, o1, 0, 0, 0);
            bf16x8 vf2 = *(const bf16x8*)(lv + (((32 + lr) << 7) + cb));
            o2 = __builtin_amdgcn_mfma_f32_16x16x32_bf16(vf2, pfrag, o2, 0, 0, 0);
            bf16x8 vf3 = *(const bf16x8*)(lv + (((48 + lr) << 7) + cb));
            o3 = __builtin_amdgcn_mfma_f32_16x16x32_bf16(vf3, pfrag, o3, 0, 0, 0);
        }
        __syncthreads();
    }

    // epilogue: normalize, write merged-head T (bf16)
    const float inv = 1.f / l_;
    const size_t trow = ((size_t)ns * LQ + row0 + w * 16 + lr) * DM + h * DHD;
    floatx4 oo[4] = { o0, o1, o2, o3 };
    #pragma unroll
    for (int jd = 0; jd < 4; ++jd) {
        union { u16 u[4]; uint2 v; } pk;
        pk.u[0] = f2bf(oo[jd][0] * inv); pk.u[1] = f2bf(oo[jd][1] * inv);
        pk.u[2] = f2bf(oo[jd][2] * inv); pk.u[3] = f2bf(oo[jd][3] * inv);
        *(uint2*)&Tbf[trow + jd * 16 + lg * 4] = pk.v;
    }
}

// ---------------------------------------------------------------------------
// BatchNorm: deterministic two-stage reduction
// ---------------------------------------------------------------------------
__global__ __launch_bounds__(256)
void bn_partial(const float* __restrict__ Y, float* __restrict__ partial)
{
    const int blk = blockIdx.x;
    const int tid = threadIdx.x;
    float s0 = 0, s1 = 0, s20 = 0, s21 = 0;
    const int r0 = blk * 32;
    for (int r2 = 0; r2 < 32; ++r2) {
        const float* row = Y + (size_t)(r0 + r2) * DM;
        float v0 = row[tid];       s0 += v0; s20 += v0 * v0;
        float v1 = row[tid + 256]; s1 += v1; s21 += v1 * v1;
    }
    float* base = partial + (size_t)blk * 1024;
    base[tid]             = s0;
    base[tid + 256]       = s1;
    base[512 + tid]       = s20;
    base[512 + tid + 256] = s21;
}

__global__ __launch_bounds__(256)
void bn_reduce(const float* __restrict__ partial, float* __restrict__ stats)
{
    const int c = blockIdx.x * 256 + threadIdx.x;   // 0..1023
    float s = 0.f;
    for (int b = 0; b < 256; ++b) s += partial[(size_t)b * 1024 + c];
    stats[c] = s;
}

__global__ __launch_bounds__(256)
void bn_final(const float* __restrict__ Y, const float* __restrict__ Qin,
              const float* __restrict__ stats,
              const float* __restrict__ gamma, const float* __restrict__ beta,
              float* __restrict__ out)
{
    const int i = blockIdx.x * 256 + threadIdx.x;
    const int c = i & (DM - 1);
    const float mu  = stats[c] * (1.f / ROWS);
    const float var = stats[512 + c] * (1.f / ROWS) - mu * mu;
    const float rs  = rsqrtf(var + 1e-5f);
    out[i] = Qin[i] + (Y[i] - mu) * rs * gamma[c] + beta[c];
}

// ---------------------------------------------------------------------------
extern "C" void kernel_launch(void* const* d_in, const int* in_sizes, int n_in,
                              void* d_out, int out_size, void* d_ws, size_t ws_size,
                              hipStream_t stream)
{
    (void)in_sizes; (void)n_in; (void)out_size; (void)ws_size;

    const float* Q    = (const float*)d_in[0];
    const float* K    = (const float*)d_in[1];
    const float* Pq   = (const float*)d_in[2];
    const float* Pk   = (const float*)d_in[3];
    const float* Wq   = (const float*)d_in[4];
    const float* bq   = (const float*)d_in[5];
    const float* Wk   = (const float*)d_in[6];
    const float* bk   = (const float*)d_in[7];
    const float* Wv   = (const float*)d_in[8];
    const float* bv   = (const float*)d_in[9];
    const float* Wp   = (const float*)d_in[10];
    const float* bp   = (const float*)d_in[11];
    const float* We   = (const float*)d_in[12];
    const float* be   = (const float*)d_in[13];
    const float* Wc   = (const float*)d_in[14];
    const float* bc   = (const float*)d_in[15];
    const float* gamma= (const float*)d_in[16];
    const float* beta = (const float*)d_in[17];

    const size_t MB = 1u << 20;
    char* w8 = (char*)d_ws;
    float* qf    = (float*)(w8);                 // 16 MB  (later: Y)
    float* kvf   = (float*)(w8 + 16 * MB);       // 32 MB  (later: part/stats)
    u16*  Abf    = (u16*)(w8 + 48 * MB);         // 17 MB  (later: H1b)
    u16*  Bbf    = (u16*)(w8 + 65 * MB);         // 17 MB
    u16*  Vtb    = (u16*)(w8 + 82 * MB);         //  9 MB
    u16*  Tbf    = (u16*)(w8 + 91 * MB);         //  9 MB
    u16*  Qbf    = (u16*)(w8 + 100 * MB);        //  9 MB
    u16*  Kbf    = (u16*)(w8 + 109 * MB);        //  9 MB
    u16*  Wqb    = (u16*)(w8 + 118 * MB);                  // 512 KB
    u16*  Wkvb   = (u16*)(w8 + 118 * MB + 512 * 1024);     // 1 MB (Wk;Wv)
    u16*  Web    = (u16*)(w8 + 118 * MB + 1536 * 1024);    // 1 MB
    u16*  Wcb    = (u16*)(w8 + 118 * MB + 2560 * 1024);    // 1 MB
    float* bkv   = (float*)(w8 + 118 * MB + 3584 * 1024);  // 4 KB ([bk;bv])
    float* Y     = qf;
    u16*  H1b    = Abf;
    float* part  = kvf;
    float* stats = kvf + 262144;

    dim3 blk256(256);

    // bf16 casts
    cvt_bf16<<<2048, blk256, 0, stream>>>(Q,  Qbf, 524288);
    cvt_bf16<<<2048, blk256, 0, stream>>>(K,  Kbf, 524288);
    cvt_bf16<<<128,  blk256, 0, stream>>>(Wq, Wqb, 32768);
    cvt_bf16<<<128,  blk256, 0, stream>>>(Wk, Wkvb, 32768);
    cvt_bf16<<<128,  blk256, 0, stream>>>(Wv, Wkvb + 262144, 32768);
    cvt_bf16<<<256,  blk256, 0, stream>>>(We, Web, 65536);
    cvt_bf16<<<256,  blk256, 0, stream>>>(Wc, Wcb, 65536);
    hipMemcpyAsync(bkv,       bk, 512 * sizeof(float), hipMemcpyDeviceToDevice, stream);
    hipMemcpyAsync(bkv + 512, bv, 512 * sizeof(float), hipMemcpyDeviceToDevice, stream);

    // projections: Q-proj (N=512) and fused KV-proj (N=1024)
    gemm_bf16<<<dim3(4, 64), blk256, 0, stream>>>(Qbf, Wqb,  bq,  qf,  DM, DM, 0, 0);
    gemm_bf16<<<dim3(8, 64), blk256, 0, stream>>>(Kbf, Wkvb, bkv, kvf, DM, 2 * DM, 0, 0);

    // phase projection + sin/cos operand build
    make_ab<<<ROWS, 512, 0, stream>>>(Pq, Pk, Wp, bp, qf, kvf, Abf, Bbf, Vtb);

    // flash attention
    attn_mfma<<<1024, blk256, 0, stream>>>(Abf, Bbf, Vtb, Tbf);

    // FFN (bf16 chain), final output f32
    gemm_bf16<<<dim3(8, 64), blk256, 0, stream>>>(Tbf, Web, be, H1b, DM, 2 * DM, 1, 1);
    gemm_bf16<<<dim3(4, 64), blk256, 0, stream>>>(H1b, Wcb, bc, Y, 2 * DM, DM, 0, 0);

    // BatchNorm (training stats) + residual
    bn_partial<<<256, blk256, 0, stream>>>(Y, part);
    bn_reduce<<<4, blk256, 0, stream>>>(part, stats);
    bn_final<<<ROWS * DM / 256, blk256, 0, stream>>>(Y, Q, stats, gamma, beta,
                                                     (float*)d_out);
}

// Round 4
// 191.665 us; speedup vs baseline: 7.3236x; 1.1729x over previous
//
#include <hip/hip_runtime.h>
#include <math.h>

#define LQ 1024      // sequence length L
#define DM 512       // model dim D
#define HN 8         // heads
#define DHD 64       // head dim
#define ROWS 8192    // N*S*L
#define DE 128       // effective attention dim (2*DHD)
#define LOG2E 1.44269504088896f

typedef __attribute__((ext_vector_type(8))) short bf16x8;
typedef __attribute__((ext_vector_type(4))) float floatx4;
typedef unsigned short u16;

static __device__ __forceinline__ u16 f2bf(float x) {
    unsigned int u = __float_as_uint(x);
    u = (u + 0x7fffu + ((u >> 16) & 1u)) >> 16;   // round-nearest-even
    return (u16)u;
}

static __device__ __forceinline__ void gload16(const void* g, void* l) {
    __builtin_amdgcn_global_load_lds((const __attribute__((address_space(1))) void*)g,
                                     (__attribute__((address_space(3))) void*)l,
                                     16, 0, 0);
}

static __device__ __forceinline__ void cvt8(const float* s, u16* d, size_t o) {
    const float4* sp = (const float4*)s + 2 * o;
    float4 a = sp[0], b = sp[1];
    union { u16 u[8]; uint4 v; } ov;
    ov.u[0]=f2bf(a.x); ov.u[1]=f2bf(a.y); ov.u[2]=f2bf(a.z); ov.u[3]=f2bf(a.w);
    ov.u[4]=f2bf(b.x); ov.u[5]=f2bf(b.y); ov.u[6]=f2bf(b.z); ov.u[7]=f2bf(b.w);
    ((uint4*)d)[o] = ov.v;
}

// ---------------------------------------------------------------------------
// fused weight casts: Wq, Wk, Wv (concat), We, Wc  (one dispatch)
// ---------------------------------------------------------------------------
__global__ __launch_bounds__(256)
void wcast(const float* __restrict__ Wq, const float* __restrict__ Wk,
           const float* __restrict__ Wv, const float* __restrict__ We,
           const float* __restrict__ Wc,
           u16* __restrict__ Wqb, u16* __restrict__ Wkvb,
           u16* __restrict__ Web, u16* __restrict__ Wcb)
{
    int i = blockIdx.x * 256 + threadIdx.x;      // vec8 id, total 229376
    const float* s; u16* d; int o;
    if (i < 32768)        { s = Wq; d = Wqb;            o = i; }
    else if (i < 65536)   { s = Wk; d = Wkvb;           o = i - 32768; }
    else if (i < 98304)   { s = Wv; d = Wkvb + 262144;  o = i - 65536; }
    else if (i < 163840)  { s = We; d = Web;            o = i - 98304; }
    else                  { s = Wc; d = Wcb;            o = i - 163840; }
    cvt8(s, d, (size_t)o);
}

// Q and K input casts (one dispatch)
__global__ __launch_bounds__(256)
void qkcast(const float* __restrict__ Q, const float* __restrict__ K,
            u16* __restrict__ Qb, u16* __restrict__ Kb)
{
    int i = blockIdx.x * 256 + threadIdx.x;      // vec8 id, total 1048576
    const float* s = Q; u16* d = Qb; int o = i;
    if (i >= 524288) { s = K; d = Kb; o = i - 524288; }
    cvt8(s, d, (size_t)o);
}

// ---------------------------------------------------------------------------
// bf16 MFMA GEMM, 128x128 tile, BK=64, 2-phase double-buffered
// global_load_lds staging w/ XOR swizzle.
// MODE 0: f32 out + bias            MODE 1: bf16 out + bias + relu
// MODE 2: Q-proj -> A (sin/cos, log2e folded)
// MODE 3: KV-proj -> B (cols<512, sin/cos) and Vt (cols>=512, transposed)
// ---------------------------------------------------------------------------
template<int MODE>
__global__ __launch_bounds__(256)
void gemm_k(const u16* __restrict__ X, const u16* __restrict__ W,
            const float* __restrict__ bias, const float* __restrict__ bias2,
            void* __restrict__ out, u16* __restrict__ out2,
            const float* __restrict__ Pph, const float* __restrict__ Wp,
            const float* __restrict__ bp, int Kd, int Nn)
{
    const int n0 = blockIdx.x * 128, m0 = blockIdx.y * 128;
    const int tid = threadIdx.x;
    const int w = tid >> 6, lane = tid & 63;
    const int lr = lane & 15, lg = lane >> 4;
    const int wm = w >> 1, wn = w & 1;

    __shared__ __align__(16) u16 AsL[2][128 * 64];
    __shared__ __align__(16) u16 BsL[2][128 * 64];

    floatx4 acc[4][4] = {};
    const int xorp = (lr & 7) << 4;
    const int colb = lg << 4;

    const int s_row = tid >> 3, s_c16 = tid & 7;
    (void)s_row; (void)s_c16;

    auto stage = [&](int t, int b) {
        const size_t ko = (size_t)t * 64;
        #pragma unroll
        for (int r = 0; r < 4; ++r) {
            const int cid = r * 256 + tid;
            const int row = cid >> 3, c16 = cid & 7;
            const int kc = ((c16 ^ (row & 7)) << 3);
            gload16(&X[(size_t)(m0 + row) * Kd + ko + kc], &AsL[b][cid * 8]);
        }
        #pragma unroll
        for (int r = 0; r < 4; ++r) {
            const int cid = r * 256 + tid;
            const int row = cid >> 3, c16 = cid & 7;
            const int kc = ((c16 ^ (row & 7)) << 3);
            gload16(&W[(size_t)(n0 + row) * Kd + ko + kc], &BsL[b][cid * 8]);
        }
    };

    const int nt = Kd >> 6;
    stage(0, 0);
    __syncthreads();
    int c = 0;
    for (int t = 0; t < nt; ++t) {
        if (t + 1 < nt) stage(t + 1, c ^ 1);
        const char* la = (const char*)AsL[c];
        const char* lb = (const char*)BsL[c];
        #pragma unroll
        for (int ks = 0; ks < 2; ++ks) {
            const int cb = (ks * 64 + colb) ^ xorp;
            bf16x8 a[4], b[4];
            #pragma unroll
            for (int i = 0; i < 4; ++i)
                a[i] = *(const bf16x8*)(la + (((wm * 64 + i * 16 + lr) << 7) + cb));
            #pragma unroll
            for (int j = 0; j < 4; ++j)
                b[j] = *(const bf16x8*)(lb + (((wn * 64 + j * 16 + lr) << 7) + cb));
            #pragma unroll
            for (int i = 0; i < 4; ++i)
                #pragma unroll
                for (int j = 0; j < 4; ++j)
                    acc[i][j] = __builtin_amdgcn_mfma_f32_16x16x32_bf16(a[i], b[j], acc[i][j], 0, 0, 0);
        }
        __syncthreads();
        c ^= 1;
    }

    if (MODE <= 1) {
        #pragma unroll
        for (int j = 0; j < 4; ++j) {
            const int col = n0 + wn * 64 + j * 16 + lr;
            const float bi = bias[col];
            #pragma unroll
            for (int i = 0; i < 4; ++i)
                #pragma unroll
                for (int rr = 0; rr < 4; ++rr) {
                    const int row = m0 + wm * 64 + i * 16 + lg * 4 + rr;
                    float v = acc[i][j][rr] + bi;
                    if (MODE == 1) {
                        v = fmaxf(v, 0.f);
                        ((u16*)out)[(size_t)row * Nn + col] = f2bf(v);
                    } else {
                        ((float*)out)[(size_t)row * Nn + col] = v;
                    }
                }
        }
    } else if (MODE == 2) {
        u16* A = (u16*)out;
        #pragma unroll
        for (int j = 0; j < 4; ++j) {
            const int col = n0 + wn * 64 + j * 16 + lr;
            const float w0 = Wp[col * 3], w1 = Wp[col * 3 + 1], w2 = Wp[col * 3 + 2];
            const float bpd = bp[col], bi = bias[col];
            const int hh = col >> 6, dh = col & 63;
            #pragma unroll
            for (int i = 0; i < 4; ++i)
                #pragma unroll
                for (int rr = 0; rr < 4; ++rr) {
                    const int row = m0 + wm * 64 + i * 16 + lg * 4 + rr;
                    const int ns = row >> 10, l = row & 1023;
                    const float p = Pph[row * 3] * w0 + Pph[row * 3 + 1] * w1
                                  + Pph[row * 3 + 2] * w2 + bpd;
                    float sn, cs;
                    __sincosf(p, &sn, &cs);
                    const float v = acc[i][j][rr] + bi;
                    const size_t e = (((size_t)(ns * HN + hh)) * LQ + l) * DE + dh;
                    A[e]      = f2bf(v * sn * LOG2E);
                    A[e + 64] = f2bf(-v * cs * LOG2E);
                }
        }
    } else {   // MODE 3
        if (n0 < 512) {     // K half -> B with phases
            u16* B = (u16*)out;
            #pragma unroll
            for (int j = 0; j < 4; ++j) {
                const int col = n0 + wn * 64 + j * 16 + lr;
                const float w0 = Wp[col * 3], w1 = Wp[col * 3 + 1], w2 = Wp[col * 3 + 2];
                const float bi = bias[col];
                const int hh = col >> 6, dh = col & 63;
                #pragma unroll
                for (int i = 0; i < 4; ++i)
                    #pragma unroll
                    for (int rr = 0; rr < 4; ++rr) {
                        const int row = m0 + wm * 64 + i * 16 + lg * 4 + rr;
                        const int ns = row >> 10, l = row & 1023;
                        const float p = Pph[row * 3] * w0 + Pph[row * 3 + 1] * w1
                                      + Pph[row * 3 + 2] * w2;      // pk - b
                        float sn, cs;
                        __sincosf(p, &sn, &cs);
                        const float v = acc[i][j][rr] + bi;
                        const size_t e = (((size_t)(ns * HN + hh)) * LQ + l) * DE + dh;
                        B[e]      = f2bf(v * cs);
                        B[e + 64] = f2bf(v * sn);
                    }
            }
        } else {            // V half -> Vt (per-head transposed)
            u16* Vt = out2;
            #pragma unroll
            for (int j = 0; j < 4; ++j) {
                const int col = n0 + wn * 64 + j * 16 + lr;
                const int c2 = col - 512;
                const float bi = bias2[c2];
                const int hh = c2 >> 6, dh = c2 & 63;
                #pragma unroll
                for (int i = 0; i < 4; ++i)
                    #pragma unroll
                    for (int rr = 0; rr < 4; ++rr) {
                        const int row = m0 + wm * 64 + i * 16 + lg * 4 + rr;
                        const int ns = row >> 10, l = row & 1023;
                        const float v = acc[i][j][rr] + bi;
                        Vt[((size_t)((ns * HN + hh) * DHD + dh)) * LQ + l] = f2bf(v);
                    }
            }
        }
    }
}

// ---------------------------------------------------------------------------
// Flash attention, S^T orientation, no-max softmax (Cauchy-Schwarz-bounded),
// 2-phase double-buffered staging, cvt_pk P-pack.
// ---------------------------------------------------------------------------
__global__ __launch_bounds__(256)
void attn_mfma(const u16* __restrict__ Ag, const u16* __restrict__ Bg,
               const u16* __restrict__ Vtg, u16* __restrict__ Tbf)
{
    int bid = blockIdx.x;
    bid = (bid & 7) * 128 + (bid >> 3);   // XCD swizzle (1024 % 8 == 0)
    const int head = bid >> 4;            // 0..63
    const int row0 = (bid & 15) * 64;
    const int ns = head >> 3, h = head & 7;
    const int tid = threadIdx.x, w = tid >> 6, lane = tid & 63;
    const int lr = lane & 15, lg = lane >> 4;

    __shared__ __align__(16) u16 AsL[64 * 128];      // 16 KB
    __shared__ __align__(16) u16 BsL[2][64 * 128];   // 32 KB
    __shared__ __align__(16) u16 VtL[2][64 * 64];    // 16 KB
    __shared__ __align__(16) u16 Ps[4][16][72];      //  9 KB

    // stage A once
    #pragma unroll
    for (int r = 0; r < 4; ++r) {
        const int cid = r * 256 + tid;
        const int row = cid >> 4, c16 = cid & 15;
        const int kc = ((c16 ^ (row & 7)) << 3);
        gload16(&Ag[((size_t)head * LQ + row0 + row) * DE + kc], &AsL[cid * 8]);
    }
    auto stageBV = [&](int kt, int b) {
        #pragma unroll
        for (int r = 0; r < 4; ++r) {
            const int cid = r * 256 + tid;
            const int row = cid >> 4, c16 = cid & 15;
            const int kc = ((c16 ^ (row & 7)) << 3);
            gload16(&Bg[((size_t)head * LQ + kt * 64 + row) * DE + kc], &BsL[b][cid * 8]);
        }
        #pragma unroll
        for (int r = 0; r < 2; ++r) {
            const int cid = r * 256 + tid;
            const int row = cid >> 3, c16 = cid & 7;
            const int kc = ((c16 ^ (row & 7)) << 3);
            gload16(&Vtg[((size_t)head * DHD + row) * LQ + kt * 64 + kc], &VtL[b][cid * 8]);
        }
    };
    stageBV(0, 0);
    __syncthreads();

    floatx4 o0 = {}, o1 = {}, o2 = {}, o3 = {};
    float lsum = 0.f;
    const int xorp = (lr & 7) << 4;
    const int colb = lg << 4;
    int c = 0;

    for (int kt = 0; kt < 16; ++kt) {
        if (kt < 15) stageBV(kt + 1, c ^ 1);      // prefetch next tile

        const char* la = (const char*)AsL;
        const char* lb = (const char*)BsL[c];
        const char* lv = (const char*)VtL[c];

        // ---- S^T = K-rows x Q-cols ----
        floatx4 st[4] = {};
        __builtin_amdgcn_s_setprio(1);
        #pragma unroll
        for (int ks = 0; ks < 4; ++ks) {
            const int cb = (ks * 64 + colb) ^ xorp;
            bf16x8 qfrag = *(const bf16x8*)(la + (((w * 16 + lr) << 8) + cb));
            #pragma unroll
            for (int j = 0; j < 4; ++j) {
                bf16x8 kfrag = *(const bf16x8*)(lb + (((j * 16 + lr) << 8) + cb));
                st[j] = __builtin_amdgcn_mfma_f32_16x16x32_bf16(kfrag, qfrag, st[j], 0, 0, 0);
            }
        }
        __builtin_amdgcn_s_setprio(0);

        // ---- no-max softmax: P = exp2(S), per-lane partial denominator ----
        float ts = 0.f;
        #pragma unroll
        for (int j = 0; j < 4; ++j)
            #pragma unroll
            for (int r = 0; r < 4; ++r) {
                const float e = exp2f(st[j][r]);
                st[j][r] = e;
                ts += e;
            }
        lsum += ts;

        // ---- P -> per-wave LDS (cvt_pk pack) ----
        #pragma unroll
        for (int j = 0; j < 4; ++j) {
            unsigned plo, phi;
            asm("v_cvt_pk_bf16_f32 %0, %1, %2" : "=v"(plo) : "v"(st[j][0]), "v"(st[j][1]));
            asm("v_cvt_pk_bf16_f32 %0, %1, %2" : "=v"(phi) : "v"(st[j][2]), "v"(st[j][3]));
            uint2 pv2; pv2.x = plo; pv2.y = phi;
            *(uint2*)&Ps[w][lr][j * 16 + lg * 4] = pv2;
        }

        // ---- PV: O^T[d][q] += Vt[d][k] * P^T[k][q] ----
        __builtin_amdgcn_s_setprio(1);
        #pragma unroll
        for (int ks2 = 0; ks2 < 2; ++ks2) {
            bf16x8 pf = *(const bf16x8*)&Ps[w][lr][ks2 * 32 + lg * 8];
            const int cb = (ks2 * 64 + colb) ^ xorp;
            bf16x8 v0 = *(const bf16x8*)(lv + (((0  + lr) << 7) + cb));
            o0 = __builtin_amdgcn_mfma_f32_16x16x32_bf16(v0, pf, o0, 0, 0, 0);
            bf16x8 v1 = *(const bf16x8*)(lv + (((16 + lr) << 7) + cb));
            o1 = __builtin_amdgcn_mfma_f32_16x16x32_bf16(v1, pf, o1, 0, 0, 0);
            bf16x8 v2 = *(const bf16x8*)(lv + (((32 + lr) << 7) + cb));
            o2 = __builtin_amdgcn_mfma_f32_16x16x32_bf16(v2, pf, o2, 0, 0, 0);
            bf16x8 v3 = *(const bf16x8*)(lv + (((48 + lr) << 7) + cb));
            o3 = __builtin_amdgcn_mfma_f32_16x16x32_bf16(v3, pf, o3, 0, 0, 0);
        }
        __builtin_amdgcn_s_setprio(0);
        __syncthreads();
        c ^= 1;
    }

    // denominator reduce (once), normalize, write merged-head T (bf16)
    lsum += __shfl_xor(lsum, 16);
    lsum += __shfl_xor(lsum, 32);
    const float inv = 1.f / lsum;
    const size_t trow = ((size_t)ns * LQ + row0 + w * 16 + lr) * DM + h * DHD;
    floatx4 oo[4] = { o0, o1, o2, o3 };
    #pragma unroll
    for (int jd = 0; jd < 4; ++jd) {
        union { u16 u[4]; uint2 v; } pk;
        pk.u[0] = f2bf(oo[jd][0] * inv); pk.u[1] = f2bf(oo[jd][1] * inv);
        pk.u[2] = f2bf(oo[jd][2] * inv); pk.u[3] = f2bf(oo[jd][3] * inv);
        *(uint2*)&Tbf[trow + jd * 16 + lg * 4] = pk.v;
    }
}

// ---------------------------------------------------------------------------
// BatchNorm: deterministic two-stage reduction
// ---------------------------------------------------------------------------
__global__ __launch_bounds__(256)
void bn_partial(const float* __restrict__ Y, float* __restrict__ partial)
{
    const int blk = blockIdx.x;
    const int tid = threadIdx.x;
    float s0 = 0, s1 = 0, s20 = 0, s21 = 0;
    const int r0 = blk * 32;
    for (int r2 = 0; r2 < 32; ++r2) {
        const float* row = Y + (size_t)(r0 + r2) * DM;
        float v0 = row[tid];       s0 += v0; s20 += v0 * v0;
        float v1 = row[tid + 256]; s1 += v1; s21 += v1 * v1;
    }
    float* base = partial + (size_t)blk * 1024;
    base[tid]             = s0;
    base[tid + 256]       = s1;
    base[512 + tid]       = s20;
    base[512 + tid + 256] = s21;
}

__global__ __launch_bounds__(256)
void bn_reduce(const float* __restrict__ partial, float* __restrict__ stats)
{
    const int c = blockIdx.x * 256 + threadIdx.x;   // 0..1023
    float s = 0.f;
    for (int b = 0; b < 256; ++b) s += partial[(size_t)b * 1024 + c];
    stats[c] = s;
}

__global__ __launch_bounds__(256)
void bn_final(const float* __restrict__ Y, const float* __restrict__ Qin,
              const float* __restrict__ stats,
              const float* __restrict__ gamma, const float* __restrict__ beta,
              float* __restrict__ out)
{
    const int i = blockIdx.x * 256 + threadIdx.x;
    const int c = i & (DM - 1);
    const float mu  = stats[c] * (1.f / ROWS);
    const float var = stats[512 + c] * (1.f / ROWS) - mu * mu;
    const float rs  = rsqrtf(var + 1e-5f);
    out[i] = Qin[i] + (Y[i] - mu) * rs * gamma[c] + beta[c];
}

// ---------------------------------------------------------------------------
extern "C" void kernel_launch(void* const* d_in, const int* in_sizes, int n_in,
                              void* d_out, int out_size, void* d_ws, size_t ws_size,
                              hipStream_t stream)
{
    (void)in_sizes; (void)n_in; (void)out_size; (void)ws_size;

    const float* Q    = (const float*)d_in[0];
    const float* K    = (const float*)d_in[1];
    const float* Pq   = (const float*)d_in[2];
    const float* Pk   = (const float*)d_in[3];
    const float* Wq   = (const float*)d_in[4];
    const float* bq   = (const float*)d_in[5];
    const float* Wk   = (const float*)d_in[6];
    const float* bk   = (const float*)d_in[7];
    const float* Wv   = (const float*)d_in[8];
    const float* bv   = (const float*)d_in[9];
    const float* Wp   = (const float*)d_in[10];
    const float* bp   = (const float*)d_in[11];
    const float* We   = (const float*)d_in[12];
    const float* be   = (const float*)d_in[13];
    const float* Wc   = (const float*)d_in[14];
    const float* bc   = (const float*)d_in[15];
    const float* gamma= (const float*)d_in[16];
    const float* beta = (const float*)d_in[17];

    const size_t MB = 1u << 20;
    char* w8 = (char*)d_ws;
    u16*  Abf  = (u16*)(w8);                  // 16 MB (A: 64x1024x128)
    u16*  Bbf  = (u16*)(w8 + 16 * MB);        // 16 MB
    u16*  Vtb  = (u16*)(w8 + 32 * MB);        //  8 MB
    u16*  Tbf  = (u16*)(w8 + 40 * MB);        //  8 MB
    u16*  Qbf  = (u16*)(w8 + 48 * MB);        //  8 MB  } reused as H1b
    u16*  Kbf  = (u16*)(w8 + 56 * MB);        //  8 MB  }
    u16*  H1b  = (u16*)(w8 + 48 * MB);        // 16 MB (after Q/K dead)
    float* Y   = (float*)(w8);                // 16 MB (reuses Abf after attn)
    float* part  = (float*)(w8 + 16 * MB);    //  1 MB (reuses Bbf)
    float* stats = (float*)(w8 + 17 * MB);    //  4 KB
    u16*  Wqb  = (u16*)(w8 + 64 * MB);                    // 0.5 MB
    u16*  Wkvb = (u16*)(w8 + 64 * MB + 512 * 1024);       // 1 MB
    u16*  Web  = (u16*)(w8 + 64 * MB + 1536 * 1024);      // 1 MB
    u16*  Wcb  = (u16*)(w8 + 64 * MB + 2560 * 1024);      // 1 MB

    dim3 blk256(256);

    // casts (2 dispatches)
    wcast<<<896, blk256, 0, stream>>>(Wq, Wk, Wv, We, Wc, Wqb, Wkvb, Web, Wcb);
    qkcast<<<4096, blk256, 0, stream>>>(Q, K, Qbf, Kbf);

    // Q-proj + phase/sincos epilogue -> A
    gemm_k<2><<<dim3(4, 64), blk256, 0, stream>>>(Qbf, Wqb, bq, nullptr,
                                                  Abf, nullptr, Pq, Wp, bp, DM, DM);
    // KV-proj + epilogue -> B, Vt
    gemm_k<3><<<dim3(8, 64), blk256, 0, stream>>>(Kbf, Wkvb, bk, bv,
                                                  Bbf, Vtb, Pk, Wp, bp, DM, 2 * DM);

    // flash attention
    attn_mfma<<<1024, blk256, 0, stream>>>(Abf, Bbf, Vtb, Tbf);

    // FFN
    gemm_k<1><<<dim3(8, 64), blk256, 0, stream>>>(Tbf, Web, be, nullptr,
                                                  H1b, nullptr, nullptr, nullptr, nullptr,
                                                  DM, 2 * DM);
    gemm_k<0><<<dim3(4, 64), blk256, 0, stream>>>(H1b, Wcb, bc, nullptr,
                                                  Y, nullptr, nullptr, nullptr, nullptr,
                                                  2 * DM, DM);

    // BatchNorm (training stats) + residual
    bn_partial<<<256, blk256, 0, stream>>>(Y, part);
    bn_reduce<<<4, blk256, 0, stream>>>(part, stats);
    bn_final<<<ROWS * DM / 256, blk256, 0, stream>>>(Y, Q, stats, gamma, beta,
                                                     (float*)d_out);
}

// Round 5
// 182.745 us; speedup vs baseline: 7.6811x; 1.0488x over previous
//
#include <hip/hip_runtime.h>
#include <math.h>

#define LQ 1024      // sequence length L
#define DM 512       // model dim D
#define HN 8         // heads
#define DHD 64       // head dim
#define ROWS 8192    // N*S*L
#define DE 128       // effective attention dim (2*DHD)
#define LOG2E 1.44269504088896f

typedef __attribute__((ext_vector_type(8))) short bf16x8;
typedef __attribute__((ext_vector_type(4))) float floatx4;
typedef unsigned short u16;

static __device__ __forceinline__ u16 f2bf(float x) {
    unsigned int u = __float_as_uint(x);
    u = (u + 0x7fffu + ((u >> 16) & 1u)) >> 16;   // round-nearest-even
    return (u16)u;
}

static __device__ __forceinline__ void gload16(const void* g, void* l) {
    __builtin_amdgcn_global_load_lds((const __attribute__((address_space(1))) void*)g,
                                     (__attribute__((address_space(3))) void*)l,
                                     16, 0, 0);
}

static __device__ __forceinline__ void cvt8(const float* s, u16* d, size_t o) {
    const float4* sp = (const float4*)s + 2 * o;
    float4 a = sp[0], b = sp[1];
    union { u16 u[8]; uint4 v; } ov;
    ov.u[0]=f2bf(a.x); ov.u[1]=f2bf(a.y); ov.u[2]=f2bf(a.z); ov.u[3]=f2bf(a.w);
    ov.u[4]=f2bf(b.x); ov.u[5]=f2bf(b.y); ov.u[6]=f2bf(b.z); ov.u[7]=f2bf(b.w);
    ((uint4*)d)[o] = ov.v;
}

// ---------------------------------------------------------------------------
// weight casts only (Q/K now consumed as f32 by the GEMMs directly)
// ---------------------------------------------------------------------------
__global__ __launch_bounds__(256)
void wcast(const float* __restrict__ Wq, const float* __restrict__ Wk,
           const float* __restrict__ Wv, const float* __restrict__ We,
           const float* __restrict__ Wc,
           u16* __restrict__ Wqb, u16* __restrict__ Wkvb,
           u16* __restrict__ Web, u16* __restrict__ Wcb)
{
    int i = blockIdx.x * 256 + threadIdx.x;      // vec8 id, total 229376
    const float* s; u16* d; int o;
    if (i < 32768)        { s = Wq; d = Wqb;            o = i; }
    else if (i < 65536)   { s = Wk; d = Wkvb;           o = i - 32768; }
    else if (i < 98304)   { s = Wv; d = Wkvb + 262144;  o = i - 65536; }
    else if (i < 163840)  { s = We; d = Web;            o = i - 98304; }
    else                  { s = Wc; d = Wcb;            o = i - 163840; }
    cvt8(s, d, (size_t)o);
}

// ---------------------------------------------------------------------------
// bf16 MFMA GEMM, 128x128, BK=64, 2-phase dbuf, gload_lds W staging.
// FIN=1: X is f32, reg-staged (loads issued before MFMA, written after).
// MODE 0: f32 out + bias + BN partial sums   MODE 1: bf16 out + bias + relu
// MODE 2: Q-proj -> A (sin/cos, log2e)       MODE 3: KV-proj -> B / Vt
// ---------------------------------------------------------------------------
template<int MODE, int FIN>
__global__ __launch_bounds__(256)
void gemm_k(const void* __restrict__ Xv, const u16* __restrict__ W,
            const float* __restrict__ bias, const float* __restrict__ bias2,
            void* __restrict__ out, u16* __restrict__ out2,
            const float* __restrict__ Pph, const float* __restrict__ Wp,
            const float* __restrict__ bp, int Kd, int Nn,
            float* __restrict__ bnp)
{
    const int n0 = blockIdx.x * 128, m0 = blockIdx.y * 128;
    const int tid = threadIdx.x;
    const int w = tid >> 6, lane = tid & 63;
    const int lr = lane & 15, lg = lane >> 4;
    const int wm = w >> 1, wn = w & 1;

    __shared__ __align__(16) u16 AsL[2][128 * 64];
    __shared__ __align__(16) u16 BsL[2][128 * 64];
    __shared__ float BnL[2][2][4][16][2];

    const u16* Xb  = (const u16*)Xv;
    const float* Xf = (const float*)Xv;

    floatx4 acc[4][4] = {};
    const int xorp = (lr & 7) << 4;
    const int colb = lg << 4;

    auto stageW = [&](int t, int b) {
        const size_t ko = (size_t)t * 64;
        #pragma unroll
        for (int r = 0; r < 4; ++r) {
            const int cid = r * 256 + tid;
            const int row = cid >> 3, c16 = cid & 7;
            const int kc = ((c16 ^ (row & 7)) << 3);
            gload16(&W[(size_t)(n0 + row) * Kd + ko + kc], &BsL[b][cid * 8]);
        }
    };
    auto stageXb = [&](int t, int b) {
        const size_t ko = (size_t)t * 64;
        #pragma unroll
        for (int r = 0; r < 4; ++r) {
            const int cid = r * 256 + tid;
            const int row = cid >> 3, c16 = cid & 7;
            const int kc = ((c16 ^ (row & 7)) << 3);
            gload16(&Xb[(size_t)(m0 + row) * Kd + ko + kc], &AsL[b][cid * 8]);
        }
    };
    float4 xr[8];
    auto loadXf = [&](int t) {
        const size_t ko = (size_t)t * 64;
        #pragma unroll
        for (int r = 0; r < 4; ++r) {
            const int cid = r * 256 + tid;
            const int row = cid >> 3, c16 = cid & 7;
            const int kc = ((c16 ^ (row & 7)) << 3);
            const float* p = &Xf[(size_t)(m0 + row) * Kd + ko + kc];
            xr[2 * r]     = ((const float4*)p)[0];
            xr[2 * r + 1] = ((const float4*)p)[1];
        }
    };
    auto writeXf = [&](int b) {
        #pragma unroll
        for (int r = 0; r < 4; ++r) {
            const int cid = r * 256 + tid;
            float4 a = xr[2 * r], bb = xr[2 * r + 1];
            bf16x8 v;
            v[0]=f2bf(a.x);  v[1]=f2bf(a.y);  v[2]=f2bf(a.z);  v[3]=f2bf(a.w);
            v[4]=f2bf(bb.x); v[5]=f2bf(bb.y); v[6]=f2bf(bb.z); v[7]=f2bf(bb.w);
            *(bf16x8*)&AsL[b][cid * 8] = v;
        }
    };

    const int nt = Kd >> 6;
    if (FIN) { loadXf(0); stageW(0, 0); writeXf(0); }
    else     { stageXb(0, 0); stageW(0, 0); }
    __syncthreads();
    int c = 0;
    for (int t = 0; t < nt; ++t) {
        if (t + 1 < nt) {
            if (FIN) loadXf(t + 1);
            else     stageXb(t + 1, c ^ 1);
            stageW(t + 1, c ^ 1);
        }
        const char* la = (const char*)AsL[c];
        const char* lb = (const char*)BsL[c];
        #pragma unroll
        for (int ks = 0; ks < 2; ++ks) {
            const int cb = (ks * 64 + colb) ^ xorp;
            bf16x8 a[4], b[4];
            #pragma unroll
            for (int i = 0; i < 4; ++i)
                a[i] = *(const bf16x8*)(la + (((wm * 64 + i * 16 + lr) << 7) + cb));
            #pragma unroll
            for (int j = 0; j < 4; ++j)
                b[j] = *(const bf16x8*)(lb + (((wn * 64 + j * 16 + lr) << 7) + cb));
            #pragma unroll
            for (int i = 0; i < 4; ++i)
                #pragma unroll
                for (int j = 0; j < 4; ++j)
                    acc[i][j] = __builtin_amdgcn_mfma_f32_16x16x32_bf16(a[i], b[j], acc[i][j], 0, 0, 0);
        }
        if (FIN && t + 1 < nt) writeXf(c ^ 1);
        __syncthreads();
        c ^= 1;
    }

    if (MODE <= 1) {
        float bs[4], bs2[4];
        #pragma unroll
        for (int j = 0; j < 4; ++j) { bs[j] = 0.f; bs2[j] = 0.f; }
        #pragma unroll
        for (int j = 0; j < 4; ++j) {
            const int col = n0 + wn * 64 + j * 16 + lr;
            const float bi = bias[col];
            #pragma unroll
            for (int i = 0; i < 4; ++i)
                #pragma unroll
                for (int rr = 0; rr < 4; ++rr) {
                    const int row = m0 + wm * 64 + i * 16 + lg * 4 + rr;
                    float v = acc[i][j][rr] + bi;
                    if (MODE == 1) {
                        v = fmaxf(v, 0.f);
                        ((u16*)out)[(size_t)row * Nn + col] = f2bf(v);
                    } else {
                        ((float*)out)[(size_t)row * Nn + col] = v;
                        bs[j] += v; bs2[j] += v * v;
                    }
                }
        }
        if (MODE == 0) {    // BN partial: reduce 128 rows of this block
            #pragma unroll
            for (int j = 0; j < 4; ++j) {
                float s = bs[j], s2 = bs2[j];
                s  += __shfl_xor(s, 16);  s  += __shfl_xor(s, 32);
                s2 += __shfl_xor(s2, 16); s2 += __shfl_xor(s2, 32);
                if (lg == 0) { BnL[wm][wn][j][lr][0] = s; BnL[wm][wn][j][lr][1] = s2; }
            }
            __syncthreads();
            if (tid < 128) {
                const int wn2 = tid >> 6, j2 = (tid >> 4) & 3, lr2 = tid & 15;
                const float s  = BnL[0][wn2][j2][lr2][0] + BnL[1][wn2][j2][lr2][0];
                const float s2 = BnL[0][wn2][j2][lr2][1] + BnL[1][wn2][j2][lr2][1];
                const int col = n0 + tid;
                bnp[(size_t)blockIdx.y * 512 + col]         = s;
                bnp[32768 + (size_t)blockIdx.y * 512 + col] = s2;
            }
        }
    } else if (MODE == 2) {
        u16* A = (u16*)out;
        #pragma unroll
        for (int j = 0; j < 4; ++j) {
            const int col = n0 + wn * 64 + j * 16 + lr;
            const float w0 = Wp[col * 3], w1 = Wp[col * 3 + 1], w2 = Wp[col * 3 + 2];
            const float bpd = bp[col], bi = bias[col];
            const int hh = col >> 6, dh = col & 63;
            #pragma unroll
            for (int i = 0; i < 4; ++i)
                #pragma unroll
                for (int rr = 0; rr < 4; ++rr) {
                    const int row = m0 + wm * 64 + i * 16 + lg * 4 + rr;
                    const int ns = row >> 10, l = row & 1023;
                    const float p = Pph[row * 3] * w0 + Pph[row * 3 + 1] * w1
                                  + Pph[row * 3 + 2] * w2 + bpd;
                    float sn, cs;
                    __sincosf(p, &sn, &cs);
                    const float v = acc[i][j][rr] + bi;
                    const size_t e = (((size_t)(ns * HN + hh)) * LQ + l) * DE + dh;
                    A[e]      = f2bf(v * sn * LOG2E);
                    A[e + 64] = f2bf(-v * cs * LOG2E);
                }
        }
    } else {   // MODE 3
        if (n0 < 512) {     // K half -> B with phases
            u16* B = (u16*)out;
            #pragma unroll
            for (int j = 0; j < 4; ++j) {
                const int col = n0 + wn * 64 + j * 16 + lr;
                const float w0 = Wp[col * 3], w1 = Wp[col * 3 + 1], w2 = Wp[col * 3 + 2];
                const float bi = bias[col];
                const int hh = col >> 6, dh = col & 63;
                #pragma unroll
                for (int i = 0; i < 4; ++i)
                    #pragma unroll
                    for (int rr = 0; rr < 4; ++rr) {
                        const int row = m0 + wm * 64 + i * 16 + lg * 4 + rr;
                        const int ns = row >> 10, l = row & 1023;
                        const float p = Pph[row * 3] * w0 + Pph[row * 3 + 1] * w1
                                      + Pph[row * 3 + 2] * w2;      // pk - b
                        float sn, cs;
                        __sincosf(p, &sn, &cs);
                        const float v = acc[i][j][rr] + bi;
                        const size_t e = (((size_t)(ns * HN + hh)) * LQ + l) * DE + dh;
                        B[e]      = f2bf(v * cs);
                        B[e + 64] = f2bf(v * sn);
                    }
            }
        } else {            // V half -> Vt (per-head transposed)
            u16* Vt = out2;
            #pragma unroll
            for (int j = 0; j < 4; ++j) {
                const int col = n0 + wn * 64 + j * 16 + lr;
                const int c2 = col - 512;
                const float bi = bias2[c2];
                const int hh = c2 >> 6, dh = c2 & 63;
                #pragma unroll
                for (int i = 0; i < 4; ++i)
                    #pragma unroll
                    for (int rr = 0; rr < 4; ++rr) {
                        const int row = m0 + wm * 64 + i * 16 + lg * 4 + rr;
                        const int ns = row >> 10, l = row & 1023;
                        const float v = acc[i][j][rr] + bi;
                        Vt[((size_t)((ns * HN + hh) * DHD + dh)) * LQ + l] = f2bf(v);
                    }
            }
        }
    }
}

// ---------------------------------------------------------------------------
// Flash attention: QBLK=128, KVBLK=64, 4 waves x 32 q-rows.
// Q fragments register-resident (zero A LDS traffic); each kfrag/vfrag read
// feeds 2 MFMA. No-max softmax. 2-phase dbuf staging.
// ---------------------------------------------------------------------------
__global__ __launch_bounds__(256)
void attn_mfma(const u16* __restrict__ Ag, const u16* __restrict__ Bg,
               const u16* __restrict__ Vtg, u16* __restrict__ Tbf)
{
    int bid = blockIdx.x;
    bid = (bid & 7) * 64 + (bid >> 3);    // XCD swizzle (512 % 8 == 0)
    const int head = bid >> 3;            // 0..63
    const int row0 = (bid & 7) * 128;
    const int ns = head >> 3, h = head & 7;
    const int tid = threadIdx.x, w = tid >> 6, lane = tid & 63;
    const int lr = lane & 15, lg = lane >> 4;

    __shared__ __align__(16) u16 BsL[2][64 * 128];   // 32 KB
    __shared__ __align__(16) u16 VtL[2][64 * 64];    // 16 KB
    __shared__ __align__(16) u16 Ps[4][32][72];      // 18 KB

    // Q fragments -> registers (2 groups x 4 ks x bf16x8 = 32 VGPR)
    bf16x8 qfA[4], qfB[4];
    {
        const size_t rb = ((size_t)head * LQ + row0 + w * 32 + lr) * DE;
        #pragma unroll
        for (int ks = 0; ks < 4; ++ks) {
            qfA[ks] = *(const bf16x8*)&Ag[rb + ks * 32 + lg * 8];
            qfB[ks] = *(const bf16x8*)&Ag[rb + 16 * DE + ks * 32 + lg * 8];
        }
    }

    auto stageBV = [&](int kt, int b) {
        #pragma unroll
        for (int r = 0; r < 4; ++r) {
            const int cid = r * 256 + tid;
            const int row = cid >> 4, c16 = cid & 15;
            const int kc = ((c16 ^ (row & 7)) << 3);
            gload16(&Bg[((size_t)head * LQ + kt * 64 + row) * DE + kc], &BsL[b][cid * 8]);
        }
        #pragma unroll
        for (int r = 0; r < 2; ++r) {
            const int cid = r * 256 + tid;
            const int row = cid >> 3, c16 = cid & 7;
            const int kc = ((c16 ^ (row & 7)) << 3);
            gload16(&Vtg[((size_t)head * DHD + row) * LQ + kt * 64 + kc], &VtL[b][cid * 8]);
        }
    };
    stageBV(0, 0);
    __syncthreads();

    floatx4 oA[4] = {}, oB[4] = {};
    float lsA = 0.f, lsB = 0.f;
    const int xorp = (lr & 7) << 4;
    const int colb = lg << 4;
    int c = 0;

    for (int kt = 0; kt < 16; ++kt) {
        if (kt < 15) stageBV(kt + 1, c ^ 1);

        const char* lb = (const char*)BsL[c];
        const char* lv = (const char*)VtL[c];

        // ---- S^T strips for both q-groups (kfrag shared) ----
        floatx4 sA[4] = {}, sB[4] = {};
        __builtin_amdgcn_s_setprio(1);
        #pragma unroll
        for (int ks = 0; ks < 4; ++ks) {
            const int cb = (ks * 64 + colb) ^ xorp;
            bf16x8 kf[4];
            #pragma unroll
            for (int j = 0; j < 4; ++j)
                kf[j] = *(const bf16x8*)(lb + (((j * 16 + lr) << 8) + cb));
            #pragma unroll
            for (int j = 0; j < 4; ++j) {
                sA[j] = __builtin_amdgcn_mfma_f32_16x16x32_bf16(kf[j], qfA[ks], sA[j], 0, 0, 0);
                sB[j] = __builtin_amdgcn_mfma_f32_16x16x32_bf16(kf[j], qfB[ks], sB[j], 0, 0, 0);
            }
        }
        __builtin_amdgcn_s_setprio(0);

        // ---- no-max softmax ----
        float tsa = 0.f, tsb = 0.f;
        #pragma unroll
        for (int j = 0; j < 4; ++j)
            #pragma unroll
            for (int r = 0; r < 4; ++r) {
                float ea = exp2f(sA[j][r]); sA[j][r] = ea; tsa += ea;
                float eb = exp2f(sB[j][r]); sB[j][r] = eb; tsb += eb;
            }
        lsA += tsa; lsB += tsb;

        // ---- P -> per-wave LDS (cvt_pk pack), rows 0-15 = A, 16-31 = B ----
        #pragma unroll
        for (int j = 0; j < 4; ++j) {
            unsigned plo, phi;
            asm("v_cvt_pk_bf16_f32 %0, %1, %2" : "=v"(plo) : "v"(sA[j][0]), "v"(sA[j][1]));
            asm("v_cvt_pk_bf16_f32 %0, %1, %2" : "=v"(phi) : "v"(sA[j][2]), "v"(sA[j][3]));
            uint2 pv; pv.x = plo; pv.y = phi;
            *(uint2*)&Ps[w][lr][j * 16 + lg * 4] = pv;
            asm("v_cvt_pk_bf16_f32 %0, %1, %2" : "=v"(plo) : "v"(sB[j][0]), "v"(sB[j][1]));
            asm("v_cvt_pk_bf16_f32 %0, %1, %2" : "=v"(phi) : "v"(sB[j][2]), "v"(sB[j][3]));
            pv.x = plo; pv.y = phi;
            *(uint2*)&Ps[w][16 + lr][j * 16 + lg * 4] = pv;
        }

        // ---- PV: vfrag shared across both q-groups ----
        __builtin_amdgcn_s_setprio(1);
        #pragma unroll
        for (int ks2 = 0; ks2 < 2; ++ks2) {
            const int cb = (ks2 * 64 + colb) ^ xorp;
            bf16x8 pfA = *(const bf16x8*)&Ps[w][lr][ks2 * 32 + lg * 8];
            bf16x8 pfB = *(const bf16x8*)&Ps[w][16 + lr][ks2 * 32 + lg * 8];
            #pragma unroll
            for (int m = 0; m < 4; ++m) {
                bf16x8 vf = *(const bf16x8*)(lv + (((m * 16 + lr) << 7) + cb));
                oA[m] = __builtin_amdgcn_mfma_f32_16x16x32_bf16(vf, pfA, oA[m], 0, 0, 0);
                oB[m] = __builtin_amdgcn_mfma_f32_16x16x32_bf16(vf, pfB, oB[m], 0, 0, 0);
            }
        }
        __builtin_amdgcn_s_setprio(0);
        __syncthreads();
        c ^= 1;
    }

    // denominators (once), normalize, write merged-head T (bf16)
    lsA += __shfl_xor(lsA, 16); lsA += __shfl_xor(lsA, 32);
    lsB += __shfl_xor(lsB, 16); lsB += __shfl_xor(lsB, 32);
    const float invA = 1.f / lsA, invB = 1.f / lsB;
    const size_t trA = ((size_t)ns * LQ + row0 + w * 32 + lr) * DM + h * DHD;
    const size_t trB = trA + (size_t)16 * DM;
    #pragma unroll
    for (int m = 0; m < 4; ++m) {
        union { u16 u[4]; uint2 v; } pk;
        pk.u[0] = f2bf(oA[m][0] * invA); pk.u[1] = f2bf(oA[m][1] * invA);
        pk.u[2] = f2bf(oA[m][2] * invA); pk.u[3] = f2bf(oA[m][3] * invA);
        *(uint2*)&Tbf[trA + m * 16 + lg * 4] = pk.v;
        pk.u[0] = f2bf(oB[m][0] * invB); pk.u[1] = f2bf(oB[m][1] * invB);
        pk.u[2] = f2bf(oB[m][2] * invB); pk.u[3] = f2bf(oB[m][3] * invB);
        *(uint2*)&Tbf[trB + m * 16 + lg * 4] = pk.v;
    }
}

// ---------------------------------------------------------------------------
// BN: reduce per-block partials (64 m-blocks) -> stats; then final
// ---------------------------------------------------------------------------
__global__ __launch_bounds__(256)
void bn_reduce(const float* __restrict__ part, float* __restrict__ stats)
{
    const int cx = blockIdx.x * 256 + threadIdx.x;   // 0..511
    float s = 0.f, s2 = 0.f;
    for (int b = 0; b < 64; ++b) {
        s  += part[(size_t)b * 512 + cx];
        s2 += part[32768 + (size_t)b * 512 + cx];
    }
    stats[cx] = s;
    stats[512 + cx] = s2;
}

__global__ __launch_bounds__(256)
void bn_final(const float* __restrict__ Y, const float* __restrict__ Qin,
              const float* __restrict__ stats,
              const float* __restrict__ gamma, const float* __restrict__ beta,
              float* __restrict__ out)
{
    const int i = blockIdx.x * 256 + threadIdx.x;
    const int c = i & (DM - 1);
    const float mu  = stats[c] * (1.f / ROWS);
    const float var = stats[512 + c] * (1.f / ROWS) - mu * mu;
    const float rs  = rsqrtf(var + 1e-5f);
    out[i] = Qin[i] + (Y[i] - mu) * rs * gamma[c] + beta[c];
}

// ---------------------------------------------------------------------------
extern "C" void kernel_launch(void* const* d_in, const int* in_sizes, int n_in,
                              void* d_out, int out_size, void* d_ws, size_t ws_size,
                              hipStream_t stream)
{
    (void)in_sizes; (void)n_in; (void)out_size; (void)ws_size;

    const float* Q    = (const float*)d_in[0];
    const float* K    = (const float*)d_in[1];
    const float* Pq   = (const float*)d_in[2];
    const float* Pk   = (const float*)d_in[3];
    const float* Wq   = (const float*)d_in[4];
    const float* bq   = (const float*)d_in[5];
    const float* Wk   = (const float*)d_in[6];
    const float* bk   = (const float*)d_in[7];
    const float* Wv   = (const float*)d_in[8];
    const float* bv   = (const float*)d_in[9];
    const float* Wp   = (const float*)d_in[10];
    const float* bp   = (const float*)d_in[11];
    const float* We   = (const float*)d_in[12];
    const float* be   = (const float*)d_in[13];
    const float* Wc   = (const float*)d_in[14];
    const float* bc   = (const float*)d_in[15];
    const float* gamma= (const float*)d_in[16];
    const float* beta = (const float*)d_in[17];

    const size_t MB = 1u << 20;
    char* w8 = (char*)d_ws;
    u16*  Abf  = (u16*)(w8);                  // 16 MB (A operands)
    u16*  Bbf  = (u16*)(w8 + 16 * MB);        // 16 MB
    u16*  Vtb  = (u16*)(w8 + 32 * MB);        //  8 MB
    u16*  Tbf  = (u16*)(w8 + 40 * MB);        //  8 MB
    u16*  H1b  = (u16*)(w8 + 48 * MB);        // 16 MB
    float* Y   = (float*)(w8);                // 16 MB (reuses Abf after attn)
    float* part  = (float*)(w8 + 16 * MB);    // 256 KB (reuses Bbf after attn)
    float* stats = (float*)(w8 + 17 * MB);    //  4 KB
    u16*  Wqb  = (u16*)(w8 + 64 * MB);                    // 0.5 MB
    u16*  Wkvb = (u16*)(w8 + 64 * MB + 512 * 1024);       // 1 MB
    u16*  Web  = (u16*)(w8 + 64 * MB + 1536 * 1024);      // 1 MB
    u16*  Wcb  = (u16*)(w8 + 64 * MB + 2560 * 1024);      // 1 MB

    dim3 blk256(256);

    // weight casts only
    wcast<<<896, blk256, 0, stream>>>(Wq, Wk, Wv, We, Wc, Wqb, Wkvb, Web, Wcb);

    // Q-proj (f32 in) + phase/sincos epilogue -> A
    gemm_k<2, 1><<<dim3(4, 64), blk256, 0, stream>>>(Q, Wqb, bq, nullptr,
        Abf, nullptr, Pq, Wp, bp, DM, DM, nullptr);
    // KV-proj (f32 in) + epilogue -> B, Vt
    gemm_k<3, 1><<<dim3(8, 64), blk256, 0, stream>>>(K, Wkvb, bk, bv,
        Bbf, Vtb, Pk, Wp, bp, DM, 2 * DM, nullptr);

    // flash attention (512 blocks = 2/CU)
    attn_mfma<<<512, blk256, 0, stream>>>(Abf, Bbf, Vtb, Tbf);

    // FFN
    gemm_k<1, 0><<<dim3(8, 64), blk256, 0, stream>>>(Tbf, Web, be, nullptr,
        H1b, nullptr, nullptr, nullptr, nullptr, DM, 2 * DM, nullptr);
    gemm_k<0, 0><<<dim3(4, 64), blk256, 0, stream>>>(H1b, Wcb, bc, nullptr,
        Y, nullptr, nullptr, nullptr, nullptr, 2 * DM, DM, part);

    // BN stats + final
    bn_reduce<<<2, blk256, 0, stream>>>(part, stats);
    bn_final<<<ROWS * DM / 256, blk256, 0, stream>>>(Y, Q, stats, gamma, beta,
                                                     (float*)d_out);
}

// Round 6
// 158.620 us; speedup vs baseline: 8.8493x; 1.1521x over previous
//
#include <hip/hip_runtime.h>
#include <math.h>

#define LQ 1024      // sequence length L
#define DM 512       // model dim D
#define HN 8         // heads
#define DHD 64       // head dim
#define ROWS 8192    // N*S*L
#define DE 128       // effective attention dim (2*DHD)
#define LOG2E 1.44269504088896f

typedef __attribute__((ext_vector_type(8))) short bf16x8;
typedef __attribute__((ext_vector_type(4))) float floatx4;
typedef unsigned short u16;

static __device__ __forceinline__ u16 f2bf(float x) {
    unsigned int u = __float_as_uint(x);
    u = (u + 0x7fffu + ((u >> 16) & 1u)) >> 16;   // round-nearest-even
    return (u16)u;
}

static __device__ __forceinline__ void gload16(const void* g, void* l) {
    __builtin_amdgcn_global_load_lds((const __attribute__((address_space(1))) void*)g,
                                     (__attribute__((address_space(3))) void*)l,
                                     16, 0, 0);
}

static __device__ __forceinline__ void cvt8(const float* s, u16* d, size_t o) {
    const float4* sp = (const float4*)s + 2 * o;
    float4 a = sp[0], b = sp[1];
    union { u16 u[8]; uint4 v; } ov;
    ov.u[0]=f2bf(a.x); ov.u[1]=f2bf(a.y); ov.u[2]=f2bf(a.z); ov.u[3]=f2bf(a.w);
    ov.u[4]=f2bf(b.x); ov.u[5]=f2bf(b.y); ov.u[6]=f2bf(b.z); ov.u[7]=f2bf(b.w);
    ((uint4*)d)[o] = ov.v;
}

// ---------------------------------------------------------------------------
// weight casts only (Q/K consumed as f32 by the GEMMs directly)
// ---------------------------------------------------------------------------
__global__ __launch_bounds__(256)
void wcast(const float* __restrict__ Wq, const float* __restrict__ Wk,
           const float* __restrict__ Wv, const float* __restrict__ We,
           const float* __restrict__ Wc,
           u16* __restrict__ Wqb, u16* __restrict__ Wkvb,
           u16* __restrict__ Web, u16* __restrict__ Wcb)
{
    int i = blockIdx.x * 256 + threadIdx.x;      // vec8 id, total 229376
    const float* s; u16* d; int o;
    if (i < 32768)        { s = Wq; d = Wqb;            o = i; }
    else if (i < 65536)   { s = Wk; d = Wkvb;           o = i - 32768; }
    else if (i < 98304)   { s = Wv; d = Wkvb + 262144;  o = i - 65536; }
    else if (i < 163840)  { s = We; d = Web;            o = i - 98304; }
    else                  { s = Wc; d = Wcb;            o = i - 163840; }
    cvt8(s, d, (size_t)o);
}

// ---------------------------------------------------------------------------
// bf16 MFMA GEMM, 128x128, BK=64, 2-phase dbuf, gload_lds W staging.
// Grid: blockIdx.x = M-tile (fast -> same-XCD strip sharing), blockIdx.y = N-tile.
// FIN=1: X is f32, reg-staged (loads issued before MFMA, written after).
// MODE 0: f32 out + bias + BN partial sums   MODE 1: bf16 out + bias + relu
// MODE 2: Q-proj -> A (sin/cos, log2e)       MODE 3: KV-proj -> B / Vt
// ---------------------------------------------------------------------------
template<int MODE, int FIN>
__global__ __launch_bounds__(256)
void gemm_k(const void* __restrict__ Xv, const u16* __restrict__ W,
            const float* __restrict__ bias, const float* __restrict__ bias2,
            void* __restrict__ out, u16* __restrict__ out2,
            const float* __restrict__ Pph, const float* __restrict__ Wp,
            const float* __restrict__ bp, int Kd, int Nn,
            float* __restrict__ bnp)
{
    const int m0 = blockIdx.x * 128, n0 = blockIdx.y * 128;   // x = row tile!
    const int tid = threadIdx.x;
    const int w = tid >> 6, lane = tid & 63;
    const int lr = lane & 15, lg = lane >> 4;
    const int wm = w >> 1, wn = w & 1;

    __shared__ __align__(16) u16 AsL[2][128 * 64];
    __shared__ __align__(16) u16 BsL[2][128 * 64];
    __shared__ float BnL[2][2][4][16][2];

    const u16* Xb  = (const u16*)Xv;
    const float* Xf = (const float*)Xv;

    floatx4 acc[4][4] = {};
    const int xorp = (lr & 7) << 4;
    const int colb = lg << 4;

    auto stageW = [&](int t, int b) {
        const size_t ko = (size_t)t * 64;
        #pragma unroll
        for (int r = 0; r < 4; ++r) {
            const int cid = r * 256 + tid;
            const int row = cid >> 3, c16 = cid & 7;
            const int kc = ((c16 ^ (row & 7)) << 3);
            gload16(&W[(size_t)(n0 + row) * Kd + ko + kc], &BsL[b][cid * 8]);
        }
    };
    auto stageXb = [&](int t, int b) {
        const size_t ko = (size_t)t * 64;
        #pragma unroll
        for (int r = 0; r < 4; ++r) {
            const int cid = r * 256 + tid;
            const int row = cid >> 3, c16 = cid & 7;
            const int kc = ((c16 ^ (row & 7)) << 3);
            gload16(&Xb[(size_t)(m0 + row) * Kd + ko + kc], &AsL[b][cid * 8]);
        }
    };
    float4 xr[8];
    auto loadXf = [&](int t) {
        const size_t ko = (size_t)t * 64;
        #pragma unroll
        for (int r = 0; r < 4; ++r) {
            const int cid = r * 256 + tid;
            const int row = cid >> 3, c16 = cid & 7;
            const int kc = ((c16 ^ (row & 7)) << 3);
            const float* p = &Xf[(size_t)(m0 + row) * Kd + ko + kc];
            xr[2 * r]     = ((const float4*)p)[0];
            xr[2 * r + 1] = ((const float4*)p)[1];
        }
    };
    auto writeXf = [&](int b) {
        #pragma unroll
        for (int r = 0; r < 4; ++r) {
            const int cid = r * 256 + tid;
            float4 a = xr[2 * r], bb = xr[2 * r + 1];
            bf16x8 v;
            v[0]=f2bf(a.x);  v[1]=f2bf(a.y);  v[2]=f2bf(a.z);  v[3]=f2bf(a.w);
            v[4]=f2bf(bb.x); v[5]=f2bf(bb.y); v[6]=f2bf(bb.z); v[7]=f2bf(bb.w);
            *(bf16x8*)&AsL[b][cid * 8] = v;
        }
    };

    const int nt = Kd >> 6;
    if (FIN) { loadXf(0); stageW(0, 0); writeXf(0); }
    else     { stageXb(0, 0); stageW(0, 0); }
    __syncthreads();
    int c = 0;
    for (int t = 0; t < nt; ++t) {
        if (t + 1 < nt) {
            if (FIN) loadXf(t + 1);
            else     stageXb(t + 1, c ^ 1);
            stageW(t + 1, c ^ 1);
        }
        const char* la = (const char*)AsL[c];
        const char* lb = (const char*)BsL[c];
        #pragma unroll
        for (int ks = 0; ks < 2; ++ks) {
            const int cb = (ks * 64 + colb) ^ xorp;
            bf16x8 a[4], b[4];
            #pragma unroll
            for (int i = 0; i < 4; ++i)
                a[i] = *(const bf16x8*)(la + (((wm * 64 + i * 16 + lr) << 7) + cb));
            #pragma unroll
            for (int j = 0; j < 4; ++j)
                b[j] = *(const bf16x8*)(lb + (((wn * 64 + j * 16 + lr) << 7) + cb));
            #pragma unroll
            for (int i = 0; i < 4; ++i)
                #pragma unroll
                for (int j = 0; j < 4; ++j)
                    acc[i][j] = __builtin_amdgcn_mfma_f32_16x16x32_bf16(a[i], b[j], acc[i][j], 0, 0, 0);
        }
        if (FIN && t + 1 < nt) writeXf(c ^ 1);
        __syncthreads();
        c ^= 1;
    }

    if (MODE <= 1) {
        float bs[4], bs2[4];
        #pragma unroll
        for (int j = 0; j < 4; ++j) { bs[j] = 0.f; bs2[j] = 0.f; }
        #pragma unroll
        for (int j = 0; j < 4; ++j) {
            const int col = n0 + wn * 64 + j * 16 + lr;
            const float bi = bias[col];
            #pragma unroll
            for (int i = 0; i < 4; ++i)
                #pragma unroll
                for (int rr = 0; rr < 4; ++rr) {
                    const int row = m0 + wm * 64 + i * 16 + lg * 4 + rr;
                    float v = acc[i][j][rr] + bi;
                    if (MODE == 1) {
                        v = fmaxf(v, 0.f);
                        ((u16*)out)[(size_t)row * Nn + col] = f2bf(v);
                    } else {
                        ((float*)out)[(size_t)row * Nn + col] = v;
                        bs[j] += v; bs2[j] += v * v;
                    }
                }
        }
        if (MODE == 0) {    // BN partial: reduce 128 rows of this m-tile
            #pragma unroll
            for (int j = 0; j < 4; ++j) {
                float s = bs[j], s2 = bs2[j];
                s  += __shfl_xor(s, 16);  s  += __shfl_xor(s, 32);
                s2 += __shfl_xor(s2, 16); s2 += __shfl_xor(s2, 32);
                if (lg == 0) { BnL[wm][wn][j][lr][0] = s; BnL[wm][wn][j][lr][1] = s2; }
            }
            __syncthreads();
            if (tid < 128) {
                const int wn2 = tid >> 6, j2 = (tid >> 4) & 3, lr2 = tid & 15;
                const float s  = BnL[0][wn2][j2][lr2][0] + BnL[1][wn2][j2][lr2][0];
                const float s2 = BnL[0][wn2][j2][lr2][1] + BnL[1][wn2][j2][lr2][1];
                const int col = n0 + tid;
                bnp[(size_t)blockIdx.x * 512 + col]         = s;
                bnp[32768 + (size_t)blockIdx.x * 512 + col] = s2;
            }
        }
    } else if (MODE == 2) {
        u16* A = (u16*)out;
        #pragma unroll
        for (int j = 0; j < 4; ++j) {
            const int col = n0 + wn * 64 + j * 16 + lr;
            const float w0 = Wp[col * 3], w1 = Wp[col * 3 + 1], w2 = Wp[col * 3 + 2];
            const float bpd = bp[col], bi = bias[col];
            const int hh = col >> 6, dh = col & 63;
            #pragma unroll
            for (int i = 0; i < 4; ++i)
                #pragma unroll
                for (int rr = 0; rr < 4; ++rr) {
                    const int row = m0 + wm * 64 + i * 16 + lg * 4 + rr;
                    const int ns = row >> 10, l = row & 1023;
                    const float p = Pph[row * 3] * w0 + Pph[row * 3 + 1] * w1
                                  + Pph[row * 3 + 2] * w2 + bpd;
                    float sn, cs;
                    __sincosf(p, &sn, &cs);
                    const float v = acc[i][j][rr] + bi;
                    const size_t e = (((size_t)(ns * HN + hh)) * LQ + l) * DE + dh;
                    A[e]      = f2bf(v * sn * LOG2E);
                    A[e + 64] = f2bf(-v * cs * LOG2E);
                }
        }
    } else {   // MODE 3
        if (n0 < 512) {     // K half -> B with phases
            u16* B = (u16*)out;
            #pragma unroll
            for (int j = 0; j < 4; ++j) {
                const int col = n0 + wn * 64 + j * 16 + lr;
                const float w0 = Wp[col * 3], w1 = Wp[col * 3 + 1], w2 = Wp[col * 3 + 2];
                const float bi = bias[col];
                const int hh = col >> 6, dh = col & 63;
                #pragma unroll
                for (int i = 0; i < 4; ++i)
                    #pragma unroll
                    for (int rr = 0; rr < 4; ++rr) {
                        const int row = m0 + wm * 64 + i * 16 + lg * 4 + rr;
                        const int ns = row >> 10, l = row & 1023;
                        const float p = Pph[row * 3] * w0 + Pph[row * 3 + 1] * w1
                                      + Pph[row * 3 + 2] * w2;      // pk - b
                        float sn, cs;
                        __sincosf(p, &sn, &cs);
                        const float v = acc[i][j][rr] + bi;
                        const size_t e = (((size_t)(ns * HN + hh)) * LQ + l) * DE + dh;
                        B[e]      = f2bf(v * cs);
                        B[e + 64] = f2bf(v * sn);
                    }
            }
        } else {            // V half -> Vt (per-head transposed)
            u16* Vt = out2;
            #pragma unroll
            for (int j = 0; j < 4; ++j) {
                const int col = n0 + wn * 64 + j * 16 + lr;
                const int c2 = col - 512;
                const float bi = bias2[c2];
                const int hh = c2 >> 6, dh = c2 & 63;
                #pragma unroll
                for (int i = 0; i < 4; ++i)
                    #pragma unroll
                    for (int rr = 0; rr < 4; ++rr) {
                        const int row = m0 + wm * 64 + i * 16 + lg * 4 + rr;
                        const int ns = row >> 10, l = row & 1023;
                        const float v = acc[i][j][rr] + bi;
                        Vt[((size_t)((ns * HN + hh) * DHD + dh)) * LQ + l] = f2bf(v);
                    }
            }
        }
    }
}

// ---------------------------------------------------------------------------
// Flash attention: QBLK=128, KVBLK=64, 4 waves x 32 q-rows, Q in registers.
// Counted-vmcnt dual-barrier pipeline: next tile's 6 global_load_lds stay in
// flight across the barrier (no vmcnt(0) drain in steady state).
// ---------------------------------------------------------------------------
__global__ __launch_bounds__(256)
void attn_mfma(const u16* __restrict__ Ag, const u16* __restrict__ Bg,
               const u16* __restrict__ Vtg, u16* __restrict__ Tbf)
{
    int bid = blockIdx.x;
    bid = (bid & 7) * 64 + (bid >> 3);    // XCD swizzle (512 % 8 == 0)
    const int head = bid >> 3;            // 0..63
    const int row0 = (bid & 7) * 128;
    const int ns = head >> 3, h = head & 7;
    const int tid = threadIdx.x, w = tid >> 6, lane = tid & 63;
    const int lr = lane & 15, lg = lane >> 4;

    __shared__ __align__(16) u16 BsL[2][64 * 128];   // 32 KB
    __shared__ __align__(16) u16 VtL[2][64 * 64];    // 16 KB
    __shared__ __align__(16) u16 Ps[4][32][72];      // 18 KB

    // Q fragments -> registers (2 groups x 4 ks x bf16x8 = 32 VGPR)
    bf16x8 qfA[4], qfB[4];
    {
        const size_t rb = ((size_t)head * LQ + row0 + w * 32 + lr) * DE;
        #pragma unroll
        for (int ks = 0; ks < 4; ++ks) {
            qfA[ks] = *(const bf16x8*)&Ag[rb + ks * 32 + lg * 8];
            qfB[ks] = *(const bf16x8*)&Ag[rb + 16 * DE + ks * 32 + lg * 8];
        }
    }

    auto stageBV = [&](int kt, int b) {
        #pragma unroll
        for (int r = 0; r < 4; ++r) {
            const int cid = r * 256 + tid;
            const int row = cid >> 4, c16 = cid & 15;
            const int kc = ((c16 ^ (row & 7)) << 3);
            gload16(&Bg[((size_t)head * LQ + kt * 64 + row) * DE + kc], &BsL[b][cid * 8]);
        }
        #pragma unroll
        for (int r = 0; r < 2; ++r) {
            const int cid = r * 256 + tid;
            const int row = cid >> 3, c16 = cid & 7;
            const int kc = ((c16 ^ (row & 7)) << 3);
            gload16(&Vtg[((size_t)head * DHD + row) * LQ + kt * 64 + kc], &VtL[b][cid * 8]);
        }
    };
    stageBV(0, 0);

    floatx4 oA[4] = {}, oB[4] = {};
    float lsA = 0.f, lsB = 0.f;
    const int xorp = (lr & 7) << 4;
    const int colb = lg << 4;
    int c = 0;

    for (int kt = 0; kt < 16; ++kt) {
        if (kt < 15) {
            stageBV(kt + 1, c ^ 1);           // 6 loads stay in flight
            asm volatile("s_waitcnt vmcnt(6)" ::: "memory");
        } else {
            asm volatile("s_waitcnt vmcnt(0)" ::: "memory");
        }
        __builtin_amdgcn_sched_barrier(0);
        __builtin_amdgcn_s_barrier();         // tile kt fully staged for all waves

        const char* lb = (const char*)BsL[c];
        const char* lv = (const char*)VtL[c];

        // ---- S^T strips for both q-groups (kfrag shared) ----
        floatx4 sA[4] = {}, sB[4] = {};
        __builtin_amdgcn_s_setprio(1);
        #pragma unroll
        for (int ks = 0; ks < 4; ++ks) {
            const int cb = (ks * 64 + colb) ^ xorp;
            bf16x8 kf[4];
            #pragma unroll
            for (int j = 0; j < 4; ++j)
                kf[j] = *(const bf16x8*)(lb + (((j * 16 + lr) << 8) + cb));
            #pragma unroll
            for (int j = 0; j < 4; ++j) {
                sA[j] = __builtin_amdgcn_mfma_f32_16x16x32_bf16(kf[j], qfA[ks], sA[j], 0, 0, 0);
                sB[j] = __builtin_amdgcn_mfma_f32_16x16x32_bf16(kf[j], qfB[ks], sB[j], 0, 0, 0);
            }
        }
        __builtin_amdgcn_s_setprio(0);

        // ---- no-max softmax ----
        float tsa = 0.f, tsb = 0.f;
        #pragma unroll
        for (int j = 0; j < 4; ++j)
            #pragma unroll
            for (int r = 0; r < 4; ++r) {
                float ea = exp2f(sA[j][r]); sA[j][r] = ea; tsa += ea;
                float eb = exp2f(sB[j][r]); sB[j][r] = eb; tsb += eb;
            }
        lsA += tsa; lsB += tsb;

        // ---- P -> per-wave LDS (cvt_pk pack), rows 0-15 = A, 16-31 = B ----
        #pragma unroll
        for (int j = 0; j < 4; ++j) {
            unsigned plo, phi;
            asm("v_cvt_pk_bf16_f32 %0, %1, %2" : "=v"(plo) : "v"(sA[j][0]), "v"(sA[j][1]));
            asm("v_cvt_pk_bf16_f32 %0, %1, %2" : "=v"(phi) : "v"(sA[j][2]), "v"(sA[j][3]));
            uint2 pv; pv.x = plo; pv.y = phi;
            *(uint2*)&Ps[w][lr][j * 16 + lg * 4] = pv;
            asm("v_cvt_pk_bf16_f32 %0, %1, %2" : "=v"(plo) : "v"(sB[j][0]), "v"(sB[j][1]));
            asm("v_cvt_pk_bf16_f32 %0, %1, %2" : "=v"(phi) : "v"(sB[j][2]), "v"(sB[j][3]));
            pv.x = plo; pv.y = phi;
            *(uint2*)&Ps[w][16 + lr][j * 16 + lg * 4] = pv;
        }

        // ---- PV: vfrag shared across both q-groups ----
        __builtin_amdgcn_s_setprio(1);
        #pragma unroll
        for (int ks2 = 0; ks2 < 2; ++ks2) {
            const int cb = (ks2 * 64 + colb) ^ xorp;
            bf16x8 pfA = *(const bf16x8*)&Ps[w][lr][ks2 * 32 + lg * 8];
            bf16x8 pfB = *(const bf16x8*)&Ps[w][16 + lr][ks2 * 32 + lg * 8];
            #pragma unroll
            for (int m = 0; m < 4; ++m) {
                bf16x8 vf = *(const bf16x8*)(lv + (((m * 16 + lr) << 7) + cb));
                oA[m] = __builtin_amdgcn_mfma_f32_16x16x32_bf16(vf, pfA, oA[m], 0, 0, 0);
                oB[m] = __builtin_amdgcn_mfma_f32_16x16x32_bf16(vf, pfB, oB[m], 0, 0, 0);
            }
        }
        __builtin_amdgcn_s_setprio(0);
        __builtin_amdgcn_s_barrier();         // all waves done reading buf c
        __builtin_amdgcn_sched_barrier(0);
        c ^= 1;
    }

    // denominators (once), normalize, write merged-head T (bf16)
    lsA += __shfl_xor(lsA, 16); lsA += __shfl_xor(lsA, 32);
    lsB += __shfl_xor(lsB, 16); lsB += __shfl_xor(lsB, 32);
    const float invA = 1.f / lsA, invB = 1.f / lsB;
    const size_t trA = ((size_t)ns * LQ + row0 + w * 32 + lr) * DM + h * DHD;
    const size_t trB = trA + (size_t)16 * DM;
    #pragma unroll
    for (int m = 0; m < 4; ++m) {
        union { u16 u[4]; uint2 v; } pk;
        pk.u[0] = f2bf(oA[m][0] * invA); pk.u[1] = f2bf(oA[m][1] * invA);
        pk.u[2] = f2bf(oA[m][2] * invA); pk.u[3] = f2bf(oA[m][3] * invA);
        *(uint2*)&Tbf[trA + m * 16 + lg * 4] = pk.v;
        pk.u[0] = f2bf(oB[m][0] * invB); pk.u[1] = f2bf(oB[m][1] * invB);
        pk.u[2] = f2bf(oB[m][2] * invB); pk.u[3] = f2bf(oB[m][3] * invB);
        *(uint2*)&Tbf[trB + m * 16 + lg * 4] = pk.v;
    }
}

// ---------------------------------------------------------------------------
// BN: reduce per-block partials (64 m-blocks) -> stats; then final
// ---------------------------------------------------------------------------
__global__ __launch_bounds__(256)
void bn_reduce(const float* __restrict__ part, float* __restrict__ stats)
{
    const int cx = blockIdx.x * 256 + threadIdx.x;   // 0..511
    float s = 0.f, s2 = 0.f;
    for (int b = 0; b < 64; ++b) {
        s  += part[(size_t)b * 512 + cx];
        s2 += part[32768 + (size_t)b * 512 + cx];
    }
    stats[cx] = s;
    stats[512 + cx] = s2;
}

__global__ __launch_bounds__(256)
void bn_final(const float* __restrict__ Y, const float* __restrict__ Qin,
              const float* __restrict__ stats,
              const float* __restrict__ gamma, const float* __restrict__ beta,
              float* __restrict__ out)
{
    const int i = blockIdx.x * 256 + threadIdx.x;
    const int c = i & (DM - 1);
    const float mu  = stats[c] * (1.f / ROWS);
    const float var = stats[512 + c] * (1.f / ROWS) - mu * mu;
    const float rs  = rsqrtf(var + 1e-5f);
    out[i] = Qin[i] + (Y[i] - mu) * rs * gamma[c] + beta[c];
}

// ---------------------------------------------------------------------------
extern "C" void kernel_launch(void* const* d_in, const int* in_sizes, int n_in,
                              void* d_out, int out_size, void* d_ws, size_t ws_size,
                              hipStream_t stream)
{
    (void)in_sizes; (void)n_in; (void)out_size; (void)ws_size;

    const float* Q    = (const float*)d_in[0];
    const float* K    = (const float*)d_in[1];
    const float* Pq   = (const float*)d_in[2];
    const float* Pk   = (const float*)d_in[3];
    const float* Wq   = (const float*)d_in[4];
    const float* bq   = (const float*)d_in[5];
    const float* Wk   = (const float*)d_in[6];
    const float* bk   = (const float*)d_in[7];
    const float* Wv   = (const float*)d_in[8];
    const float* bv   = (const float*)d_in[9];
    const float* Wp   = (const float*)d_in[10];
    const float* bp   = (const float*)d_in[11];
    const float* We   = (const float*)d_in[12];
    const float* be   = (const float*)d_in[13];
    const float* Wc   = (const float*)d_in[14];
    const float* bc   = (const float*)d_in[15];
    const float* gamma= (const float*)d_in[16];
    const float* beta = (const float*)d_in[17];

    const size_t MB = 1u << 20;
    char* w8 = (char*)d_ws;
    u16*  Abf  = (u16*)(w8);                  // 16 MB (A operands)
    u16*  Bbf  = (u16*)(w8 + 16 * MB);        // 16 MB
    u16*  Vtb  = (u16*)(w8 + 32 * MB);        //  8 MB
    u16*  Tbf  = (u16*)(w8 + 40 * MB);        //  8 MB
    u16*  H1b  = (u16*)(w8 + 48 * MB);        // 16 MB
    float* Y   = (float*)(w8);                // 16 MB (reuses Abf after attn)
    float* part  = (float*)(w8 + 16 * MB);    // 256 KB (reuses Bbf after attn)
    float* stats = (float*)(w8 + 17 * MB);    //  4 KB
    u16*  Wqb  = (u16*)(w8 + 64 * MB);                    // 0.5 MB
    u16*  Wkvb = (u16*)(w8 + 64 * MB + 512 * 1024);       // 1 MB
    u16*  Web  = (u16*)(w8 + 64 * MB + 1536 * 1024);      // 1 MB
    u16*  Wcb  = (u16*)(w8 + 64 * MB + 2560 * 1024);      // 1 MB

    dim3 blk256(256);

    // weight casts only
    wcast<<<896, blk256, 0, stream>>>(Wq, Wk, Wv, We, Wc, Wqb, Wkvb, Web, Wcb);

    // Q-proj (f32 in) + phase/sincos epilogue -> A   [grid x = M-tiles]
    gemm_k<2, 1><<<dim3(64, 4), blk256, 0, stream>>>(Q, Wqb, bq, nullptr,
        Abf, nullptr, Pq, Wp, bp, DM, DM, nullptr);
    // KV-proj (f32 in) + epilogue -> B, Vt
    gemm_k<3, 1><<<dim3(64, 8), blk256, 0, stream>>>(K, Wkvb, bk, bv,
        Bbf, Vtb, Pk, Wp, bp, DM, 2 * DM, nullptr);

    // flash attention (512 blocks = 2/CU)
    attn_mfma<<<512, blk256, 0, stream>>>(Abf, Bbf, Vtb, Tbf);

    // FFN
    gemm_k<1, 0><<<dim3(64, 8), blk256, 0, stream>>>(Tbf, Web, be, nullptr,
        H1b, nullptr, nullptr, nullptr, nullptr, DM, 2 * DM, nullptr);
    gemm_k<0, 0><<<dim3(64, 4), blk256, 0, stream>>>(H1b, Wcb, bc, nullptr,
        Y, nullptr, nullptr, nullptr, nullptr, 2 * DM, DM, part);

    // BN stats + final
    bn_reduce<<<2, blk256, 0, stream>>>(part, stats);
    bn_final<<<ROWS * DM / 256, blk256, 0, stream>>>(Y, Q, stats, gamma, beta,
                                                     (float*)d_out);
}

// Round 7
// 155.156 us; speedup vs baseline: 9.0468x; 1.0223x over previous
//
#include <hip/hip_runtime.h>
#include <math.h>

#define LQ 1024      // sequence length L
#define DM 512       // model dim D
#define HN 8         // heads
#define DHD 64       // head dim
#define ROWS 8192    // N*S*L
#define DE 128       // effective attention dim (2*DHD)
#define LOG2E 1.44269504088896f

typedef __attribute__((ext_vector_type(8))) short bf16x8;
typedef __attribute__((ext_vector_type(4))) float floatx4;
typedef unsigned short u16;

static __device__ __forceinline__ u16 f2bf(float x) {
    unsigned int u = __float_as_uint(x);
    u = (u + 0x7fffu + ((u >> 16) & 1u)) >> 16;   // round-nearest-even
    return (u16)u;
}

static __device__ __forceinline__ void gload16(const void* g, void* l) {
    __builtin_amdgcn_global_load_lds((const __attribute__((address_space(1))) void*)g,
                                     (__attribute__((address_space(3))) void*)l,
                                     16, 0, 0);
}

static __device__ __forceinline__ void cvt8(const float* s, u16* d, size_t o) {
    const float4* sp = (const float4*)s + 2 * o;
    float4 a = sp[0], b = sp[1];
    union { u16 u[8]; uint4 v; } ov;
    ov.u[0]=f2bf(a.x); ov.u[1]=f2bf(a.y); ov.u[2]=f2bf(a.z); ov.u[3]=f2bf(a.w);
    ov.u[4]=f2bf(b.x); ov.u[5]=f2bf(b.y); ov.u[6]=f2bf(b.z); ov.u[7]=f2bf(b.w);
    ((uint4*)d)[o] = ov.v;
}

// ---------------------------------------------------------------------------
// weight casts
// ---------------------------------------------------------------------------
__global__ __launch_bounds__(256)
void wcast(const float* __restrict__ Wq, const float* __restrict__ Wk,
           const float* __restrict__ Wv, const float* __restrict__ We,
           const float* __restrict__ Wc,
           u16* __restrict__ Wqb, u16* __restrict__ Wkvb,
           u16* __restrict__ Web, u16* __restrict__ Wcb)
{
    int i = blockIdx.x * 256 + threadIdx.x;      // vec8 id, total 229376
    const float* s; u16* d; int o;
    if (i < 32768)        { s = Wq; d = Wqb;            o = i; }
    else if (i < 65536)   { s = Wk; d = Wkvb;           o = i - 32768; }
    else if (i < 98304)   { s = Wv; d = Wkvb + 262144;  o = i - 65536; }
    else if (i < 163840)  { s = We; d = Web;            o = i - 98304; }
    else                  { s = Wc; d = Wcb;            o = i - 163840; }
    cvt8(s, d, (size_t)o);
}

// ---------------------------------------------------------------------------
// Fused Q-proj + KV-proj (one dispatch, 768 blocks).
// bid < 256: Q @ Wq^T -> A (sin/cos, log2e folded)      [grid-local m fast]
// bid >= 256: K @ Wkv^T -> B (cols<512) / Vt (cols>=512)
// X is f32, reg-staged; W bf16 via global_load_lds. 128x128 tile, BK=64.
// ---------------------------------------------------------------------------
__global__ __launch_bounds__(256)
void gemm_qkv(const float* __restrict__ Q, const float* __restrict__ K,
              const u16* __restrict__ Wqb, const u16* __restrict__ Wkvb,
              const float* __restrict__ bq, const float* __restrict__ bk,
              const float* __restrict__ bv,
              u16* __restrict__ Abf, u16* __restrict__ Bbf, u16* __restrict__ Vtb,
              const float* __restrict__ Pq, const float* __restrict__ Pk,
              const float* __restrict__ Wp, const float* __restrict__ bp)
{
    const int bid = blockIdx.x;
    const bool isQ = bid < 256;
    const int lb = isQ ? bid : bid - 256;
    const int m0 = (lb & 63) * 128, n0 = (lb >> 6) * 128;
    const float* Xf = isQ ? Q : K;
    const u16* W = isQ ? Wqb : Wkvb;
    const int Kd = DM;

    const int tid = threadIdx.x;
    const int w = tid >> 6, lane = tid & 63;
    const int lr = lane & 15, lg = lane >> 4;
    const int wm = w >> 1, wn = w & 1;

    __shared__ __align__(16) u16 AsL[2][128 * 64];
    __shared__ __align__(16) u16 BsL[2][128 * 64];

    floatx4 acc[4][4] = {};
    const int xorp = (lr & 7) << 4;
    const int colb = lg << 4;

    auto stageW = [&](int t, int b) {
        const size_t ko = (size_t)t * 64;
        #pragma unroll
        for (int r = 0; r < 4; ++r) {
            const int cid = r * 256 + tid;
            const int row = cid >> 3, c16 = cid & 7;
            const int kc = ((c16 ^ (row & 7)) << 3);
            gload16(&W[(size_t)(n0 + row) * Kd + ko + kc], &BsL[b][cid * 8]);
        }
    };
    float4 xr[8];
    auto loadXf = [&](int t) {
        const size_t ko = (size_t)t * 64;
        #pragma unroll
        for (int r = 0; r < 4; ++r) {
            const int cid = r * 256 + tid;
            const int row = cid >> 3, c16 = cid & 7;
            const int kc = ((c16 ^ (row & 7)) << 3);
            const float* p = &Xf[(size_t)(m0 + row) * Kd + ko + kc];
            xr[2 * r]     = ((const float4*)p)[0];
            xr[2 * r + 1] = ((const float4*)p)[1];
        }
    };
    auto writeXf = [&](int b) {
        #pragma unroll
        for (int r = 0; r < 4; ++r) {
            const int cid = r * 256 + tid;
            float4 a = xr[2 * r], bb = xr[2 * r + 1];
            bf16x8 v;
            v[0]=f2bf(a.x);  v[1]=f2bf(a.y);  v[2]=f2bf(a.z);  v[3]=f2bf(a.w);
            v[4]=f2bf(bb.x); v[5]=f2bf(bb.y); v[6]=f2bf(bb.z); v[7]=f2bf(bb.w);
            *(bf16x8*)&AsL[b][cid * 8] = v;
        }
    };

    const int nt = Kd >> 6;
    loadXf(0); stageW(0, 0); writeXf(0);
    __syncthreads();
    int c = 0;
    for (int t = 0; t < nt; ++t) {
        if (t + 1 < nt) { loadXf(t + 1); stageW(t + 1, c ^ 1); }
        const char* la = (const char*)AsL[c];
        const char* lb = (const char*)BsL[c];
        #pragma unroll
        for (int ks = 0; ks < 2; ++ks) {
            const int cb = (ks * 64 + colb) ^ xorp;
            bf16x8 a[4], b[4];
            #pragma unroll
            for (int i = 0; i < 4; ++i)
                a[i] = *(const bf16x8*)(la + (((wm * 64 + i * 16 + lr) << 7) + cb));
            #pragma unroll
            for (int j = 0; j < 4; ++j)
                b[j] = *(const bf16x8*)(lb + (((wn * 64 + j * 16 + lr) << 7) + cb));
            #pragma unroll
            for (int i = 0; i < 4; ++i)
                #pragma unroll
                for (int j = 0; j < 4; ++j)
                    acc[i][j] = __builtin_amdgcn_mfma_f32_16x16x32_bf16(a[i], b[j], acc[i][j], 0, 0, 0);
        }
        if (t + 1 < nt) writeXf(c ^ 1);
        __syncthreads();
        c ^= 1;
    }

    if (isQ) {      // -> A with phases (log2e folded)
        #pragma unroll
        for (int j = 0; j < 4; ++j) {
            const int col = n0 + wn * 64 + j * 16 + lr;
            const float w0 = Wp[col * 3], w1 = Wp[col * 3 + 1], w2 = Wp[col * 3 + 2];
            const float bpd = bp[col], bi = bq[col];
            const int hh = col >> 6, dh = col & 63;
            #pragma unroll
            for (int i = 0; i < 4; ++i)
                #pragma unroll
                for (int rr = 0; rr < 4; ++rr) {
                    const int row = m0 + wm * 64 + i * 16 + lg * 4 + rr;
                    const int ns = row >> 10, l = row & 1023;
                    const float p = Pq[row * 3] * w0 + Pq[row * 3 + 1] * w1
                                  + Pq[row * 3 + 2] * w2 + bpd;
                    float sn, cs;
                    __sincosf(p, &sn, &cs);
                    const float v = acc[i][j][rr] + bi;
                    const size_t e = (((size_t)(ns * HN + hh)) * LQ + l) * DE + dh;
                    Abf[e]      = f2bf(v * sn * LOG2E);
                    Abf[e + 64] = f2bf(-v * cs * LOG2E);
                }
        }
    } else if (n0 < 512) {    // K half -> B with phases
        #pragma unroll
        for (int j = 0; j < 4; ++j) {
            const int col = n0 + wn * 64 + j * 16 + lr;
            const float w0 = Wp[col * 3], w1 = Wp[col * 3 + 1], w2 = Wp[col * 3 + 2];
            const float bi = bk[col];
            const int hh = col >> 6, dh = col & 63;
            #pragma unroll
            for (int i = 0; i < 4; ++i)
                #pragma unroll
                for (int rr = 0; rr < 4; ++rr) {
                    const int row = m0 + wm * 64 + i * 16 + lg * 4 + rr;
                    const int ns = row >> 10, l = row & 1023;
                    const float p = Pk[row * 3] * w0 + Pk[row * 3 + 1] * w1
                                  + Pk[row * 3 + 2] * w2;      // pk - b
                    float sn, cs;
                    __sincosf(p, &sn, &cs);
                    const float v = acc[i][j][rr] + bi;
                    const size_t e = (((size_t)(ns * HN + hh)) * LQ + l) * DE + dh;
                    Bbf[e]      = f2bf(v * cs);
                    Bbf[e + 64] = f2bf(v * sn);
                }
        }
    } else {                  // V half -> Vt (per-head transposed)
        #pragma unroll
        for (int j = 0; j < 4; ++j) {
            const int col = n0 + wn * 64 + j * 16 + lr;
            const int c2 = col - 512;
            const float bi = bv[c2];
            const int hh = c2 >> 6, dh = c2 & 63;
            #pragma unroll
            for (int i = 0; i < 4; ++i)
                #pragma unroll
                for (int rr = 0; rr < 4; ++rr) {
                    const int row = m0 + wm * 64 + i * 16 + lg * 4 + rr;
                    const int ns = row >> 10, l = row & 1023;
                    const float v = acc[i][j][rr] + bi;
                    Vtb[((size_t)((ns * HN + hh) * DHD + dh)) * LQ + l] = f2bf(v);
                }
        }
    }
}

// ---------------------------------------------------------------------------
// FFN GEMM (bf16 X): 128x128, BK=64, 2-phase dbuf.
// MODE 0: f32 out + bias + BN partials   MODE 1: bf16 out + bias + relu
// ---------------------------------------------------------------------------
template<int MODE>
__global__ __launch_bounds__(256)
void gemm_k(const u16* __restrict__ Xb, const u16* __restrict__ W,
            const float* __restrict__ bias, void* __restrict__ out,
            int Kd, int Nn, float* __restrict__ bnp)
{
    const int m0 = blockIdx.x * 128, n0 = blockIdx.y * 128;
    const int tid = threadIdx.x;
    const int w = tid >> 6, lane = tid & 63;
    const int lr = lane & 15, lg = lane >> 4;
    const int wm = w >> 1, wn = w & 1;

    __shared__ __align__(16) u16 AsL[2][128 * 64];
    __shared__ __align__(16) u16 BsL[2][128 * 64];
    __shared__ float BnL[2][2][4][16][2];

    floatx4 acc[4][4] = {};
    const int xorp = (lr & 7) << 4;
    const int colb = lg << 4;

    auto stage = [&](int t, int b) {
        const size_t ko = (size_t)t * 64;
        #pragma unroll
        for (int r = 0; r < 4; ++r) {
            const int cid = r * 256 + tid;
            const int row = cid >> 3, c16 = cid & 7;
            const int kc = ((c16 ^ (row & 7)) << 3);
            gload16(&Xb[(size_t)(m0 + row) * Kd + ko + kc], &AsL[b][cid * 8]);
        }
        #pragma unroll
        for (int r = 0; r < 4; ++r) {
            const int cid = r * 256 + tid;
            const int row = cid >> 3, c16 = cid & 7;
            const int kc = ((c16 ^ (row & 7)) << 3);
            gload16(&W[(size_t)(n0 + row) * Kd + ko + kc], &BsL[b][cid * 8]);
        }
    };

    const int nt = Kd >> 6;
    stage(0, 0);
    __syncthreads();
    int c = 0;
    for (int t = 0; t < nt; ++t) {
        if (t + 1 < nt) stage(t + 1, c ^ 1);
        const char* la = (const char*)AsL[c];
        const char* lb = (const char*)BsL[c];
        #pragma unroll
        for (int ks = 0; ks < 2; ++ks) {
            const int cb = (ks * 64 + colb) ^ xorp;
            bf16x8 a[4], b[4];
            #pragma unroll
            for (int i = 0; i < 4; ++i)
                a[i] = *(const bf16x8*)(la + (((wm * 64 + i * 16 + lr) << 7) + cb));
            #pragma unroll
            for (int j = 0; j < 4; ++j)
                b[j] = *(const bf16x8*)(lb + (((wn * 64 + j * 16 + lr) << 7) + cb));
            #pragma unroll
            for (int i = 0; i < 4; ++i)
                #pragma unroll
                for (int j = 0; j < 4; ++j)
                    acc[i][j] = __builtin_amdgcn_mfma_f32_16x16x32_bf16(a[i], b[j], acc[i][j], 0, 0, 0);
        }
        __syncthreads();
        c ^= 1;
    }

    float bs[4], bs2[4];
    #pragma unroll
    for (int j = 0; j < 4; ++j) { bs[j] = 0.f; bs2[j] = 0.f; }
    #pragma unroll
    for (int j = 0; j < 4; ++j) {
        const int col = n0 + wn * 64 + j * 16 + lr;
        const float bi = bias[col];
        #pragma unroll
        for (int i = 0; i < 4; ++i)
            #pragma unroll
            for (int rr = 0; rr < 4; ++rr) {
                const int row = m0 + wm * 64 + i * 16 + lg * 4 + rr;
                float v = acc[i][j][rr] + bi;
                if (MODE == 1) {
                    v = fmaxf(v, 0.f);
                    ((u16*)out)[(size_t)row * Nn + col] = f2bf(v);
                } else {
                    ((float*)out)[(size_t)row * Nn + col] = v;
                    bs[j] += v; bs2[j] += v * v;
                }
            }
    }
    if (MODE == 0) {
        #pragma unroll
        for (int j = 0; j < 4; ++j) {
            float s = bs[j], s2 = bs2[j];
            s  += __shfl_xor(s, 16);  s  += __shfl_xor(s, 32);
            s2 += __shfl_xor(s2, 16); s2 += __shfl_xor(s2, 32);
            if (lg == 0) { BnL[wm][wn][j][lr][0] = s; BnL[wm][wn][j][lr][1] = s2; }
        }
        __syncthreads();
        if (tid < 128) {
            const int wn2 = tid >> 6, j2 = (tid >> 4) & 3, lr2 = tid & 15;
            const float s  = BnL[0][wn2][j2][lr2][0] + BnL[1][wn2][j2][lr2][0];
            const float s2 = BnL[0][wn2][j2][lr2][1] + BnL[1][wn2][j2][lr2][1];
            const int col = n0 + tid;
            bnp[(size_t)blockIdx.x * 512 + col]         = s;
            bnp[32768 + (size_t)blockIdx.x * 512 + col] = s2;
        }
    }
}

// ---------------------------------------------------------------------------
// Flash attention: 512-thread blocks (8 waves), QBLK=128, KVBLK=64.
// Each wave owns one 16-q-row group; Q frags in registers; no-max softmax;
// counted-vmcnt dual-barrier staging. 2 blocks/CU = 4 waves/SIMD.
// ---------------------------------------------------------------------------
__global__ __launch_bounds__(512, 4)
void attn_mfma(const u16* __restrict__ Ag, const u16* __restrict__ Bg,
               const u16* __restrict__ Vtg, u16* __restrict__ Tbf)
{
    int bid = blockIdx.x;
    bid = (bid & 7) * 64 + (bid >> 3);    // XCD swizzle (512 % 8 == 0)
    const int head = bid >> 3;            // 0..63
    const int row0 = (bid & 7) * 128;
    const int ns = head >> 3, h = head & 7;
    const int tid = threadIdx.x, w = tid >> 6, lane = tid & 63;
    const int lr = lane & 15, lg = lane >> 4;

    __shared__ __align__(16) u16 BsL[2][64 * 128];   // 32 KB
    __shared__ __align__(16) u16 VtL[2][64 * 64];    // 16 KB
    __shared__ __align__(16) u16 Ps[8][16][72];      // 18 KB

    // Q fragments -> registers (wave w: q rows row0 + w*16 .. +15)
    bf16x8 qf[4];
    {
        const size_t rb = ((size_t)head * LQ + row0 + w * 16 + lr) * DE;
        #pragma unroll
        for (int ks = 0; ks < 4; ++ks)
            qf[ks] = *(const bf16x8*)&Ag[rb + ks * 32 + lg * 8];
    }

    auto stageBV = [&](int kt, int b) {
        #pragma unroll
        for (int r = 0; r < 2; ++r) {                 // B tile 16 KB
            const int cid = r * 512 + tid;
            const int row = cid >> 4, c16 = cid & 15;
            const int kc = ((c16 ^ (row & 7)) << 3);
            gload16(&Bg[((size_t)head * LQ + kt * 64 + row) * DE + kc], &BsL[b][cid * 8]);
        }
        {                                             // Vt tile 8 KB
            const int row = tid >> 3, c16 = tid & 7;
            const int kc = ((c16 ^ (row & 7)) << 3);
            gload16(&Vtg[((size_t)head * DHD + row) * LQ + kt * 64 + kc], &VtL[b][tid * 8]);
        }
    };
    stageBV(0, 0);

    floatx4 o[4] = {};
    float lsum = 0.f;
    const int xorp = (lr & 7) << 4;
    const int colb = lg << 4;
    int c = 0;

    for (int kt = 0; kt < 16; ++kt) {
        if (kt < 15) {
            stageBV(kt + 1, c ^ 1);                   // 3 loads stay in flight
            asm volatile("s_waitcnt vmcnt(3)" ::: "memory");
        } else {
            asm volatile("s_waitcnt vmcnt(0)" ::: "memory");
        }
        __builtin_amdgcn_sched_barrier(0);
        __builtin_amdgcn_s_barrier();                 // tile kt staged for all waves

        const char* lb = (const char*)BsL[c];
        const char* lv = (const char*)VtL[c];

        // ---- S^T = K-rows x Q-cols: lane holds 16 keys for q = lr ----
        floatx4 s[4] = {};
        __builtin_amdgcn_s_setprio(1);
        #pragma unroll
        for (int ks = 0; ks < 4; ++ks) {
            const int cb = (ks * 64 + colb) ^ xorp;
            #pragma unroll
            for (int j = 0; j < 4; ++j) {
                bf16x8 kf = *(const bf16x8*)(lb + (((j * 16 + lr) << 8) + cb));
                s[j] = __builtin_amdgcn_mfma_f32_16x16x32_bf16(kf, qf[ks], s[j], 0, 0, 0);
            }
        }
        __builtin_amdgcn_s_setprio(0);

        // ---- no-max softmax ----
        float ts = 0.f;
        #pragma unroll
        for (int j = 0; j < 4; ++j)
            #pragma unroll
            for (int r = 0; r < 4; ++r) {
                const float e = exp2f(s[j][r]);
                s[j][r] = e;
                ts += e;
            }
        lsum += ts;

        // ---- P -> per-wave LDS (cvt_pk pack) ----
        #pragma unroll
        for (int j = 0; j < 4; ++j) {
            unsigned plo, phi;
            asm("v_cvt_pk_bf16_f32 %0, %1, %2" : "=v"(plo) : "v"(s[j][0]), "v"(s[j][1]));
            asm("v_cvt_pk_bf16_f32 %0, %1, %2" : "=v"(phi) : "v"(s[j][2]), "v"(s[j][3]));
            uint2 pv; pv.x = plo; pv.y = phi;
            *(uint2*)&Ps[w][lr][j * 16 + lg * 4] = pv;
        }

        // ---- PV: O^T[d][q] += Vt[d][k] * P^T[k][q] ----
        __builtin_amdgcn_s_setprio(1);
        #pragma unroll
        for (int ks2 = 0; ks2 < 2; ++ks2) {
            bf16x8 pf = *(const bf16x8*)&Ps[w][lr][ks2 * 32 + lg * 8];
            const int cb = (ks2 * 64 + colb) ^ xorp;
            #pragma unroll
            for (int m = 0; m < 4; ++m) {
                bf16x8 vf = *(const bf16x8*)(lv + (((m * 16 + lr) << 7) + cb));
                o[m] = __builtin_amdgcn_mfma_f32_16x16x32_bf16(vf, pf, o[m], 0, 0, 0);
            }
        }
        __builtin_amdgcn_s_setprio(0);
        __builtin_amdgcn_s_barrier();                 // all waves done with buf c
        __builtin_amdgcn_sched_barrier(0);
        c ^= 1;
    }

    // denominator (once), normalize, write merged-head T (bf16)
    lsum += __shfl_xor(lsum, 16);
    lsum += __shfl_xor(lsum, 32);
    const float inv = 1.f / lsum;
    const size_t trow = ((size_t)ns * LQ + row0 + w * 16 + lr) * DM + h * DHD;
    #pragma unroll
    for (int m = 0; m < 4; ++m) {
        union { u16 u[4]; uint2 v; } pk;
        pk.u[0] = f2bf(o[m][0] * inv); pk.u[1] = f2bf(o[m][1] * inv);
        pk.u[2] = f2bf(o[m][2] * inv); pk.u[3] = f2bf(o[m][3] * inv);
        *(uint2*)&Tbf[trow + m * 16 + lg * 4] = pk.v;
    }
}

// ---------------------------------------------------------------------------
// BN: reduce per-block partials (64 m-blocks) -> stats; then final
// ---------------------------------------------------------------------------
__global__ __launch_bounds__(256)
void bn_reduce(const float* __restrict__ part, float* __restrict__ stats)
{
    const int cx = blockIdx.x * 256 + threadIdx.x;   // 0..511
    float s = 0.f, s2 = 0.f;
    for (int b = 0; b < 64; ++b) {
        s  += part[(size_t)b * 512 + cx];
        s2 += part[32768 + (size_t)b * 512 + cx];
    }
    stats[cx] = s;
    stats[512 + cx] = s2;
}

__global__ __launch_bounds__(256)
void bn_final(const float* __restrict__ Y, const float* __restrict__ Qin,
              const float* __restrict__ stats,
              const float* __restrict__ gamma, const float* __restrict__ beta,
              float* __restrict__ out)
{
    const int i = blockIdx.x * 256 + threadIdx.x;
    const int c = i & (DM - 1);
    const float mu  = stats[c] * (1.f / ROWS);
    const float var = stats[512 + c] * (1.f / ROWS) - mu * mu;
    const float rs  = rsqrtf(var + 1e-5f);
    out[i] = Qin[i] + (Y[i] - mu) * rs * gamma[c] + beta[c];
}

// ---------------------------------------------------------------------------
extern "C" void kernel_launch(void* const* d_in, const int* in_sizes, int n_in,
                              void* d_out, int out_size, void* d_ws, size_t ws_size,
                              hipStream_t stream)
{
    (void)in_sizes; (void)n_in; (void)out_size; (void)ws_size;

    const float* Q    = (const float*)d_in[0];
    const float* K    = (const float*)d_in[1];
    const float* Pq   = (const float*)d_in[2];
    const float* Pk   = (const float*)d_in[3];
    const float* Wq   = (const float*)d_in[4];
    const float* bq   = (const float*)d_in[5];
    const float* Wk   = (const float*)d_in[6];
    const float* bk   = (const float*)d_in[7];
    const float* Wv   = (const float*)d_in[8];
    const float* bv   = (const float*)d_in[9];
    const float* Wp   = (const float*)d_in[10];
    const float* bp   = (const float*)d_in[11];
    const float* We   = (const float*)d_in[12];
    const float* be   = (const float*)d_in[13];
    const float* Wc   = (const float*)d_in[14];
    const float* bc   = (const float*)d_in[15];
    const float* gamma= (const float*)d_in[16];
    const float* beta = (const float*)d_in[17];

    const size_t MB = 1u << 20;
    char* w8 = (char*)d_ws;
    u16*  Abf  = (u16*)(w8);                  // 16 MB (A operands)
    u16*  Bbf  = (u16*)(w8 + 16 * MB);        // 16 MB
    u16*  Vtb  = (u16*)(w8 + 32 * MB);        //  8 MB
    u16*  Tbf  = (u16*)(w8 + 40 * MB);        //  8 MB
    u16*  H1b  = (u16*)(w8 + 48 * MB);        // 16 MB
    float* Y   = (float*)(w8);                // 16 MB (reuses Abf after attn)
    float* part  = (float*)(w8 + 16 * MB);    // 256 KB (reuses Bbf after attn)
    float* stats = (float*)(w8 + 17 * MB);    //  4 KB
    u16*  Wqb  = (u16*)(w8 + 64 * MB);                    // 0.5 MB
    u16*  Wkvb = (u16*)(w8 + 64 * MB + 512 * 1024);       // 1 MB
    u16*  Web  = (u16*)(w8 + 64 * MB + 1536 * 1024);      // 1 MB
    u16*  Wcb  = (u16*)(w8 + 64 * MB + 2560 * 1024);      // 1 MB

    dim3 blk256(256);

    // weight casts
    wcast<<<896, blk256, 0, stream>>>(Wq, Wk, Wv, We, Wc, Wqb, Wkvb, Web, Wcb);

    // fused Q-proj + KV-proj (one dispatch, 768 blocks)
    gemm_qkv<<<768, blk256, 0, stream>>>(Q, K, Wqb, Wkvb, bq, bk, bv,
                                         Abf, Bbf, Vtb, Pq, Pk, Wp, bp);

    // flash attention (512 blocks x 8 waves = 4 waves/SIMD)
    attn_mfma<<<512, dim3(512), 0, stream>>>(Abf, Bbf, Vtb, Tbf);

    // FFN
    gemm_k<1><<<dim3(64, 8), blk256, 0, stream>>>(Tbf, Web, be, H1b, DM, 2 * DM, nullptr);
    gemm_k<0><<<dim3(64, 4), blk256, 0, stream>>>(H1b, Wcb, bc, Y, 2 * DM, DM, part);

    // BN stats + final
    bn_reduce<<<2, blk256, 0, stream>>>(part, stats);
    bn_final<<<ROWS * DM / 256, blk256, 0, stream>>>(Y, Q, stats, gamma, beta,
                                                     (float*)d_out);
}

// Round 8
// 149.352 us; speedup vs baseline: 9.3984x; 1.0389x over previous
//
#include <hip/hip_runtime.h>
#include <math.h>

#define LQ 1024      // sequence length L
#define DM 512       // model dim D
#define HN 8         // heads
#define DHD 64       // head dim
#define ROWS 8192    // N*S*L
#define DE 128       // effective attention dim (2*DHD)
#define LOG2E 1.44269504088896f

typedef __attribute__((ext_vector_type(8))) short bf16x8;
typedef __attribute__((ext_vector_type(4))) float floatx4;
typedef unsigned short u16;

static __device__ __forceinline__ u16 f2bf(float x) {
    unsigned int u = __float_as_uint(x);
    u = (u + 0x7fffu + ((u >> 16) & 1u)) >> 16;   // round-nearest-even
    return (u16)u;
}

static __device__ __forceinline__ void gload16(const void* g, void* l) {
    __builtin_amdgcn_global_load_lds((const __attribute__((address_space(1))) void*)g,
                                     (__attribute__((address_space(3))) void*)l,
                                     16, 0, 0);
}

static __device__ __forceinline__ void cvt8(const float* s, u16* d, size_t o) {
    const float4* sp = (const float4*)s + 2 * o;
    float4 a = sp[0], b = sp[1];
    union { u16 u[8]; uint4 v; } ov;
    ov.u[0]=f2bf(a.x); ov.u[1]=f2bf(a.y); ov.u[2]=f2bf(a.z); ov.u[3]=f2bf(a.w);
    ov.u[4]=f2bf(b.x); ov.u[5]=f2bf(b.y); ov.u[6]=f2bf(b.z); ov.u[7]=f2bf(b.w);
    ((uint4*)d)[o] = ov.v;
}

// ---------------------------------------------------------------------------
// one fused cast dispatch: all weights + Q + K  (memory-bound)
// ---------------------------------------------------------------------------
__global__ __launch_bounds__(256)
void castall(const float* __restrict__ Wq, const float* __restrict__ Wk,
             const float* __restrict__ Wv, const float* __restrict__ We,
             const float* __restrict__ Wc, const float* __restrict__ Q,
             const float* __restrict__ K,
             u16* __restrict__ Wqb, u16* __restrict__ Wkvb,
             u16* __restrict__ Web, u16* __restrict__ Wcb,
             u16* __restrict__ Qb, u16* __restrict__ Kb)
{
    int i = blockIdx.x * 256 + threadIdx.x;      // vec8 id, total 1277952
    const float* s; u16* d; int o;
    if (i < 32768)        { s = Wq; d = Wqb;            o = i; }
    else if (i < 65536)   { s = Wk; d = Wkvb;           o = i - 32768; }
    else if (i < 98304)   { s = Wv; d = Wkvb + 262144;  o = i - 65536; }
    else if (i < 163840)  { s = We; d = Web;            o = i - 98304; }
    else if (i < 229376)  { s = Wc; d = Wcb;            o = i - 163840; }
    else if (i < 753664)  { s = Q;  d = Qb;             o = i - 229376; }
    else                  { s = K;  d = Kb;             o = i - 753664; }
    cvt8(s, d, (size_t)o);
}

// ---------------------------------------------------------------------------
// bf16 MFMA GEMM, 128x128, BK=64, counted-vmcnt dual-barrier 2-phase dbuf,
// pure global_load_lds staging w/ XOR swizzle. blockIdx.x = M-tile (fast).
// MODE 0: f32 out + bias + BN partials   MODE 1: bf16 out + bias + relu
// MODE 2: Q-proj -> A (sin/cos, log2e)   MODE 3: KV-proj -> B / Vt
// ---------------------------------------------------------------------------
template<int MODE>
__global__ __launch_bounds__(256)
void gemm_k(const u16* __restrict__ Xb, const u16* __restrict__ W,
            const float* __restrict__ bias, const float* __restrict__ bias2,
            void* __restrict__ out, u16* __restrict__ out2,
            const float* __restrict__ Pph, const float* __restrict__ Wp,
            const float* __restrict__ bp, int Kd, int Nn,
            float* __restrict__ bnp)
{
    const int m0 = blockIdx.x * 128, n0 = blockIdx.y * 128;
    const int tid = threadIdx.x;
    const int w = tid >> 6, lane = tid & 63;
    const int lr = lane & 15, lg = lane >> 4;
    const int wm = w >> 1, wn = w & 1;

    __shared__ __align__(16) u16 AsL[2][128 * 64];
    __shared__ __align__(16) u16 BsL[2][128 * 64];
    __shared__ float BnL[2][2][4][16][2];

    floatx4 acc[4][4] = {};
    const int xorp = (lr & 7) << 4;
    const int colb = lg << 4;

    auto stage = [&](int t, int b) {
        const size_t ko = (size_t)t * 64;
        #pragma unroll
        for (int r = 0; r < 4; ++r) {
            const int cid = r * 256 + tid;
            const int row = cid >> 3, c16 = cid & 7;
            const int kc = ((c16 ^ (row & 7)) << 3);
            gload16(&Xb[(size_t)(m0 + row) * Kd + ko + kc], &AsL[b][cid * 8]);
        }
        #pragma unroll
        for (int r = 0; r < 4; ++r) {
            const int cid = r * 256 + tid;
            const int row = cid >> 3, c16 = cid & 7;
            const int kc = ((c16 ^ (row & 7)) << 3);
            gload16(&W[(size_t)(n0 + row) * Kd + ko + kc], &BsL[b][cid * 8]);
        }
    };

    const int nt = Kd >> 6;
    stage(0, 0);
    int c = 0;
    for (int t = 0; t < nt; ++t) {
        if (t + 1 < nt) {
            stage(t + 1, c ^ 1);                       // 8 loads stay in flight
            asm volatile("s_waitcnt vmcnt(8)" ::: "memory");
        } else {
            asm volatile("s_waitcnt vmcnt(0)" ::: "memory");
        }
        __builtin_amdgcn_sched_barrier(0);
        __builtin_amdgcn_s_barrier();                  // buf c staged for all waves

        const char* la = (const char*)AsL[c];
        const char* lb = (const char*)BsL[c];
        __builtin_amdgcn_s_setprio(1);
        #pragma unroll
        for (int ks = 0; ks < 2; ++ks) {
            const int cb = (ks * 64 + colb) ^ xorp;
            bf16x8 a[4], b[4];
            #pragma unroll
            for (int i = 0; i < 4; ++i)
                a[i] = *(const bf16x8*)(la + (((wm * 64 + i * 16 + lr) << 7) + cb));
            #pragma unroll
            for (int j = 0; j < 4; ++j)
                b[j] = *(const bf16x8*)(lb + (((wn * 64 + j * 16 + lr) << 7) + cb));
            #pragma unroll
            for (int i = 0; i < 4; ++i)
                #pragma unroll
                for (int j = 0; j < 4; ++j)
                    acc[i][j] = __builtin_amdgcn_mfma_f32_16x16x32_bf16(a[i], b[j], acc[i][j], 0, 0, 0);
        }
        __builtin_amdgcn_s_setprio(0);
        __builtin_amdgcn_s_barrier();                  // all waves done reading buf c
        __builtin_amdgcn_sched_barrier(0);
        c ^= 1;
    }

    if (MODE <= 1) {
        float bs[4], bs2[4];
        #pragma unroll
        for (int j = 0; j < 4; ++j) { bs[j] = 0.f; bs2[j] = 0.f; }
        #pragma unroll
        for (int j = 0; j < 4; ++j) {
            const int col = n0 + wn * 64 + j * 16 + lr;
            const float bi = bias[col];
            #pragma unroll
            for (int i = 0; i < 4; ++i)
                #pragma unroll
                for (int rr = 0; rr < 4; ++rr) {
                    const int row = m0 + wm * 64 + i * 16 + lg * 4 + rr;
                    float v = acc[i][j][rr] + bi;
                    if (MODE == 1) {
                        v = fmaxf(v, 0.f);
                        ((u16*)out)[(size_t)row * Nn + col] = f2bf(v);
                    } else {
                        ((float*)out)[(size_t)row * Nn + col] = v;
                        bs[j] += v; bs2[j] += v * v;
                    }
                }
        }
        if (MODE == 0) {    // BN partial over this m-tile's 128 rows
            #pragma unroll
            for (int j = 0; j < 4; ++j) {
                float s = bs[j], s2 = bs2[j];
                s  += __shfl_xor(s, 16);  s  += __shfl_xor(s, 32);
                s2 += __shfl_xor(s2, 16); s2 += __shfl_xor(s2, 32);
                if (lg == 0) { BnL[wm][wn][j][lr][0] = s; BnL[wm][wn][j][lr][1] = s2; }
            }
            __syncthreads();
            if (tid < 128) {
                const int wn2 = tid >> 6, j2 = (tid >> 4) & 3, lr2 = tid & 15;
                const float s  = BnL[0][wn2][j2][lr2][0] + BnL[1][wn2][j2][lr2][0];
                const float s2 = BnL[0][wn2][j2][lr2][1] + BnL[1][wn2][j2][lr2][1];
                const int col = n0 + tid;
                bnp[(size_t)blockIdx.x * 512 + col]         = s;
                bnp[32768 + (size_t)blockIdx.x * 512 + col] = s2;
            }
        }
    } else if (MODE == 2) {
        u16* A = (u16*)out;
        #pragma unroll
        for (int j = 0; j < 4; ++j) {
            const int col = n0 + wn * 64 + j * 16 + lr;
            const float w0 = Wp[col * 3], w1 = Wp[col * 3 + 1], w2 = Wp[col * 3 + 2];
            const float bpd = bp[col], bi = bias[col];
            const int hh = col >> 6, dh = col & 63;
            #pragma unroll
            for (int i = 0; i < 4; ++i)
                #pragma unroll
                for (int rr = 0; rr < 4; ++rr) {
                    const int row = m0 + wm * 64 + i * 16 + lg * 4 + rr;
                    const int ns = row >> 10, l = row & 1023;
                    const float p = Pph[row * 3] * w0 + Pph[row * 3 + 1] * w1
                                  + Pph[row * 3 + 2] * w2 + bpd;
                    float sn, cs;
                    __sincosf(p, &sn, &cs);
                    const float v = acc[i][j][rr] + bi;
                    const size_t e = (((size_t)(ns * HN + hh)) * LQ + l) * DE + dh;
                    A[e]      = f2bf(v * sn * LOG2E);
                    A[e + 64] = f2bf(-v * cs * LOG2E);
                }
        }
    } else {   // MODE 3
        if (n0 < 512) {     // K half -> B with phases
            u16* B = (u16*)out;
            #pragma unroll
            for (int j = 0; j < 4; ++j) {
                const int col = n0 + wn * 64 + j * 16 + lr;
                const float w0 = Wp[col * 3], w1 = Wp[col * 3 + 1], w2 = Wp[col * 3 + 2];
                const float bi = bias[col];
                const int hh = col >> 6, dh = col & 63;
                #pragma unroll
                for (int i = 0; i < 4; ++i)
                    #pragma unroll
                    for (int rr = 0; rr < 4; ++rr) {
                        const int row = m0 + wm * 64 + i * 16 + lg * 4 + rr;
                        const int ns = row >> 10, l = row & 1023;
                        const float p = Pph[row * 3] * w0 + Pph[row * 3 + 1] * w1
                                      + Pph[row * 3 + 2] * w2;      // pk - b
                        float sn, cs;
                        __sincosf(p, &sn, &cs);
                        const float v = acc[i][j][rr] + bi;
                        const size_t e = (((size_t)(ns * HN + hh)) * LQ + l) * DE + dh;
                        B[e]      = f2bf(v * cs);
                        B[e + 64] = f2bf(v * sn);
                    }
            }
        } else {            // V half -> Vt (per-head transposed)
            #pragma unroll
            for (int j = 0; j < 4; ++j) {
                const int col = n0 + wn * 64 + j * 16 + lr;
                const int c2 = col - 512;
                const float bi = bias2[c2];
                const int hh = c2 >> 6, dh = c2 & 63;
                #pragma unroll
                for (int i = 0; i < 4; ++i)
                    #pragma unroll
                    for (int rr = 0; rr < 4; ++rr) {
                        const int row = m0 + wm * 64 + i * 16 + lg * 4 + rr;
                        const int ns = row >> 10, l = row & 1023;
                        const float v = acc[i][j][rr] + bi;
                        out2[((size_t)((ns * HN + hh) * DHD + dh)) * LQ + l] = f2bf(v);
                    }
            }
        }
    }
}

// ---------------------------------------------------------------------------
// Flash attention: 512-thread blocks (8 waves), QBLK=128, KVBLK=64.
// Each wave owns one 16-q-row group; Q frags in registers; no-max softmax;
// counted-vmcnt dual-barrier staging. 2 blocks/CU = 4 waves/SIMD.
// ---------------------------------------------------------------------------
__global__ __launch_bounds__(512, 4)
void attn_mfma(const u16* __restrict__ Ag, const u16* __restrict__ Bg,
               const u16* __restrict__ Vtg, u16* __restrict__ Tbf)
{
    int bid = blockIdx.x;
    bid = (bid & 7) * 64 + (bid >> 3);    // XCD swizzle (512 % 8 == 0)
    const int head = bid >> 3;            // 0..63
    const int row0 = (bid & 7) * 128;
    const int ns = head >> 3, h = head & 7;
    const int tid = threadIdx.x, w = tid >> 6, lane = tid & 63;
    const int lr = lane & 15, lg = lane >> 4;

    __shared__ __align__(16) u16 BsL[2][64 * 128];   // 32 KB
    __shared__ __align__(16) u16 VtL[2][64 * 64];    // 16 KB
    __shared__ __align__(16) u16 Ps[8][16][72];      // 18 KB

    // Q fragments -> registers (wave w: q rows row0 + w*16 .. +15)
    bf16x8 qf[4];
    {
        const size_t rb = ((size_t)head * LQ + row0 + w * 16 + lr) * DE;
        #pragma unroll
        for (int ks = 0; ks < 4; ++ks)
            qf[ks] = *(const bf16x8*)&Ag[rb + ks * 32 + lg * 8];
    }

    auto stageBV = [&](int kt, int b) {
        #pragma unroll
        for (int r = 0; r < 2; ++r) {                 // B tile 16 KB
            const int cid = r * 512 + tid;
            const int row = cid >> 4, c16 = cid & 15;
            const int kc = ((c16 ^ (row & 7)) << 3);
            gload16(&Bg[((size_t)head * LQ + kt * 64 + row) * DE + kc], &BsL[b][cid * 8]);
        }
        {                                             // Vt tile 8 KB
            const int row = tid >> 3, c16 = tid & 7;
            const int kc = ((c16 ^ (row & 7)) << 3);
            gload16(&Vtg[((size_t)head * DHD + row) * LQ + kt * 64 + kc], &VtL[b][tid * 8]);
        }
    };
    stageBV(0, 0);

    floatx4 o[4] = {};
    float lsum = 0.f;
    const int xorp = (lr & 7) << 4;
    const int colb = lg << 4;
    int c = 0;

    for (int kt = 0; kt < 16; ++kt) {
        if (kt < 15) {
            stageBV(kt + 1, c ^ 1);                   // 3 loads stay in flight
            asm volatile("s_waitcnt vmcnt(3)" ::: "memory");
        } else {
            asm volatile("s_waitcnt vmcnt(0)" ::: "memory");
        }
        __builtin_amdgcn_sched_barrier(0);
        __builtin_amdgcn_s_barrier();                 // tile kt staged for all waves

        const char* lb = (const char*)BsL[c];
        const char* lv = (const char*)VtL[c];

        // ---- S^T = K-rows x Q-cols: lane holds 16 keys for q = lr ----
        floatx4 s[4] = {};
        __builtin_amdgcn_s_setprio(1);
        #pragma unroll
        for (int ks = 0; ks < 4; ++ks) {
            const int cb = (ks * 64 + colb) ^ xorp;
            #pragma unroll
            for (int j = 0; j < 4; ++j) {
                bf16x8 kf = *(const bf16x8*)(lb + (((j * 16 + lr) << 8) + cb));
                s[j] = __builtin_amdgcn_mfma_f32_16x16x32_bf16(kf, qf[ks], s[j], 0, 0, 0);
            }
        }
        __builtin_amdgcn_s_setprio(0);

        // ---- no-max softmax ----
        float ts = 0.f;
        #pragma unroll
        for (int j = 0; j < 4; ++j)
            #pragma unroll
            for (int r = 0; r < 4; ++r) {
                const float e = exp2f(s[j][r]);
                s[j][r] = e;
                ts += e;
            }
        lsum += ts;

        // ---- P -> per-wave LDS (cvt_pk pack) ----
        #pragma unroll
        for (int j = 0; j < 4; ++j) {
            unsigned plo, phi;
            asm("v_cvt_pk_bf16_f32 %0, %1, %2" : "=v"(plo) : "v"(s[j][0]), "v"(s[j][1]));
            asm("v_cvt_pk_bf16_f32 %0, %1, %2" : "=v"(phi) : "v"(s[j][2]), "v"(s[j][3]));
            uint2 pv; pv.x = plo; pv.y = phi;
            *(uint2*)&Ps[w][lr][j * 16 + lg * 4] = pv;
        }

        // ---- PV: O^T[d][q] += Vt[d][k] * P^T[k][q] ----
        __builtin_amdgcn_s_setprio(1);
        #pragma unroll
        for (int ks2 = 0; ks2 < 2; ++ks2) {
            bf16x8 pf = *(const bf16x8*)&Ps[w][lr][ks2 * 32 + lg * 8];
            const int cb = (ks2 * 64 + colb) ^ xorp;
            #pragma unroll
            for (int m = 0; m < 4; ++m) {
                bf16x8 vf = *(const bf16x8*)(lv + (((m * 16 + lr) << 7) + cb));
                o[m] = __builtin_amdgcn_mfma_f32_16x16x32_bf16(vf, pf, o[m], 0, 0, 0);
            }
        }
        __builtin_amdgcn_s_setprio(0);
        __builtin_amdgcn_s_barrier();                 // all waves done with buf c
        __builtin_amdgcn_sched_barrier(0);
        c ^= 1;
    }

    // denominator (once), normalize, write merged-head T (bf16)
    lsum += __shfl_xor(lsum, 16);
    lsum += __shfl_xor(lsum, 32);
    const float inv = 1.f / lsum;
    const size_t trow = ((size_t)ns * LQ + row0 + w * 16 + lr) * DM + h * DHD;
    #pragma unroll
    for (int m = 0; m < 4; ++m) {
        union { u16 u[4]; uint2 v; } pk;
        pk.u[0] = f2bf(o[m][0] * inv); pk.u[1] = f2bf(o[m][1] * inv);
        pk.u[2] = f2bf(o[m][2] * inv); pk.u[3] = f2bf(o[m][3] * inv);
        *(uint2*)&Tbf[trow + m * 16 + lg * 4] = pk.v;
    }
}

// ---------------------------------------------------------------------------
// BN: reduce per-block partials (64 m-blocks) -> stats; then final
// ---------------------------------------------------------------------------
__global__ __launch_bounds__(256)
void bn_reduce(const float* __restrict__ part, float* __restrict__ stats)
{
    const int cx = blockIdx.x * 256 + threadIdx.x;   // 0..511
    float s = 0.f, s2 = 0.f;
    for (int b = 0; b < 64; ++b) {
        s  += part[(size_t)b * 512 + cx];
        s2 += part[32768 + (size_t)b * 512 + cx];
    }
    stats[cx] = s;
    stats[512 + cx] = s2;
}

__global__ __launch_bounds__(256)
void bn_final(const float* __restrict__ Y, const float* __restrict__ Qin,
              const float* __restrict__ stats,
              const float* __restrict__ gamma, const float* __restrict__ beta,
              float* __restrict__ out)
{
    const int i = blockIdx.x * 256 + threadIdx.x;
    const int c = i & (DM - 1);
    const float mu  = stats[c] * (1.f / ROWS);
    const float var = stats[512 + c] * (1.f / ROWS) - mu * mu;
    const float rs  = rsqrtf(var + 1e-5f);
    out[i] = Qin[i] + (Y[i] - mu) * rs * gamma[c] + beta[c];
}

// ---------------------------------------------------------------------------
extern "C" void kernel_launch(void* const* d_in, const int* in_sizes, int n_in,
                              void* d_out, int out_size, void* d_ws, size_t ws_size,
                              hipStream_t stream)
{
    (void)in_sizes; (void)n_in; (void)out_size; (void)ws_size;

    const float* Q    = (const float*)d_in[0];
    const float* K    = (const float*)d_in[1];
    const float* Pq   = (const float*)d_in[2];
    const float* Pk   = (const float*)d_in[3];
    const float* Wq   = (const float*)d_in[4];
    const float* bq   = (const float*)d_in[5];
    const float* Wk   = (const float*)d_in[6];
    const float* bk   = (const float*)d_in[7];
    const float* Wv   = (const float*)d_in[8];
    const float* bv   = (const float*)d_in[9];
    const float* Wp   = (const float*)d_in[10];
    const float* bp   = (const float*)d_in[11];
    const float* We   = (const float*)d_in[12];
    const float* be   = (const float*)d_in[13];
    const float* Wc   = (const float*)d_in[14];
    const float* bc   = (const float*)d_in[15];
    const float* gamma= (const float*)d_in[16];
    const float* beta = (const float*)d_in[17];

    const size_t MB = 1u << 20;
    char* w8 = (char*)d_ws;
    u16*  Abf  = (u16*)(w8);                  // 16 MB (A operands)
    u16*  Bbf  = (u16*)(w8 + 16 * MB);        // 16 MB
    u16*  Vtb  = (u16*)(w8 + 32 * MB);        //  8 MB
    u16*  Tbf  = (u16*)(w8 + 40 * MB);        //  8 MB
    u16*  H1b  = (u16*)(w8 + 48 * MB);        // 16 MB
    u16*  Qbf  = (u16*)(w8 + 64 * MB);        //  8 MB
    u16*  Kbf  = (u16*)(w8 + 72 * MB);        //  8 MB
    float* Y   = (float*)(w8);                // 16 MB (reuses Abf after attn)
    float* part  = (float*)(w8 + 16 * MB);    // 256 KB (reuses Bbf after attn)
    float* stats = (float*)(w8 + 17 * MB);    //  4 KB
    u16*  Wqb  = (u16*)(w8 + 80 * MB);                    // 0.5 MB
    u16*  Wkvb = (u16*)(w8 + 80 * MB + 512 * 1024);       // 1 MB
    u16*  Web  = (u16*)(w8 + 80 * MB + 1536 * 1024);      // 1 MB
    u16*  Wcb  = (u16*)(w8 + 80 * MB + 2560 * 1024);      // 1 MB

    dim3 blk256(256);

    // one fused cast: weights + Q + K
    castall<<<4992, blk256, 0, stream>>>(Wq, Wk, Wv, We, Wc, Q, K,
                                         Wqb, Wkvb, Web, Wcb, Qbf, Kbf);

    // Q-proj + phase epilogue -> A   (pure gload_lds path)
    gemm_k<2><<<dim3(64, 4), blk256, 0, stream>>>(Qbf, Wqb, bq, nullptr,
        Abf, nullptr, Pq, Wp, bp, DM, DM, nullptr);
    // KV-proj + epilogue -> B, Vt
    gemm_k<3><<<dim3(64, 8), blk256, 0, stream>>>(Kbf, Wkvb, bk, bv,
        Bbf, Vtb, Pk, Wp, bp, DM, 2 * DM, nullptr);

    // flash attention (512 blocks x 8 waves = 4 waves/SIMD)
    attn_mfma<<<512, dim3(512), 0, stream>>>(Abf, Bbf, Vtb, Tbf);

    // FFN
    gemm_k<1><<<dim3(64, 8), blk256, 0, stream>>>(Tbf, Web, be, nullptr,
        H1b, nullptr, nullptr, nullptr, nullptr, DM, 2 * DM, nullptr);
    gemm_k<0><<<dim3(64, 4), blk256, 0, stream>>>(H1b, Wcb, bc, nullptr,
        Y, nullptr, nullptr, nullptr, nullptr, 2 * DM, DM, part);

    // BN stats + final
    bn_reduce<<<2, blk256, 0, stream>>>(part, stats);
    bn_final<<<ROWS * DM / 256, blk256, 0, stream>>>(Y, Q, stats, gamma, beta,
                                                     (float*)d_out);
}

// Round 9
// 148.261 us; speedup vs baseline: 9.4676x; 1.0074x over previous
//
#include <hip/hip_runtime.h>
#include <math.h>

#define LQ 1024      // sequence length L
#define DM 512       // model dim D
#define HN 8         // heads
#define DHD 64       // head dim
#define ROWS 8192    // N*S*L
#define DE 128       // effective attention dim (2*DHD)
#define LOG2E 1.44269504088896f

typedef __attribute__((ext_vector_type(8))) short bf16x8;
typedef __attribute__((ext_vector_type(4))) float floatx4;
typedef unsigned short u16;

static __device__ __forceinline__ u16 f2bf(float x) {
    unsigned int u = __float_as_uint(x);
    u = (u + 0x7fffu + ((u >> 16) & 1u)) >> 16;   // round-nearest-even
    return (u16)u;
}

static __device__ __forceinline__ void gload16(const void* g, void* l) {
    __builtin_amdgcn_global_load_lds((const __attribute__((address_space(1))) void*)g,
                                     (__attribute__((address_space(3))) void*)l,
                                     16, 0, 0);
}

static __device__ __forceinline__ void cvt8(const float* s, u16* d, size_t o) {
    const float4* sp = (const float4*)s + 2 * o;
    float4 a = sp[0], b = sp[1];
    union { u16 u[8]; uint4 v; } ov;
    ov.u[0]=f2bf(a.x); ov.u[1]=f2bf(a.y); ov.u[2]=f2bf(a.z); ov.u[3]=f2bf(a.w);
    ov.u[4]=f2bf(b.x); ov.u[5]=f2bf(b.y); ov.u[6]=f2bf(b.z); ov.u[7]=f2bf(b.w);
    ((uint4*)d)[o] = ov.v;
}

// ---------------------------------------------------------------------------
// one fused cast dispatch: all weights + Q + K  (memory-bound)
// ---------------------------------------------------------------------------
__global__ __launch_bounds__(256)
void castall(const float* __restrict__ Wq, const float* __restrict__ Wk,
             const float* __restrict__ Wv, const float* __restrict__ We,
             const float* __restrict__ Wc, const float* __restrict__ Q,
             const float* __restrict__ K,
             u16* __restrict__ Wqb, u16* __restrict__ Wkvb,
             u16* __restrict__ Web, u16* __restrict__ Wcb,
             u16* __restrict__ Qb, u16* __restrict__ Kb)
{
    int i = blockIdx.x * 256 + threadIdx.x;      // vec8 id, total 1277952
    const float* s; u16* d; int o;
    if (i < 32768)        { s = Wq; d = Wqb;            o = i; }
    else if (i < 65536)   { s = Wk; d = Wkvb;           o = i - 32768; }
    else if (i < 98304)   { s = Wv; d = Wkvb + 262144;  o = i - 65536; }
    else if (i < 163840)  { s = We; d = Web;            o = i - 98304; }
    else if (i < 229376)  { s = Wc; d = Wcb;            o = i - 163840; }
    else if (i < 753664)  { s = Q;  d = Qb;             o = i - 229376; }
    else                  { s = K;  d = Kb;             o = i - 753664; }
    cvt8(s, d, (size_t)o);
}

// ---------------------------------------------------------------------------
// bf16 MFMA GEMM, 128x128, BK=64, counted-vmcnt dual-barrier 2-phase dbuf,
// pure global_load_lds staging w/ XOR swizzle. blockIdx.x = M-tile (fast).
// MODE 0: f32 out + bias + BN partials   MODE 1: bf16 out + bias + relu
// MODE 2: Q-proj -> A (sin/cos, log2e)   MODE 3: KV-proj -> B / Vt
// ---------------------------------------------------------------------------
template<int MODE>
__global__ __launch_bounds__(256)
void gemm_k(const u16* __restrict__ Xb, const u16* __restrict__ W,
            const float* __restrict__ bias, const float* __restrict__ bias2,
            void* __restrict__ out, u16* __restrict__ out2,
            const float* __restrict__ Pph, const float* __restrict__ Wp,
            const float* __restrict__ bp, int Kd, int Nn,
            float* __restrict__ bnp)
{
    const int m0 = blockIdx.x * 128, n0 = blockIdx.y * 128;
    const int tid = threadIdx.x;
    const int w = tid >> 6, lane = tid & 63;
    const int lr = lane & 15, lg = lane >> 4;
    const int wm = w >> 1, wn = w & 1;

    __shared__ __align__(16) u16 AsL[2][128 * 64];
    __shared__ __align__(16) u16 BsL[2][128 * 64];
    __shared__ float BnL[2][2][4][16][2];

    floatx4 acc[4][4] = {};
    const int xorp = (lr & 7) << 4;
    const int colb = lg << 4;

    auto stage = [&](int t, int b) {
        const size_t ko = (size_t)t * 64;
        #pragma unroll
        for (int r = 0; r < 4; ++r) {
            const int cid = r * 256 + tid;
            const int row = cid >> 3, c16 = cid & 7;
            const int kc = ((c16 ^ (row & 7)) << 3);
            gload16(&Xb[(size_t)(m0 + row) * Kd + ko + kc], &AsL[b][cid * 8]);
        }
        #pragma unroll
        for (int r = 0; r < 4; ++r) {
            const int cid = r * 256 + tid;
            const int row = cid >> 3, c16 = cid & 7;
            const int kc = ((c16 ^ (row & 7)) << 3);
            gload16(&W[(size_t)(n0 + row) * Kd + ko + kc], &BsL[b][cid * 8]);
        }
    };

    const int nt = Kd >> 6;
    stage(0, 0);
    int c = 0;
    for (int t = 0; t < nt; ++t) {
        if (t + 1 < nt) {
            stage(t + 1, c ^ 1);                       // 8 loads stay in flight
            asm volatile("s_waitcnt vmcnt(8)" ::: "memory");
        } else {
            asm volatile("s_waitcnt vmcnt(0)" ::: "memory");
        }
        __builtin_amdgcn_sched_barrier(0);
        __builtin_amdgcn_s_barrier();                  // buf c staged for all waves

        const char* la = (const char*)AsL[c];
        const char* lb = (const char*)BsL[c];
        __builtin_amdgcn_s_setprio(1);
        #pragma unroll
        for (int ks = 0; ks < 2; ++ks) {
            const int cb = (ks * 64 + colb) ^ xorp;
            bf16x8 a[4], b[4];
            #pragma unroll
            for (int i = 0; i < 4; ++i)
                a[i] = *(const bf16x8*)(la + (((wm * 64 + i * 16 + lr) << 7) + cb));
            #pragma unroll
            for (int j = 0; j < 4; ++j)
                b[j] = *(const bf16x8*)(lb + (((wn * 64 + j * 16 + lr) << 7) + cb));
            #pragma unroll
            for (int i = 0; i < 4; ++i)
                #pragma unroll
                for (int j = 0; j < 4; ++j)
                    acc[i][j] = __builtin_amdgcn_mfma_f32_16x16x32_bf16(a[i], b[j], acc[i][j], 0, 0, 0);
        }
        __builtin_amdgcn_s_setprio(0);
        __builtin_amdgcn_s_barrier();                  // all waves done reading buf c
        __builtin_amdgcn_sched_barrier(0);
        c ^= 1;
    }

    if (MODE <= 1) {
        float bs[4], bs2[4];
        #pragma unroll
        for (int j = 0; j < 4; ++j) { bs[j] = 0.f; bs2[j] = 0.f; }
        #pragma unroll
        for (int j = 0; j < 4; ++j) {
            const int col = n0 + wn * 64 + j * 16 + lr;
            const float bi = bias[col];
            #pragma unroll
            for (int i = 0; i < 4; ++i)
                #pragma unroll
                for (int rr = 0; rr < 4; ++rr) {
                    const int row = m0 + wm * 64 + i * 16 + lg * 4 + rr;
                    float v = acc[i][j][rr] + bi;
                    if (MODE == 1) {
                        v = fmaxf(v, 0.f);
                        ((u16*)out)[(size_t)row * Nn + col] = f2bf(v);
                    } else {
                        ((float*)out)[(size_t)row * Nn + col] = v;
                        bs[j] += v; bs2[j] += v * v;
                    }
                }
        }
        if (MODE == 0) {    // BN partial over this m-tile's 128 rows
            #pragma unroll
            for (int j = 0; j < 4; ++j) {
                float s = bs[j], s2 = bs2[j];
                s  += __shfl_xor(s, 16);  s  += __shfl_xor(s, 32);
                s2 += __shfl_xor(s2, 16); s2 += __shfl_xor(s2, 32);
                if (lg == 0) { BnL[wm][wn][j][lr][0] = s; BnL[wm][wn][j][lr][1] = s2; }
            }
            __syncthreads();
            if (tid < 128) {
                const int wn2 = tid >> 6, j2 = (tid >> 4) & 3, lr2 = tid & 15;
                const float s  = BnL[0][wn2][j2][lr2][0] + BnL[1][wn2][j2][lr2][0];
                const float s2 = BnL[0][wn2][j2][lr2][1] + BnL[1][wn2][j2][lr2][1];
                const int col = n0 + tid;
                bnp[(size_t)blockIdx.x * 512 + col]         = s;
                bnp[32768 + (size_t)blockIdx.x * 512 + col] = s2;
            }
        }
    } else if (MODE == 2) {
        u16* A = (u16*)out;
        #pragma unroll
        for (int j = 0; j < 4; ++j) {
            const int col = n0 + wn * 64 + j * 16 + lr;
            const float w0 = Wp[col * 3], w1 = Wp[col * 3 + 1], w2 = Wp[col * 3 + 2];
            const float bpd = bp[col], bi = bias[col];
            const int hh = col >> 6, dh = col & 63;
            #pragma unroll
            for (int i = 0; i < 4; ++i)
                #pragma unroll
                for (int rr = 0; rr < 4; ++rr) {
                    const int row = m0 + wm * 64 + i * 16 + lg * 4 + rr;
                    const int ns = row >> 10, l = row & 1023;
                    const float p = Pph[row * 3] * w0 + Pph[row * 3 + 1] * w1
                                  + Pph[row * 3 + 2] * w2 + bpd;
                    float sn, cs;
                    __sincosf(p, &sn, &cs);
                    const float v = acc[i][j][rr] + bi;
                    const size_t e = (((size_t)(ns * HN + hh)) * LQ + l) * DE + dh;
                    A[e]      = f2bf(v * sn * LOG2E);
                    A[e + 64] = f2bf(-v * cs * LOG2E);
                }
        }
    } else {   // MODE 3
        if (n0 < 512) {     // K half -> B with phases
            u16* B = (u16*)out;
            #pragma unroll
            for (int j = 0; j < 4; ++j) {
                const int col = n0 + wn * 64 + j * 16 + lr;
                const float w0 = Wp[col * 3], w1 = Wp[col * 3 + 1], w2 = Wp[col * 3 + 2];
                const float bi = bias[col];
                const int hh = col >> 6, dh = col & 63;
                #pragma unroll
                for (int i = 0; i < 4; ++i)
                    #pragma unroll
                    for (int rr = 0; rr < 4; ++rr) {
                        const int row = m0 + wm * 64 + i * 16 + lg * 4 + rr;
                        const int ns = row >> 10, l = row & 1023;
                        const float p = Pph[row * 3] * w0 + Pph[row * 3 + 1] * w1
                                      + Pph[row * 3 + 2] * w2;      // pk - b
                        float sn, cs;
                        __sincosf(p, &sn, &cs);
                        const float v = acc[i][j][rr] + bi;
                        const size_t e = (((size_t)(ns * HN + hh)) * LQ + l) * DE + dh;
                        B[e]      = f2bf(v * cs);
                        B[e + 64] = f2bf(v * sn);
                    }
            }
        } else {            // V half -> Vt (per-head transposed)
            #pragma unroll
            for (int j = 0; j < 4; ++j) {
                const int col = n0 + wn * 64 + j * 16 + lr;
                const int c2 = col - 512;
                const float bi = bias2[c2];
                const int hh = c2 >> 6, dh = c2 & 63;
                #pragma unroll
                for (int i = 0; i < 4; ++i)
                    #pragma unroll
                    for (int rr = 0; rr < 4; ++rr) {
                        const int row = m0 + wm * 64 + i * 16 + lg * 4 + rr;
                        const int ns = row >> 10, l = row & 1023;
                        const float v = acc[i][j][rr] + bi;
                        out2[((size_t)((ns * HN + hh) * DHD + dh)) * LQ + l] = f2bf(v);
                    }
            }
        }
    }
}

// ---------------------------------------------------------------------------
// Flash attention: 512-thr blocks (8 waves), QBLK=256, KVBLK=64.
// Each wave owns 32 q-rows as TWO 16-q groups -> every kfrag/vfrag LDS read
// feeds 2 MFMA (halves LDS read traffic per q). 256 blocks = 1/CU, no
// inter-block LDS contention. No-max softmax; counted-vmcnt dual-barrier.
// ---------------------------------------------------------------------------
__global__ __launch_bounds__(512, 2)
void attn_mfma(const u16* __restrict__ Ag, const u16* __restrict__ Bg,
               const u16* __restrict__ Vtg, u16* __restrict__ Tbf)
{
    int bid = blockIdx.x;
    bid = (bid & 7) * 32 + (bid >> 3);    // XCD swizzle (256 % 8 == 0): 8 heads/XCD
    const int head = bid >> 2;            // 0..63
    const int row0 = (bid & 3) * 256;
    const int ns = head >> 3, h = head & 7;
    const int tid = threadIdx.x, w = tid >> 6, lane = tid & 63;
    const int lr = lane & 15, lg = lane >> 4;

    __shared__ __align__(16) u16 BsL[2][64 * 128];   // 32 KB
    __shared__ __align__(16) u16 VtL[2][64 * 64];    // 16 KB
    __shared__ __align__(16) u16 Ps[8][32][72];      // 36 KB

    // Q fragments -> registers: group A rows w*32+lr, group B rows w*32+16+lr
    bf16x8 qfA[4], qfB[4];
    {
        const size_t rb = ((size_t)head * LQ + row0 + w * 32 + lr) * DE;
        #pragma unroll
        for (int ks = 0; ks < 4; ++ks) {
            qfA[ks] = *(const bf16x8*)&Ag[rb + ks * 32 + lg * 8];
            qfB[ks] = *(const bf16x8*)&Ag[rb + 16 * DE + ks * 32 + lg * 8];
        }
    }

    auto stageBV = [&](int kt, int b) {
        #pragma unroll
        for (int r = 0; r < 2; ++r) {                 // B tile 16 KB
            const int cid = r * 512 + tid;
            const int row = cid >> 4, c16 = cid & 15;
            const int kc = ((c16 ^ (row & 7)) << 3);
            gload16(&Bg[((size_t)head * LQ + kt * 64 + row) * DE + kc], &BsL[b][cid * 8]);
        }
        {                                             // Vt tile 8 KB
            const int row = tid >> 3, c16 = tid & 7;
            const int kc = ((c16 ^ (row & 7)) << 3);
            gload16(&Vtg[((size_t)head * DHD + row) * LQ + kt * 64 + kc], &VtL[b][tid * 8]);
        }
    };
    stageBV(0, 0);

    floatx4 oA[4] = {}, oB[4] = {};
    float lsA = 0.f, lsB = 0.f;
    const int xorp = (lr & 7) << 4;
    const int colb = lg << 4;
    int c = 0;

    for (int kt = 0; kt < 16; ++kt) {
        if (kt < 15) {
            stageBV(kt + 1, c ^ 1);                   // 3 loads stay in flight
            asm volatile("s_waitcnt vmcnt(3)" ::: "memory");
        } else {
            asm volatile("s_waitcnt vmcnt(0)" ::: "memory");
        }
        __builtin_amdgcn_sched_barrier(0);
        __builtin_amdgcn_s_barrier();                 // tile kt staged for all waves

        const char* lb = (const char*)BsL[c];
        const char* lv = (const char*)VtL[c];

        // ---- S^T strips, kfrag shared across both q-groups ----
        floatx4 sA[4] = {}, sB[4] = {};
        __builtin_amdgcn_s_setprio(1);
        #pragma unroll
        for (int ks = 0; ks < 4; ++ks) {
            const int cb = (ks * 64 + colb) ^ xorp;
            bf16x8 kf[4];
            #pragma unroll
            for (int j = 0; j < 4; ++j)
                kf[j] = *(const bf16x8*)(lb + (((j * 16 + lr) << 8) + cb));
            #pragma unroll
            for (int j = 0; j < 4; ++j) {
                sA[j] = __builtin_amdgcn_mfma_f32_16x16x32_bf16(kf[j], qfA[ks], sA[j], 0, 0, 0);
                sB[j] = __builtin_amdgcn_mfma_f32_16x16x32_bf16(kf[j], qfB[ks], sB[j], 0, 0, 0);
            }
        }
        __builtin_amdgcn_s_setprio(0);

        // ---- no-max softmax ----
        float tsa = 0.f, tsb = 0.f;
        #pragma unroll
        for (int j = 0; j < 4; ++j)
            #pragma unroll
            for (int r = 0; r < 4; ++r) {
                float ea = exp2f(sA[j][r]); sA[j][r] = ea; tsa += ea;
                float eb = exp2f(sB[j][r]); sB[j][r] = eb; tsb += eb;
            }
        lsA += tsa; lsB += tsb;

        // ---- P -> per-wave LDS (cvt_pk), rows 0-15 = A, 16-31 = B ----
        #pragma unroll
        for (int j = 0; j < 4; ++j) {
            unsigned plo, phi;
            asm("v_cvt_pk_bf16_f32 %0, %1, %2" : "=v"(plo) : "v"(sA[j][0]), "v"(sA[j][1]));
            asm("v_cvt_pk_bf16_f32 %0, %1, %2" : "=v"(phi) : "v"(sA[j][2]), "v"(sA[j][3]));
            uint2 pv; pv.x = plo; pv.y = phi;
            *(uint2*)&Ps[w][lr][j * 16 + lg * 4] = pv;
            asm("v_cvt_pk_bf16_f32 %0, %1, %2" : "=v"(plo) : "v"(sB[j][0]), "v"(sB[j][1]));
            asm("v_cvt_pk_bf16_f32 %0, %1, %2" : "=v"(phi) : "v"(sB[j][2]), "v"(sB[j][3]));
            pv.x = plo; pv.y = phi;
            *(uint2*)&Ps[w][16 + lr][j * 16 + lg * 4] = pv;
        }

        // ---- PV: vfrag shared across both q-groups ----
        __builtin_amdgcn_s_setprio(1);
        #pragma unroll
        for (int ks2 = 0; ks2 < 2; ++ks2) {
            const int cb = (ks2 * 64 + colb) ^ xorp;
            bf16x8 pfA = *(const bf16x8*)&Ps[w][lr][ks2 * 32 + lg * 8];
            bf16x8 pfB = *(const bf16x8*)&Ps[w][16 + lr][ks2 * 32 + lg * 8];
            #pragma unroll
            for (int m = 0; m < 4; ++m) {
                bf16x8 vf = *(const bf16x8*)(lv + (((m * 16 + lr) << 7) + cb));
                oA[m] = __builtin_amdgcn_mfma_f32_16x16x32_bf16(vf, pfA, oA[m], 0, 0, 0);
                oB[m] = __builtin_amdgcn_mfma_f32_16x16x32_bf16(vf, pfB, oB[m], 0, 0, 0);
            }
        }
        __builtin_amdgcn_s_setprio(0);
        __builtin_amdgcn_s_barrier();                 // all waves done with buf c
        __builtin_amdgcn_sched_barrier(0);
        c ^= 1;
    }

    // denominators (once), normalize, write merged-head T (bf16)
    lsA += __shfl_xor(lsA, 16); lsA += __shfl_xor(lsA, 32);
    lsB += __shfl_xor(lsB, 16); lsB += __shfl_xor(lsB, 32);
    const float invA = 1.f / lsA, invB = 1.f / lsB;
    const size_t trA = ((size_t)ns * LQ + row0 + w * 32 + lr) * DM + h * DHD;
    const size_t trB = trA + (size_t)16 * DM;
    #pragma unroll
    for (int m = 0; m < 4; ++m) {
        union { u16 u[4]; uint2 v; } pk;
        pk.u[0] = f2bf(oA[m][0] * invA); pk.u[1] = f2bf(oA[m][1] * invA);
        pk.u[2] = f2bf(oA[m][2] * invA); pk.u[3] = f2bf(oA[m][3] * invA);
        *(uint2*)&Tbf[trA + m * 16 + lg * 4] = pk.v;
        pk.u[0] = f2bf(oB[m][0] * invB); pk.u[1] = f2bf(oB[m][1] * invB);
        pk.u[2] = f2bf(oB[m][2] * invB); pk.u[3] = f2bf(oB[m][3] * invB);
        *(uint2*)&Tbf[trB + m * 16 + lg * 4] = pk.v;
    }
}

// ---------------------------------------------------------------------------
// BN: reduce per-block partials (64 m-blocks) -> stats; then final (float4)
// ---------------------------------------------------------------------------
__global__ __launch_bounds__(256)
void bn_reduce(const float* __restrict__ part, float* __restrict__ stats)
{
    const int cx = blockIdx.x * 256 + threadIdx.x;   // 0..511
    float s = 0.f, s2 = 0.f;
    for (int b = 0; b < 64; ++b) {
        s  += part[(size_t)b * 512 + cx];
        s2 += part[32768 + (size_t)b * 512 + cx];
    }
    stats[cx] = s;
    stats[512 + cx] = s2;
}

__global__ __launch_bounds__(256)
void bn_final(const float* __restrict__ Y, const float* __restrict__ Qin,
              const float* __restrict__ stats,
              const float* __restrict__ gamma, const float* __restrict__ beta,
              float* __restrict__ out)
{
    const int i4 = blockIdx.x * 256 + threadIdx.x;   // 0..ROWS*DM/4-1
    const int c4 = (i4 & 127) * 4;                   // channel base
    const float4 sm  = *(const float4*)&stats[c4];
    const float4 sq  = *(const float4*)&stats[512 + c4];
    const float4 gm  = *(const float4*)&gamma[c4];
    const float4 bt  = *(const float4*)&beta[c4];
    const float4 y   = *(const float4*)&Y[(size_t)i4 * 4];
    const float4 q   = *(const float4*)&Qin[(size_t)i4 * 4];
    float4 o;
    {
        const float mu = sm.x * (1.f / ROWS);
        const float rs = rsqrtf(sq.x * (1.f / ROWS) - mu * mu + 1e-5f);
        o.x = q.x + (y.x - mu) * rs * gm.x + bt.x;
    }
    {
        const float mu = sm.y * (1.f / ROWS);
        const float rs = rsqrtf(sq.y * (1.f / ROWS) - mu * mu + 1e-5f);
        o.y = q.y + (y.y - mu) * rs * gm.y + bt.y;
    }
    {
        const float mu = sm.z * (1.f / ROWS);
        const float rs = rsqrtf(sq.z * (1.f / ROWS) - mu * mu + 1e-5f);
        o.z = q.z + (y.z - mu) * rs * gm.z + bt.z;
    }
    {
        const float mu = sm.w * (1.f / ROWS);
        const float rs = rsqrtf(sq.w * (1.f / ROWS) - mu * mu + 1e-5f);
        o.w = q.w + (y.w - mu) * rs * gm.w + bt.w;
    }
    *(float4*)&out[(size_t)i4 * 4] = o;
}

// ---------------------------------------------------------------------------
extern "C" void kernel_launch(void* const* d_in, const int* in_sizes, int n_in,
                              void* d_out, int out_size, void* d_ws, size_t ws_size,
                              hipStream_t stream)
{
    (void)in_sizes; (void)n_in; (void)out_size; (void)ws_size;

    const float* Q    = (const float*)d_in[0];
    const float* K    = (const float*)d_in[1];
    const float* Pq   = (const float*)d_in[2];
    const float* Pk   = (const float*)d_in[3];
    const float* Wq   = (const float*)d_in[4];
    const float* bq   = (const float*)d_in[5];
    const float* Wk   = (const float*)d_in[6];
    const float* bk   = (const float*)d_in[7];
    const float* Wv   = (const float*)d_in[8];
    const float* bv   = (const float*)d_in[9];
    const float* Wp   = (const float*)d_in[10];
    const float* bp   = (const float*)d_in[11];
    const float* We   = (const float*)d_in[12];
    const float* be   = (const float*)d_in[13];
    const float* Wc   = (const float*)d_in[14];
    const float* bc   = (const float*)d_in[15];
    const float* gamma= (const float*)d_in[16];
    const float* beta = (const float*)d_in[17];

    const size_t MB = 1u << 20;
    char* w8 = (char*)d_ws;
    u16*  Abf  = (u16*)(w8);                  // 16 MB (A operands)
    u16*  Bbf  = (u16*)(w8 + 16 * MB);        // 16 MB
    u16*  Vtb  = (u16*)(w8 + 32 * MB);        //  8 MB
    u16*  Tbf  = (u16*)(w8 + 40 * MB);        //  8 MB
    u16*  H1b  = (u16*)(w8 + 48 * MB);        // 16 MB
    u16*  Qbf  = (u16*)(w8 + 64 * MB);        //  8 MB
    u16*  Kbf  = (u16*)(w8 + 72 * MB);        //  8 MB
    float* Y   = (float*)(w8);                // 16 MB (reuses Abf after attn)
    float* part  = (float*)(w8 + 16 * MB);    // 256 KB (reuses Bbf after attn)
    float* stats = (float*)(w8 + 17 * MB);    //  4 KB
    u16*  Wqb  = (u16*)(w8 + 80 * MB);                    // 0.5 MB
    u16*  Wkvb = (u16*)(w8 + 80 * MB + 512 * 1024);       // 1 MB
    u16*  Web  = (u16*)(w8 + 80 * MB + 1536 * 1024);      // 1 MB
    u16*  Wcb  = (u16*)(w8 + 80 * MB + 2560 * 1024);      // 1 MB

    dim3 blk256(256);

    // one fused cast: weights + Q + K
    castall<<<4992, blk256, 0, stream>>>(Wq, Wk, Wv, We, Wc, Q, K,
                                         Wqb, Wkvb, Web, Wcb, Qbf, Kbf);

    // Q-proj + phase epilogue -> A   (pure gload_lds path)
    gemm_k<2><<<dim3(64, 4), blk256, 0, stream>>>(Qbf, Wqb, bq, nullptr,
        Abf, nullptr, Pq, Wp, bp, DM, DM, nullptr);
    // KV-proj + epilogue -> B, Vt
    gemm_k<3><<<dim3(64, 8), blk256, 0, stream>>>(Kbf, Wkvb, bk, bv,
        Bbf, Vtb, Pk, Wp, bp, DM, 2 * DM, nullptr);

    // flash attention (256 blocks x 8 waves, dual-group, 1 block/CU)
    attn_mfma<<<256, dim3(512), 0, stream>>>(Abf, Bbf, Vtb, Tbf);

    // FFN
    gemm_k<1><<<dim3(64, 8), blk256, 0, stream>>>(Tbf, Web, be, nullptr,
        H1b, nullptr, nullptr, nullptr, nullptr, DM, 2 * DM, nullptr);
    gemm_k<0><<<dim3(64, 4), blk256, 0, stream>>>(H1b, Wcb, bc, nullptr,
        Y, nullptr, nullptr, nullptr, nullptr, 2 * DM, DM, part);

    // BN stats + final
    bn_reduce<<<2, blk256, 0, stream>>>(part, stats);
    bn_final<<<ROWS * DM / 1024, blk256, 0, stream>>>(Y, Q, stats, gamma, beta,
                                                      (float*)d_out);
}

// Round 11
// 143.367 us; speedup vs baseline: 9.7908x; 1.0341x over previous
//
#include <hip/hip_runtime.h>
#include <math.h>

#define LQ 1024      // sequence length L
#define DM 512       // model dim D
#define HN 8         // heads
#define DHD 64       // head dim
#define ROWS 8192    // N*S*L
#define DE 128       // effective attention dim (2*DHD)
#define LOG2E 1.44269504088896f

typedef __attribute__((ext_vector_type(8))) short bf16x8;
typedef __attribute__((ext_vector_type(4))) float floatx4;
typedef unsigned short u16;

static __device__ __forceinline__ u16 f2bf(float x) {
    unsigned int u = __float_as_uint(x);
    u = (u + 0x7fffu + ((u >> 16) & 1u)) >> 16;   // round-nearest-even
    return (u16)u;
}

static __device__ __forceinline__ void gload16(const void* g, void* l) {
    __builtin_amdgcn_global_load_lds((const __attribute__((address_space(1))) void*)g,
                                     (__attribute__((address_space(3))) void*)l,
                                     16, 0, 0);
}

static __device__ __forceinline__ void cvt8(const float* s, u16* d, size_t o) {
    const float4* sp = (const float4*)s + 2 * o;
    float4 a = sp[0], b = sp[1];
    union { u16 u[8]; uint4 v; } ov;
    ov.u[0]=f2bf(a.x); ov.u[1]=f2bf(a.y); ov.u[2]=f2bf(a.z); ov.u[3]=f2bf(a.w);
    ov.u[4]=f2bf(b.x); ov.u[5]=f2bf(b.y); ov.u[6]=f2bf(b.z); ov.u[7]=f2bf(b.w);
    ((uint4*)d)[o] = ov.v;
}

// ---------------------------------------------------------------------------
// one fused cast dispatch: all weights + Q + K  (memory-bound)
// ---------------------------------------------------------------------------
__global__ __launch_bounds__(256)
void castall(const float* __restrict__ Wq, const float* __restrict__ Wk,
             const float* __restrict__ Wv, const float* __restrict__ We,
             const float* __restrict__ Wc, const float* __restrict__ Q,
             const float* __restrict__ K,
             u16* __restrict__ Wqb, u16* __restrict__ Wkvb,
             u16* __restrict__ Web, u16* __restrict__ Wcb,
             u16* __restrict__ Qb, u16* __restrict__ Kb)
{
    int i = blockIdx.x * 256 + threadIdx.x;      // vec8 id, total 1277952
    const float* s; u16* d; int o;
    if (i < 32768)        { s = Wq; d = Wqb;            o = i; }
    else if (i < 65536)   { s = Wk; d = Wkvb;           o = i - 32768; }
    else if (i < 98304)   { s = Wv; d = Wkvb + 262144;  o = i - 65536; }
    else if (i < 163840)  { s = We; d = Web;            o = i - 98304; }
    else if (i < 229376)  { s = Wc; d = Wcb;            o = i - 163840; }
    else if (i < 753664)  { s = Q;  d = Qb;             o = i - 229376; }
    else                  { s = K;  d = Kb;             o = i - 753664; }
    cvt8(s, d, (size_t)o);
}

// ---------------------------------------------------------------------------
// Fused projection GEMM: one dispatch, grid (64, 12).
// blockIdx.y < 4 : Q-proj -> A (sin/cos, log2e folded)
// blockIdx.y >= 4: KV-proj -> B (n0<512) / Vt (n0>=512, per-head transposed)
// 128x128 tile, BK=64, counted-vmcnt dual-barrier 2-phase dbuf,
// pure global_load_lds staging w/ XOR swizzle. Kd = 512 for both paths.
// ---------------------------------------------------------------------------
__global__ __launch_bounds__(256)
void proj_qkv(const u16* __restrict__ Qb, const u16* __restrict__ Kb,
              const u16* __restrict__ Wqb, const u16* __restrict__ Wkvb,
              const float* __restrict__ bq, const float* __restrict__ bk,
              const float* __restrict__ bv,
              u16* __restrict__ Abf, u16* __restrict__ Bbf, u16* __restrict__ Vtb,
              const float* __restrict__ Pq, const float* __restrict__ Pk,
              const float* __restrict__ Wp, const float* __restrict__ bp)
{
    const bool isQ = blockIdx.y < 4;
    const int m0 = blockIdx.x * 128;
    const int n0 = (isQ ? blockIdx.y : blockIdx.y - 4) * 128;
    const u16* Xb = isQ ? Qb : Kb;
    const u16* W  = isQ ? Wqb : Wkvb;
    const float* Pph = isQ ? Pq : Pk;
    const int Kd = DM;

    const int tid = threadIdx.x;
    const int w = tid >> 6, lane = tid & 63;
    const int lr = lane & 15, lg = lane >> 4;
    const int wm = w >> 1, wn = w & 1;

    __shared__ __align__(16) u16 AsL[2][128 * 64];
    __shared__ __align__(16) u16 BsL[2][128 * 64];

    floatx4 acc[4][4] = {};
    const int xorp = (lr & 7) << 4;
    const int colb = lg << 4;

    auto stage = [&](int t, int b) {
        const size_t ko = (size_t)t * 64;
        #pragma unroll
        for (int r = 0; r < 4; ++r) {
            const int cid = r * 256 + tid;
            const int row = cid >> 3, c16 = cid & 7;
            const int kc = ((c16 ^ (row & 7)) << 3);
            gload16(&Xb[(size_t)(m0 + row) * Kd + ko + kc], &AsL[b][cid * 8]);
        }
        #pragma unroll
        for (int r = 0; r < 4; ++r) {
            const int cid = r * 256 + tid;
            const int row = cid >> 3, c16 = cid & 7;
            const int kc = ((c16 ^ (row & 7)) << 3);
            gload16(&W[(size_t)(n0 + row) * Kd + ko + kc], &BsL[b][cid * 8]);
        }
    };

    const int nt = Kd >> 6;
    stage(0, 0);
    int c = 0;
    for (int t = 0; t < nt; ++t) {
        if (t + 1 < nt) {
            stage(t + 1, c ^ 1);                       // 8 loads stay in flight
            asm volatile("s_waitcnt vmcnt(8)" ::: "memory");
        } else {
            asm volatile("s_waitcnt vmcnt(0)" ::: "memory");
        }
        __builtin_amdgcn_sched_barrier(0);
        __builtin_amdgcn_s_barrier();                  // buf c staged for all waves

        const char* la = (const char*)AsL[c];
        const char* lb = (const char*)BsL[c];
        __builtin_amdgcn_s_setprio(1);
        #pragma unroll
        for (int ks = 0; ks < 2; ++ks) {
            const int cb = (ks * 64 + colb) ^ xorp;
            bf16x8 a[4], b[4];
            #pragma unroll
            for (int i = 0; i < 4; ++i)
                a[i] = *(const bf16x8*)(la + (((wm * 64 + i * 16 + lr) << 7) + cb));
            #pragma unroll
            for (int j = 0; j < 4; ++j)
                b[j] = *(const bf16x8*)(lb + (((wn * 64 + j * 16 + lr) << 7) + cb));
            #pragma unroll
            for (int i = 0; i < 4; ++i)
                #pragma unroll
                for (int j = 0; j < 4; ++j)
                    acc[i][j] = __builtin_amdgcn_mfma_f32_16x16x32_bf16(a[i], b[j], acc[i][j], 0, 0, 0);
        }
        __builtin_amdgcn_s_setprio(0);
        __builtin_amdgcn_s_barrier();                  // all waves done reading buf c
        __builtin_amdgcn_sched_barrier(0);
        c ^= 1;
    }

    if (isQ) {          // -> A with phases (log2e folded)
        #pragma unroll
        for (int j = 0; j < 4; ++j) {
            const int col = n0 + wn * 64 + j * 16 + lr;
            const float w0 = Wp[col * 3], w1 = Wp[col * 3 + 1], w2 = Wp[col * 3 + 2];
            const float bpd = bp[col], bi = bq[col];
            const int hh = col >> 6, dh = col & 63;
            #pragma unroll
            for (int i = 0; i < 4; ++i)
                #pragma unroll
                for (int rr = 0; rr < 4; ++rr) {
                    const int row = m0 + wm * 64 + i * 16 + lg * 4 + rr;
                    const int ns = row >> 10, l = row & 1023;
                    const float p = Pph[row * 3] * w0 + Pph[row * 3 + 1] * w1
                                  + Pph[row * 3 + 2] * w2 + bpd;
                    float sn, cs;
                    __sincosf(p, &sn, &cs);
                    const float v = acc[i][j][rr] + bi;
                    const size_t e = (((size_t)(ns * HN + hh)) * LQ + l) * DE + dh;
                    Abf[e]      = f2bf(v * sn * LOG2E);
                    Abf[e + 64] = f2bf(-v * cs * LOG2E);
                }
        }
    } else if (n0 < 512) {    // K half -> B with phases
        #pragma unroll
        for (int j = 0; j < 4; ++j) {
            const int col = n0 + wn * 64 + j * 16 + lr;
            const float w0 = Wp[col * 3], w1 = Wp[col * 3 + 1], w2 = Wp[col * 3 + 2];
            const float bi = bk[col];
            const int hh = col >> 6, dh = col & 63;
            #pragma unroll
            for (int i = 0; i < 4; ++i)
                #pragma unroll
                for (int rr = 0; rr < 4; ++rr) {
                    const int row = m0 + wm * 64 + i * 16 + lg * 4 + rr;
                    const int ns = row >> 10, l = row & 1023;
                    const float p = Pph[row * 3] * w0 + Pph[row * 3 + 1] * w1
                                  + Pph[row * 3 + 2] * w2;      // pk - b
                    float sn, cs;
                    __sincosf(p, &sn, &cs);
                    const float v = acc[i][j][rr] + bi;
                    const size_t e = (((size_t)(ns * HN + hh)) * LQ + l) * DE + dh;
                    Bbf[e]      = f2bf(v * cs);
                    Bbf[e + 64] = f2bf(v * sn);
                }
        }
    } else {                  // V half -> Vt (per-head transposed)
        #pragma unroll
        for (int j = 0; j < 4; ++j) {
            const int col = n0 + wn * 64 + j * 16 + lr;
            const int c2 = col - 512;
            const float bi = bv[c2];
            const int hh = c2 >> 6, dh = c2 & 63;
            #pragma unroll
            for (int i = 0; i < 4; ++i)
                #pragma unroll
                for (int rr = 0; rr < 4; ++rr) {
                    const int row = m0 + wm * 64 + i * 16 + lg * 4 + rr;
                    const int ns = row >> 10, l = row & 1023;
                    const float v = acc[i][j][rr] + bi;
                    Vtb[((size_t)((ns * HN + hh) * DHD + dh)) * LQ + l] = f2bf(v);
                }
        }
    }
}

// ---------------------------------------------------------------------------
// FFN GEMM: 128x128, BK=64, counted-vmcnt dual-barrier 2-phase dbuf.
// MODE 0: f32 out + bias + BN partials   MODE 1: bf16 out + bias + relu
// ---------------------------------------------------------------------------
template<int MODE>
__global__ __launch_bounds__(256)
void gemm_k(const u16* __restrict__ Xb, const u16* __restrict__ W,
            const float* __restrict__ bias, void* __restrict__ out,
            int Kd, int Nn, float* __restrict__ bnp)
{
    const int m0 = blockIdx.x * 128, n0 = blockIdx.y * 128;
    const int tid = threadIdx.x;
    const int w = tid >> 6, lane = tid & 63;
    const int lr = lane & 15, lg = lane >> 4;
    const int wm = w >> 1, wn = w & 1;

    __shared__ __align__(16) u16 AsL[2][128 * 64];
    __shared__ __align__(16) u16 BsL[2][128 * 64];
    __shared__ float BnL[2][2][4][16][2];

    floatx4 acc[4][4] = {};
    const int xorp = (lr & 7) << 4;
    const int colb = lg << 4;

    auto stage = [&](int t, int b) {
        const size_t ko = (size_t)t * 64;
        #pragma unroll
        for (int r = 0; r < 4; ++r) {
            const int cid = r * 256 + tid;
            const int row = cid >> 3, c16 = cid & 7;
            const int kc = ((c16 ^ (row & 7)) << 3);
            gload16(&Xb[(size_t)(m0 + row) * Kd + ko + kc], &AsL[b][cid * 8]);
        }
        #pragma unroll
        for (int r = 0; r < 4; ++r) {
            const int cid = r * 256 + tid;
            const int row = cid >> 3, c16 = cid & 7;
            const int kc = ((c16 ^ (row & 7)) << 3);
            gload16(&W[(size_t)(n0 + row) * Kd + ko + kc], &BsL[b][cid * 8]);
        }
    };

    const int nt = Kd >> 6;
    stage(0, 0);
    int c = 0;
    for (int t = 0; t < nt; ++t) {
        if (t + 1 < nt) {
            stage(t + 1, c ^ 1);                       // 8 loads stay in flight
            asm volatile("s_waitcnt vmcnt(8)" ::: "memory");
        } else {
            asm volatile("s_waitcnt vmcnt(0)" ::: "memory");
        }
        __builtin_amdgcn_sched_barrier(0);
        __builtin_amdgcn_s_barrier();                  // buf c staged for all waves

        const char* la = (const char*)AsL[c];
        const char* lb = (const char*)BsL[c];
        __builtin_amdgcn_s_setprio(1);
        #pragma unroll
        for (int ks = 0; ks < 2; ++ks) {
            const int cb = (ks * 64 + colb) ^ xorp;
            bf16x8 a[4], b[4];
            #pragma unroll
            for (int i = 0; i < 4; ++i)
                a[i] = *(const bf16x8*)(la + (((wm * 64 + i * 16 + lr) << 7) + cb));
            #pragma unroll
            for (int j = 0; j < 4; ++j)
                b[j] = *(const bf16x8*)(lb + (((wn * 64 + j * 16 + lr) << 7) + cb));
            #pragma unroll
            for (int i = 0; i < 4; ++i)
                #pragma unroll
                for (int j = 0; j < 4; ++j)
                    acc[i][j] = __builtin_amdgcn_mfma_f32_16x16x32_bf16(a[i], b[j], acc[i][j], 0, 0, 0);
        }
        __builtin_amdgcn_s_setprio(0);
        __builtin_amdgcn_s_barrier();                  // all waves done reading buf c
        __builtin_amdgcn_sched_barrier(0);
        c ^= 1;
    }

    float bs[4], bs2[4];
    #pragma unroll
    for (int j = 0; j < 4; ++j) { bs[j] = 0.f; bs2[j] = 0.f; }
    #pragma unroll
    for (int j = 0; j < 4; ++j) {
        const int col = n0 + wn * 64 + j * 16 + lr;
        const float bi = bias[col];
        #pragma unroll
        for (int i = 0; i < 4; ++i)
            #pragma unroll
            for (int rr = 0; rr < 4; ++rr) {
                const int row = m0 + wm * 64 + i * 16 + lg * 4 + rr;
                float v = acc[i][j][rr] + bi;
                if (MODE == 1) {
                    v = fmaxf(v, 0.f);
                    ((u16*)out)[(size_t)row * Nn + col] = f2bf(v);
                } else {
                    ((float*)out)[(size_t)row * Nn + col] = v;
                    bs[j] += v; bs2[j] += v * v;
                }
            }
    }
    if (MODE == 0) {    // BN partial over this m-tile's 128 rows
        #pragma unroll
        for (int j = 0; j < 4; ++j) {
            float s = bs[j], s2 = bs2[j];
            s  += __shfl_xor(s, 16);  s  += __shfl_xor(s, 32);
            s2 += __shfl_xor(s2, 16); s2 += __shfl_xor(s2, 32);
            if (lg == 0) { BnL[wm][wn][j][lr][0] = s; BnL[wm][wn][j][lr][1] = s2; }
        }
        __syncthreads();
        if (tid < 128) {
            const int wn2 = tid >> 6, j2 = (tid >> 4) & 3, lr2 = tid & 15;
            const float s  = BnL[0][wn2][j2][lr2][0] + BnL[1][wn2][j2][lr2][0];
            const float s2 = BnL[0][wn2][j2][lr2][1] + BnL[1][wn2][j2][lr2][1];
            const int col = n0 + tid;
            bnp[(size_t)blockIdx.x * 512 + col]         = s;
            bnp[32768 + (size_t)blockIdx.x * 512 + col] = s2;
        }
    }
}

// ---------------------------------------------------------------------------
// Flash attention (R9-verified): 512-thr blocks (8 waves), QBLK=256, KVBLK=64.
// Each wave owns 32 q-rows as TWO 16-q groups -> every kfrag/vfrag LDS read
// feeds 2 MFMA. 256 blocks = 1/CU. No-max softmax; counted-vmcnt dual-barrier.
// ---------------------------------------------------------------------------
__global__ __launch_bounds__(512, 2)
void attn_mfma(const u16* __restrict__ Ag, const u16* __restrict__ Bg,
               const u16* __restrict__ Vtg, u16* __restrict__ Tbf)
{
    int bid = blockIdx.x;
    bid = (bid & 7) * 32 + (bid >> 3);    // XCD swizzle (256 % 8 == 0): 8 heads/XCD
    const int head = bid >> 2;            // 0..63
    const int row0 = (bid & 3) * 256;
    const int ns = head >> 3, h = head & 7;
    const int tid = threadIdx.x, w = tid >> 6, lane = tid & 63;
    const int lr = lane & 15, lg = lane >> 4;

    __shared__ __align__(16) u16 BsL[2][64 * 128];   // 32 KB
    __shared__ __align__(16) u16 VtL[2][64 * 64];    // 16 KB
    __shared__ __align__(16) u16 Ps[8][32][72];      // 36 KB

    // Q fragments -> registers: group A rows w*32+lr, group B rows w*32+16+lr
    bf16x8 qfA[4], qfB[4];
    {
        const size_t rb = ((size_t)head * LQ + row0 + w * 32 + lr) * DE;
        #pragma unroll
        for (int ks = 0; ks < 4; ++ks) {
            qfA[ks] = *(const bf16x8*)&Ag[rb + ks * 32 + lg * 8];
            qfB[ks] = *(const bf16x8*)&Ag[rb + 16 * DE + ks * 32 + lg * 8];
        }
    }

    auto stageBV = [&](int kt, int b) {
        #pragma unroll
        for (int r = 0; r < 2; ++r) {                 // B tile 16 KB
            const int cid = r * 512 + tid;
            const int row = cid >> 4, c16 = cid & 15;
            const int kc = ((c16 ^ (row & 7)) << 3);
            gload16(&Bg[((size_t)head * LQ + kt * 64 + row) * DE + kc], &BsL[b][cid * 8]);
        }
        {                                             // Vt tile 8 KB
            const int row = tid >> 3, c16 = tid & 7;
            const int kc = ((c16 ^ (row & 7)) << 3);
            gload16(&Vtg[((size_t)head * DHD + row) * LQ + kt * 64 + kc], &VtL[b][tid * 8]);
        }
    };
    stageBV(0, 0);

    floatx4 oA[4] = {}, oB[4] = {};
    float lsA = 0.f, lsB = 0.f;
    const int xorp = (lr & 7) << 4;
    const int colb = lg << 4;
    int c = 0;

    for (int kt = 0; kt < 16; ++kt) {
        if (kt < 15) {
            stageBV(kt + 1, c ^ 1);                   // 3 loads stay in flight
            asm volatile("s_waitcnt vmcnt(3)" ::: "memory");
        } else {
            asm volatile("s_waitcnt vmcnt(0)" ::: "memory");
        }
        __builtin_amdgcn_sched_barrier(0);
        __builtin_amdgcn_s_barrier();                 // tile kt staged for all waves

        const char* lb = (const char*)BsL[c];
        const char* lv = (const char*)VtL[c];

        // ---- S^T strips, kfrag shared across both q-groups ----
        floatx4 sA[4] = {}, sB[4] = {};
        __builtin_amdgcn_s_setprio(1);
        #pragma unroll
        for (int ks = 0; ks < 4; ++ks) {
            const int cb = (ks * 64 + colb) ^ xorp;
            bf16x8 kf[4];
            #pragma unroll
            for (int j = 0; j < 4; ++j)
                kf[j] = *(const bf16x8*)(lb + (((j * 16 + lr) << 8) + cb));
            #pragma unroll
            for (int j = 0; j < 4; ++j) {
                sA[j] = __builtin_amdgcn_mfma_f32_16x16x32_bf16(kf[j], qfA[ks], sA[j], 0, 0, 0);
                sB[j] = __builtin_amdgcn_mfma_f32_16x16x32_bf16(kf[j], qfB[ks], sB[j], 0, 0, 0);
            }
        }
        __builtin_amdgcn_s_setprio(0);

        // ---- no-max softmax ----
        float tsa = 0.f, tsb = 0.f;
        #pragma unroll
        for (int j = 0; j < 4; ++j)
            #pragma unroll
            for (int r = 0; r < 4; ++r) {
                float ea = exp2f(sA[j][r]); sA[j][r] = ea; tsa += ea;
                float eb = exp2f(sB[j][r]); sB[j][r] = eb; tsb += eb;
            }
        lsA += tsa; lsB += tsb;

        // ---- P -> per-wave LDS (cvt_pk), rows 0-15 = A, 16-31 = B ----
        #pragma unroll
        for (int j = 0; j < 4; ++j) {
            unsigned plo, phi;
            asm("v_cvt_pk_bf16_f32 %0, %1, %2" : "=v"(plo) : "v"(sA[j][0]), "v"(sA[j][1]));
            asm("v_cvt_pk_bf16_f32 %0, %1, %2" : "=v"(phi) : "v"(sA[j][2]), "v"(sA[j][3]));
            uint2 pv; pv.x = plo; pv.y = phi;
            *(uint2*)&Ps[w][lr][j * 16 + lg * 4] = pv;
            asm("v_cvt_pk_bf16_f32 %0, %1, %2" : "=v"(plo) : "v"(sB[j][0]), "v"(sB[j][1]));
            asm("v_cvt_pk_bf16_f32 %0, %1, %2" : "=v"(phi) : "v"(sB[j][2]), "v"(sB[j][3]));
            pv.x = plo; pv.y = phi;
            *(uint2*)&Ps[w][16 + lr][j * 16 + lg * 4] = pv;
        }

        // ---- PV: vfrag shared across both q-groups ----
        __builtin_amdgcn_s_setprio(1);
        #pragma unroll
        for (int ks2 = 0; ks2 < 2; ++ks2) {
            const int cb = (ks2 * 64 + colb) ^ xorp;
            bf16x8 pfA = *(const bf16x8*)&Ps[w][lr][ks2 * 32 + lg * 8];
            bf16x8 pfB = *(const bf16x8*)&Ps[w][16 + lr][ks2 * 32 + lg * 8];
            #pragma unroll
            for (int m = 0; m < 4; ++m) {
                bf16x8 vf = *(const bf16x8*)(lv + (((m * 16 + lr) << 7) + cb));
                oA[m] = __builtin_amdgcn_mfma_f32_16x16x32_bf16(vf, pfA, oA[m], 0, 0, 0);
                oB[m] = __builtin_amdgcn_mfma_f32_16x16x32_bf16(vf, pfB, oB[m], 0, 0, 0);
            }
        }
        __builtin_amdgcn_s_setprio(0);
        __builtin_amdgcn_s_barrier();                 // all waves done with buf c
        __builtin_amdgcn_sched_barrier(0);
        c ^= 1;
    }

    // denominators (once), normalize, write merged-head T (bf16)
    lsA += __shfl_xor(lsA, 16); lsA += __shfl_xor(lsA, 32);
    lsB += __shfl_xor(lsB, 16); lsB += __shfl_xor(lsB, 32);
    const float invA = 1.f / lsA, invB = 1.f / lsB;
    const size_t trA = ((size_t)ns * LQ + row0 + w * 32 + lr) * DM + h * DHD;
    const size_t trB = trA + (size_t)16 * DM;
    #pragma unroll
    for (int m = 0; m < 4; ++m) {
        union { u16 u[4]; uint2 v; } pk;
        pk.u[0] = f2bf(oA[m][0] * invA); pk.u[1] = f2bf(oA[m][1] * invA);
        pk.u[2] = f2bf(oA[m][2] * invA); pk.u[3] = f2bf(oA[m][3] * invA);
        *(uint2*)&Tbf[trA + m * 16 + lg * 4] = pk.v;
        pk.u[0] = f2bf(oB[m][0] * invB); pk.u[1] = f2bf(oB[m][1] * invB);
        pk.u[2] = f2bf(oB[m][2] * invB); pk.u[3] = f2bf(oB[m][3] * invB);
        *(uint2*)&Tbf[trB + m * 16 + lg * 4] = pk.v;
    }
}

// ---------------------------------------------------------------------------
// BN: reduce per-block partials (64 m-blocks) -> stats; then final (float4)
// ---------------------------------------------------------------------------
__global__ __launch_bounds__(256)
void bn_reduce(const float* __restrict__ part, float* __restrict__ stats)
{
    const int cx = blockIdx.x * 256 + threadIdx.x;   // 0..511
    float s = 0.f, s2 = 0.f;
    for (int b = 0; b < 64; ++b) {
        s  += part[(size_t)b * 512 + cx];
        s2 += part[32768 + (size_t)b * 512 + cx];
    }
    stats[cx] = s;
    stats[512 + cx] = s2;
}

__global__ __launch_bounds__(256)
void bn_final(const float* __restrict__ Y, const float* __restrict__ Qin,
              const float* __restrict__ stats,
              const float* __restrict__ gamma, const float* __restrict__ beta,
              float* __restrict__ out)
{
    const int i4 = blockIdx.x * 256 + threadIdx.x;   // 0..ROWS*DM/4-1
    const int c4 = (i4 & 127) * 4;                   // channel base
    const float4 sm  = *(const float4*)&stats[c4];
    const float4 sq  = *(const float4*)&stats[512 + c4];
    const float4 gm  = *(const float4*)&gamma[c4];
    const float4 bt  = *(const float4*)&beta[c4];
    const float4 y   = *(const float4*)&Y[(size_t)i4 * 4];
    const float4 q   = *(const float4*)&Qin[(size_t)i4 * 4];
    float4 o;
    {
        const float mu = sm.x * (1.f / ROWS);
        const float rs = rsqrtf(sq.x * (1.f / ROWS) - mu * mu + 1e-5f);
        o.x = q.x + (y.x - mu) * rs * gm.x + bt.x;
    }
    {
        const float mu = sm.y * (1.f / ROWS);
        const float rs = rsqrtf(sq.y * (1.f / ROWS) - mu * mu + 1e-5f);
        o.y = q.y + (y.y - mu) * rs * gm.y + bt.y;
    }
    {
        const float mu = sm.z * (1.f / ROWS);
        const float rs = rsqrtf(sq.z * (1.f / ROWS) - mu * mu + 1e-5f);
        o.z = q.z + (y.z - mu) * rs * gm.z + bt.z;
    }
    {
        const float mu = sm.w * (1.f / ROWS);
        const float rs = rsqrtf(sq.w * (1.f / ROWS) - mu * mu + 1e-5f);
        o.w = q.w + (y.w - mu) * rs * gm.w + bt.w;
    }
    *(float4*)&out[(size_t)i4 * 4] = o;
}

// ---------------------------------------------------------------------------
extern "C" void kernel_launch(void* const* d_in, const int* in_sizes, int n_in,
                              void* d_out, int out_size, void* d_ws, size_t ws_size,
                              hipStream_t stream)
{
    (void)in_sizes; (void)n_in; (void)out_size; (void)ws_size;

    const float* Q    = (const float*)d_in[0];
    const float* K    = (const float*)d_in[1];
    const float* Pq   = (const float*)d_in[2];
    const float* Pk   = (const float*)d_in[3];
    const float* Wq   = (const float*)d_in[4];
    const float* bq   = (const float*)d_in[5];
    const float* Wk   = (const float*)d_in[6];
    const float* bk   = (const float*)d_in[7];
    const float* Wv   = (const float*)d_in[8];
    const float* bv   = (const float*)d_in[9];
    const float* Wp   = (const float*)d_in[10];
    const float* bp   = (const float*)d_in[11];
    const float* We   = (const float*)d_in[12];
    const float* be   = (const float*)d_in[13];
    const float* Wc   = (const float*)d_in[14];
    const float* bc   = (const float*)d_in[15];
    const float* gamma= (const float*)d_in[16];
    const float* beta = (const float*)d_in[17];

    const size_t MB = 1u << 20;
    char* w8 = (char*)d_ws;
    u16*  Abf  = (u16*)(w8);                  // 16 MB (A operands)
    u16*  Bbf  = (u16*)(w8 + 16 * MB);        // 16 MB
    u16*  Vtb  = (u16*)(w8 + 32 * MB);        //  8 MB
    u16*  Tbf  = (u16*)(w8 + 40 * MB);        //  8 MB
    u16*  H1b  = (u16*)(w8 + 48 * MB);        // 16 MB
    u16*  Qbf  = (u16*)(w8 + 64 * MB);        //  8 MB
    u16*  Kbf  = (u16*)(w8 + 72 * MB);        //  8 MB
    float* Y   = (float*)(w8);                // 16 MB (reuses Abf after attn)
    float* part  = (float*)(w8 + 16 * MB);    // 256 KB (reuses Bbf after attn)
    float* stats = (float*)(w8 + 17 * MB);    //  4 KB
    u16*  Wqb  = (u16*)(w8 + 80 * MB);                    // 0.5 MB
    u16*  Wkvb = (u16*)(w8 + 80 * MB + 512 * 1024);       // 1 MB
    u16*  Web  = (u16*)(w8 + 80 * MB + 1536 * 1024);      // 1 MB
    u16*  Wcb  = (u16*)(w8 + 80 * MB + 2560 * 1024);      // 1 MB

    dim3 blk256(256);

    // one fused cast: weights + Q + K
    castall<<<4992, blk256, 0, stream>>>(Wq, Wk, Wv, We, Wc, Q, K,
                                         Wqb, Wkvb, Web, Wcb, Qbf, Kbf);

    // fused Q-proj + KV-proj (one dispatch, 768 blocks, pure gload_lds path)
    proj_qkv<<<dim3(64, 12), blk256, 0, stream>>>(Qbf, Kbf, Wqb, Wkvb,
        bq, bk, bv, Abf, Bbf, Vtb, Pq, Pk, Wp, bp);

    // flash attention (256 blocks x 8 waves, dual-group, 1 block/CU)
    attn_mfma<<<256, dim3(512), 0, stream>>>(Abf, Bbf, Vtb, Tbf);

    // FFN
    gemm_k<1><<<dim3(64, 8), blk256, 0, stream>>>(Tbf, Web, be, H1b, DM, 2 * DM, nullptr);
    gemm_k<0><<<dim3(64, 4), blk256, 0, stream>>>(H1b, Wcb, bc, Y, 2 * DM, DM, part);

    // BN stats + final
    bn_reduce<<<2, blk256, 0, stream>>>(part, stats);
    bn_final<<<ROWS * DM / 1024, blk256, 0, stream>>>(Y, Q, stats, gamma, beta,
                                                      (float*)d_out);
}